// Round 1
// baseline (1621.356 us; speedup 1.0000x reference)
//
#include <hip/hip_runtime.h>
#include <math.h>
#include <cstddef>

// Problem constants
#define LQ   19200          // NL*H*W tokens
#define HH   40
#define WW   120
#define HWp  4800
#define CCh  128
#define NHd  8
#define NLv  4
#define NPt  4
#define DFFc 512
#define RHs  80
#define RWs  240

// ---------------------------------------------------------------------------
// Tiled SGEMM: Out[M,N] = (A [+Pos]) [M,K] @ Wt[N,K]^T + bias, opt relu,
// opt transposed store (Out[n*M+m]). M%64==0, N%64==0, K%16==0 assumed.
// ---------------------------------------------------------------------------
template<bool ADD_POS, bool RELU, bool TRANS_OUT>
__global__ __launch_bounds__(256) void gemm_tn(
    const float* __restrict__ A, const float* __restrict__ Pos,
    const float* __restrict__ Wt, const float* __restrict__ bias,
    float* __restrict__ Out, int M, int N, int K)
{
    constexpr int BM = 64, BN = 64, BK = 16;
    __shared__ float As[BK][BM + 1];
    __shared__ float Bs[BK][BN + 1];
    const int bm = blockIdx.y * BM, bn = blockIdx.x * BN;
    const int tid = threadIdx.x;
    const int tx = tid & 15, ty = tid >> 4;
    const int lrow = tid >> 2;          // 0..63
    const int lk = (tid & 3) << 2;      // 0,4,8,12

    float acc[4][4] = {};
    const float* aptr = A + (size_t)(bm + lrow) * K + lk;
    const float* pptr = ADD_POS ? (Pos + (size_t)(bm + lrow) * K + lk) : nullptr;
    const float* wptr = Wt + (size_t)(bn + lrow) * K + lk;

    for (int k0 = 0; k0 < K; k0 += BK) {
        float4 a4 = *(const float4*)(aptr + k0);
        if constexpr (ADD_POS) {
            float4 p4 = *(const float4*)(pptr + k0);
            a4.x += p4.x; a4.y += p4.y; a4.z += p4.z; a4.w += p4.w;
        }
        float4 b4 = *(const float4*)(wptr + k0);
        As[lk + 0][lrow] = a4.x; As[lk + 1][lrow] = a4.y;
        As[lk + 2][lrow] = a4.z; As[lk + 3][lrow] = a4.w;
        Bs[lk + 0][lrow] = b4.x; Bs[lk + 1][lrow] = b4.y;
        Bs[lk + 2][lrow] = b4.z; Bs[lk + 3][lrow] = b4.w;
        __syncthreads();
        #pragma unroll
        for (int kk = 0; kk < BK; kk++) {
            float a[4], b[4];
            #pragma unroll
            for (int i = 0; i < 4; i++) a[i] = As[kk][(ty << 2) + i];
            #pragma unroll
            for (int j = 0; j < 4; j++) b[j] = Bs[kk][(tx << 2) + j];
            #pragma unroll
            for (int i = 0; i < 4; i++)
                #pragma unroll
                for (int j = 0; j < 4; j++)
                    acc[i][j] = fmaf(a[i], b[j], acc[i][j]);
        }
        __syncthreads();
    }
    #pragma unroll
    for (int i = 0; i < 4; i++) {
        int row = bm + (ty << 2) + i;
        #pragma unroll
        for (int j = 0; j < 4; j++) {
            int col = bn + (tx << 2) + j;
            float v = acc[i][j] + bias[col];
            if (RELU) v = fmaxf(v, 0.f);
            if (TRANS_OUT) Out[(size_t)col * M + row] = v;
            else           Out[(size_t)row * N + col] = v;
        }
    }
}

// ---------------------------------------------------------------------------
// im2col for stride-2 3x3 pad-1 conv, input x:(4,128,80,240)
// col[row=n*4800+oh*120+ow][k=cin*9+ky*3+kx]
// ---------------------------------------------------------------------------
__global__ void im2col_s2(const float* __restrict__ x, float* __restrict__ col)
{
    unsigned idx = blockIdx.x * 256u + threadIdx.x;   // < 22,118,400
    if (idx >= (unsigned)LQ * 1152u) return;
    int k = idx % 1152;
    int row = idx / 1152;
    int cin = k / 9, r = k % 9;
    int ky = r / 3, kx = r % 3;
    int n = row / HWp, pix = row % HWp;
    int oh = pix / WW, ow = pix % WW;
    int iy = oh * 2 + ky - 1, ix = ow * 2 + kx - 1;
    float v = 0.f;
    if ((unsigned)iy < (unsigned)RHs && (unsigned)ix < (unsigned)RWs)
        v = x[(((size_t)n * CCh + cin) * RHs + iy) * RWs + ix];
    col[idx] = v;
}

// im2col for stride-1 3x3 pad-1 conv, input ups:(128,80,240)
__global__ void im2col_s1(const float* __restrict__ ups, float* __restrict__ col)
{
    unsigned idx = blockIdx.x * 256u + threadIdx.x;
    if (idx >= (unsigned)19200 * 1152u) return;
    int k = idx % 1152;
    int row = idx / 1152;
    int cin = k / 9, r = k % 9;
    int ky = r / 3, kx = r % 3;
    int y = row / RWs, x = row % RWs;
    int iy = y + ky - 1, ix = x + kx - 1;
    float v = 0.f;
    if ((unsigned)iy < (unsigned)RHs && (unsigned)ix < (unsigned)RWs)
        v = ups[((size_t)cin * RHs + iy) * RWs + ix];
    col[idx] = v;
}

// ---------------------------------------------------------------------------
// Sine positional embedding + level embedding: pos[q=(n,h,w)][c]
// c in [0,64): y-embed; [64,128): x-embed. even=sin, odd=cos.
// ---------------------------------------------------------------------------
__global__ void pos_embed(const float* __restrict__ lvl_emb, float* __restrict__ pos)
{
    unsigned idx = blockIdx.x * 256u + threadIdx.x;   // < LQ*128
    if (idx >= (unsigned)LQ * CCh) return;
    int c = idx & 127;
    int q = idx >> 7;
    int n = q / HWp, pix = q % HWp;
    int h = pix / WW, w = pix % WW;
    int cc = (c < 64) ? c : (c - 64);
    float coord = (c < 64) ? (float)(h + 1) : (float)(w + 1);
    float denom = (c < 64) ? 40.0f : 120.0f;
    float e = coord / (denom + 1e-6f) * 6.283185307179586f;
    float expo = (float)(cc & ~1) * (1.0f / 64.0f);
    float dim_t = powf(10000.0f, expo);
    float p = e / dim_t;
    float v = (cc & 1) ? cosf(p) : sinf(p);
    pos[idx] = v + lvl_emb[n * CCh + c];
}

// softmax over 16 consecutive values per (q, head); attn (LQ,128) in-place
__global__ void softmax16(float* __restrict__ a)
{
    unsigned gid = blockIdx.x * 256u + threadIdx.x;   // < LQ*NH
    if (gid >= (unsigned)LQ * NHd) return;
    float* p = a + (size_t)gid * 16;
    float m = p[0];
    #pragma unroll
    for (int i = 1; i < 16; i++) m = fmaxf(m, p[i]);
    float e[16], s = 0.f;
    #pragma unroll
    for (int i = 0; i < 16; i++) { e[i] = expf(p[i] - m); s += e[i]; }
    float r = 1.0f / s;
    #pragma unroll
    for (int i = 0; i < 16; i++) p[i] = e[i] * r;
}

__device__ inline void fma4(float4& a, float w, const float4 v)
{
    a.x = fmaf(w, v.x, a.x); a.y = fmaf(w, v.y, a.y);
    a.z = fmaf(w, v.z, a.z); a.w = fmaf(w, v.w, a.w);
}

// ---------------------------------------------------------------------------
// MS deformable attention sampling.
// val:(LQ,128) rows = l*4800+pix; off:(LQ,256) [(h,l,p),(x,y)];
// attn:(LQ,128) softmaxed [(h),(l*4+p)]; out:(LQ,128) [(h),(d)]
// sample coord: x_img = qx + off_x ; y_img = qy + off_y  (pixel-center refs)
// ---------------------------------------------------------------------------
__global__ __launch_bounds__(256) void deform_sample(
    const float* __restrict__ val, const float* __restrict__ off,
    const float* __restrict__ attn, float* __restrict__ out)
{
    unsigned gid = blockIdx.x * 256u + threadIdx.x;   // < LQ*NH
    if (gid >= (unsigned)LQ * NHd) return;
    int q = gid >> 3, h = gid & 7;
    int pix = q % HWp;
    int qy = pix / WW, qx = pix % WW;
    const float* offp = off + (size_t)q * (NHd * NLv * NPt * 2) + h * (NLv * NPt * 2);
    const float* ap = attn + (size_t)q * CCh + h * 16;
    float4 acc0 = {0,0,0,0}, acc1 = {0,0,0,0}, acc2 = {0,0,0,0}, acc3 = {0,0,0,0};
    for (int l = 0; l < NLv; l++) {
        const float* vbase = val + (size_t)l * HWp * CCh + h * 16;
        #pragma unroll
        for (int p = 0; p < NPt; p++) {
            float ox = offp[(l * NPt + p) * 2 + 0];
            float oy = offp[(l * NPt + p) * 2 + 1];
            float a = ap[l * NPt + p];
            float x = (float)qx + ox;
            float y = (float)qy + oy;
            float xf = floorf(x), yf = floorf(y);
            int x0 = (int)xf, y0 = (int)yf;
            float wx1 = x - xf, wy1 = y - yf;
            float wx0 = 1.f - wx1, wy0 = 1.f - wy1;
            #pragma unroll
            for (int dy = 0; dy < 2; dy++) {
                int yc = y0 + dy;
                if ((unsigned)yc >= (unsigned)HH) continue;
                float wy = dy ? wy1 : wy0;
                #pragma unroll
                for (int dx = 0; dx < 2; dx++) {
                    int xc = x0 + dx;
                    if ((unsigned)xc >= (unsigned)WW) continue;
                    float wgt = a * wy * (dx ? wx1 : wx0);
                    const float4* vp = (const float4*)(vbase + (size_t)(yc * WW + xc) * CCh);
                    fma4(acc0, wgt, vp[0]);
                    fma4(acc1, wgt, vp[1]);
                    fma4(acc2, wgt, vp[2]);
                    fma4(acc3, wgt, vp[3]);
                }
            }
        }
    }
    float4* op = (float4*)(out + (size_t)q * CCh + h * 16);
    op[0] = acc0; op[1] = acc1; op[2] = acc2; op[3] = acc3;
}

// Residual + LayerNorm, in-place on src. One wave (64 lanes) per 128-ch row.
__global__ __launch_bounds__(256) void ln_residual(
    float* __restrict__ src, const float* __restrict__ delta,
    const float* __restrict__ g, const float* __restrict__ b)
{
    int row = blockIdx.x * 4 + (threadIdx.x >> 6);
    int lane = threadIdx.x & 63;
    float* sp = src + (size_t)row * CCh;
    const float* dp = delta + (size_t)row * CCh;
    float x0 = sp[lane] + dp[lane];
    float x1 = sp[lane + 64] + dp[lane + 64];
    float s = x0 + x1, ss = x0 * x0 + x1 * x1;
    #pragma unroll
    for (int o = 32; o > 0; o >>= 1) {
        s += __shfl_down(s, o);
        ss += __shfl_down(ss, o);
    }
    s = __shfl(s, 0); ss = __shfl(ss, 0);
    float mean = s * (1.0f / 128.0f);
    float var = ss * (1.0f / 128.0f) - mean * mean;
    float inv = rsqrtf(var + 1e-5f);
    sp[lane]      = (x0 - mean) * inv * g[lane] + b[lane];
    sp[lane + 64] = (x1 - mean) * inv * g[lane + 64] + b[lane + 64];
}

// Gather src (LQ,128) -> A_merge (4800, 512): A[pix][n*128+c] = src[n*4800+pix][c]
__global__ void merge_gather(const float* __restrict__ src, float* __restrict__ A)
{
    unsigned idx = blockIdx.x * 256u + threadIdx.x;   // < 4800*512
    if (idx >= 4800u * 512u) return;
    int k = idx & 511;
    int pix = idx >> 9;
    int n = k >> 7, c = k & 127;
    A[idx] = src[((size_t)(n * HWp + pix)) * CCh + c];
}

// Bilinear 2x upsample (half-pixel, edge clamp): m (128,40,120) -> ups (128,80,240)
__global__ void upsample2x(const float* __restrict__ m, float* __restrict__ ups)
{
    unsigned idx = blockIdx.x * 256u + threadIdx.x;   // < 128*80*240
    if (idx >= (unsigned)CCh * RHs * RWs) return;
    int x = idx % RWs;
    int t = idx / RWs;
    int y = t % RHs;
    int c = t / RHs;
    float fy = (y + 0.5f) * 0.5f - 0.5f;
    float fx = (x + 0.5f) * 0.5f - 0.5f;
    float fyf = floorf(fy), fxf = floorf(fx);
    int y0 = (int)fyf, x0 = (int)fxf;
    float wy = fy - fyf, wx = fx - fxf;
    int y0c = max(y0, 0), y1c = min(y0 + 1, HH - 1);
    int x0c = max(x0, 0), x1c = min(x0 + 1, WW - 1);
    const float* mp = m + (size_t)c * HWp;
    float v00 = mp[y0c * WW + x0c], v01 = mp[y0c * WW + x1c];
    float v10 = mp[y1c * WW + x0c], v11 = mp[y1c * WW + x1c];
    ups[idx] = (1.f - wy) * ((1.f - wx) * v00 + wx * v01)
             + wy * ((1.f - wx) * v10 + wx * v11);
}

// ---------------------------------------------------------------------------
extern "C" void kernel_launch(void* const* d_in, const int* in_sizes, int n_in,
                              void* d_out, int out_size, void* d_ws, size_t ws_size,
                              hipStream_t stream)
{
    const float* x       = (const float*)d_in[0];
    const float* dconv_w = (const float*)d_in[1];
    const float* dconv_b = (const float*)d_in[2];
    const float* lvl_emb = (const float*)d_in[3];
    const float* W_off   = (const float*)d_in[4];
    const float* b_off   = (const float*)d_in[5];
    const float* W_attn  = (const float*)d_in[6];
    const float* b_attn  = (const float*)d_in[7];
    const float* W_val   = (const float*)d_in[8];
    const float* b_val   = (const float*)d_in[9];
    const float* W_out   = (const float*)d_in[10];
    const float* b_out   = (const float*)d_in[11];
    const float* ln1_g   = (const float*)d_in[12];
    const float* ln1_b   = (const float*)d_in[13];
    const float* W_ff1   = (const float*)d_in[14];
    const float* b_ff1   = (const float*)d_in[15];
    const float* W_ff2   = (const float*)d_in[16];
    const float* b_ff2   = (const float*)d_in[17];
    const float* ln2_g   = (const float*)d_in[18];
    const float* ln2_b   = (const float*)d_in[19];
    const float* merge_w = (const float*)d_in[20];
    const float* merge_b = (const float*)d_in[21];
    const float* uconv_w = (const float*)d_in[22];
    const float* uconv_b = (const float*)d_in[23];

    float* ws = (float*)d_ws;
    // layout (floats):
    float* colbuf  = ws;                 // 22,118,400  (19200 x 1152)
    float* src     = ws + 22118400;      //  2,457,600
    float* pos     = ws + 24576000;      //  2,457,600
    float* val     = ws + 27033600;      //  2,457,600
    float* attnb   = ws + 29491200;      //  2,457,600
    float* attnout = ws + 31948800;      //  2,457,600 -> total 34,406,400 floats (131.3 MiB)
    // aliases inside colbuf during transformer layers (colbuf idle then):
    float* offb = colbuf;                //  4,915,200 (19200 x 256)
    float* ff1  = colbuf + 4915200;      //  9,830,400 (19200 x 512)
    float* tmp  = colbuf + 14745600;     //  2,457,600
    // end-stage aliases (layer buffers dead):
    float* merge_in = attnb;             //  2,457,600 (4800 x 512)
    float* mbuf     = attnout;           //    614,400 (128 x 4800)
    float* ups      = val;               //  2,457,600 (128 x 80 x 240)
    float* outp = (float*)d_out;

    // 1) downsample conv as im2col + GEMM -> src (LQ,128), relu
    im2col_s2<<<86400, 256, 0, stream>>>(x, colbuf);
    gemm_tn<false, true, false><<<dim3(2, 300), 256, 0, stream>>>(
        colbuf, nullptr, dconv_w, dconv_b, src, LQ, 128, 1152);

    // 2) positional + level embedding
    pos_embed<<<9600, 256, 0, stream>>>(lvl_emb, pos);

    // 3) encoder layers
    for (int i = 0; i < 3; i++) {
        const float* Wv = W_val  + (size_t)i * 128 * 128;
        const float* bv = b_val  + (size_t)i * 128;
        const float* Wo = W_off  + (size_t)i * 256 * 128;
        const float* bo = b_off  + (size_t)i * 256;
        const float* Wa = W_attn + (size_t)i * 128 * 128;
        const float* ba = b_attn + (size_t)i * 128;
        const float* Wu = W_out  + (size_t)i * 128 * 128;
        const float* bu = b_out  + (size_t)i * 128;
        const float* g1 = ln1_g  + (size_t)i * 128;
        const float* c1 = ln1_b  + (size_t)i * 128;
        const float* Wf1 = W_ff1 + (size_t)i * 512 * 128;
        const float* bf1 = b_ff1 + (size_t)i * 512;
        const float* Wf2 = W_ff2 + (size_t)i * 128 * 512;
        const float* bf2 = b_ff2 + (size_t)i * 128;
        const float* g2 = ln2_g  + (size_t)i * 128;
        const float* c2 = ln2_b  + (size_t)i * 128;

        gemm_tn<false, false, false><<<dim3(2, 300), 256, 0, stream>>>(
            src, nullptr, Wv, bv, val, LQ, 128, 128);
        gemm_tn<true, false, false><<<dim3(4, 300), 256, 0, stream>>>(
            src, pos, Wo, bo, offb, LQ, 256, 128);
        gemm_tn<true, false, false><<<dim3(2, 300), 256, 0, stream>>>(
            src, pos, Wa, ba, attnb, LQ, 128, 128);
        softmax16<<<600, 256, 0, stream>>>(attnb);
        deform_sample<<<600, 256, 0, stream>>>(val, offb, attnb, attnout);
        gemm_tn<false, false, false><<<dim3(2, 300), 256, 0, stream>>>(
            attnout, nullptr, Wu, bu, tmp, LQ, 128, 128);
        ln_residual<<<4800, 256, 0, stream>>>(src, tmp, g1, c1);
        gemm_tn<false, true, false><<<dim3(8, 300), 256, 0, stream>>>(
            src, nullptr, Wf1, bf1, ff1, LQ, 512, 128);
        gemm_tn<false, false, false><<<dim3(2, 300), 256, 0, stream>>>(
            ff1, nullptr, Wf2, bf2, tmp, LQ, 128, 512);
        ln_residual<<<4800, 256, 0, stream>>>(src, tmp, g2, c2);
    }

    // 4) merge 1x1 conv: gather (4800,512) then GEMM -> m (128,40,120), relu
    merge_gather<<<9600, 256, 0, stream>>>(src, merge_in);
    gemm_tn<false, true, true><<<dim3(2, 75), 256, 0, stream>>>(
        merge_in, nullptr, merge_w, merge_b, mbuf, 4800, 128, 512);

    // 5) bilinear 2x upsample -> (128,80,240)
    upsample2x<<<9600, 256, 0, stream>>>(mbuf, ups);

    // 6) uconv 3x3 as im2col + GEMM -> d_out (1,128,80,240), relu
    im2col_s1<<<86400, 256, 0, stream>>>(ups, colbuf);
    gemm_tn<false, true, true><<<dim3(2, 300), 256, 0, stream>>>(
        colbuf, nullptr, uconv_w, uconv_b, outp, 19200, 128, 1152);
}

// Round 2
// 722.542 us; speedup vs baseline: 2.2440x; 2.2440x over previous
//
#include <hip/hip_runtime.h>
#include <math.h>
#include <cstddef>

// Problem constants
#define LQ   19200          // NL*H*W tokens
#define HH   40
#define WW   120
#define HWp  4800
#define CCh  128
#define NHd  8
#define NLv  4
#define NPt  4
#define RHs  80
#define RWs  240

typedef __attribute__((ext_vector_type(8))) short bf16x8;
typedef __attribute__((ext_vector_type(4))) float f32x4;
typedef __attribute__((address_space(1))) const unsigned int GUI;
typedef __attribute__((address_space(3))) unsigned int LUI;

__device__ inline unsigned short f2bf(float f) {
    unsigned int u = __float_as_uint(f);
    u += 0x7fffu + ((u >> 16) & 1u);        // round-to-nearest-even
    return (unsigned short)(u >> 16);
}
__device__ inline float bf2f(unsigned int lo16) { return __uint_as_float(lo16 << 16); }

// ---------------------------------------------------------------------------
// bf16 MFMA GEMM: Out[M,N] = A[M,K] @ Bw[N,K]^T + bias, opt relu.
// BIAS_ROW: bias indexed by row (for weight-as-A transposed-conv trick).
// OMODE: 0 = fp32 out, 1 = bf16 out, 2 = both.
// M%128==0 or M==128; N%64==0; K%32==0. All pointers 16B-aligned.
// Structure: 128x64 block tile, BK=32, global_load_lds(16B), 4 waves x 64x32.
// ---------------------------------------------------------------------------
template<bool BIAS_ROW, bool RELU, int OMODE>
__global__ __launch_bounds__(256) void gemm_bf16(
    const unsigned short* __restrict__ A,
    const unsigned short* __restrict__ Bw,
    const float* __restrict__ bias,
    float* __restrict__ OutF, unsigned short* __restrict__ OutB,
    int M, int N, int K)
{
    constexpr int BM = 128, BN = 64, BK = 32;
    __shared__ unsigned short As[BM * BK];   // row-major [m][k], 64 B/row
    __shared__ unsigned short Bs[BN * BK];
    const int bm = blockIdx.y * BM, bn = blockIdx.x * BN;
    const int tid = threadIdx.x;
    const int wid = tid >> 6, lane = tid & 63;
    const int wm = (wid & 1) * 64, wn = (wid >> 1) * 32;
    const int lm = lane & 15, lqd = lane >> 4;

    f32x4 acc[4][2] = {};

    const int arow = lane >> 2;          // 0..15 within a 16-row chunk
    const int akc  = (lane & 3) * 8;     // k element offset (16 B granules)
    const unsigned short* aG0 = A  + (size_t)(bm + wid * 32 +      arow) * K + akc;
    const unsigned short* aG1 = A  + (size_t)(bm + wid * 32 + 16 + arow) * K + akc;
    const unsigned short* bG  = Bw + (size_t)(bn + wid * 16 +      arow) * K + akc;
    unsigned short* aL0 = As + wid * 1024 + lane * 8;        // chunk 2*wid
    unsigned short* aL1 = As + wid * 1024 + 512 + lane * 8;  // chunk 2*wid+1
    unsigned short* bL  = Bs + wid * 512 + lane * 8;

    for (int k0 = 0; k0 < K; k0 += BK) {
        __builtin_amdgcn_global_load_lds((GUI*)(aG0 + k0), (LUI*)aL0, 16, 0, 0);
        __builtin_amdgcn_global_load_lds((GUI*)(aG1 + k0), (LUI*)aL1, 16, 0, 0);
        __builtin_amdgcn_global_load_lds((GUI*)(bG  + k0), (LUI*)bL,  16, 0, 0);
        __syncthreads();
        bf16x8 a[4], b[2];
        #pragma unroll
        for (int i = 0; i < 4; i++)
            a[i] = *(const bf16x8*)(As + (wm + i * 16 + lm) * BK + lqd * 8);
        #pragma unroll
        for (int j = 0; j < 2; j++)
            b[j] = *(const bf16x8*)(Bs + (wn + j * 16 + lm) * BK + lqd * 8);
        #pragma unroll
        for (int i = 0; i < 4; i++)
            #pragma unroll
            for (int j = 0; j < 2; j++)
                acc[i][j] = __builtin_amdgcn_mfma_f32_16x16x32_bf16(a[i], b[j], acc[i][j], 0, 0, 0);
        __syncthreads();
    }

    #pragma unroll
    for (int i = 0; i < 4; i++) {
        int row0 = bm + wm + i * 16 + lqd * 4;
        #pragma unroll
        for (int j = 0; j < 2; j++) {
            int col = bn + wn + j * 16 + lm;
            float bc = BIAS_ROW ? 0.f : bias[col];
            #pragma unroll
            for (int r = 0; r < 4; r++) {
                int row = row0 + r;
                float v = acc[i][j][r] + (BIAS_ROW ? bias[row] : bc);
                if (RELU) v = fmaxf(v, 0.f);
                size_t o = (size_t)row * N + col;
                if (OMODE == 0) OutF[o] = v;
                else if (OMODE == 1) OutB[o] = f2bf(v);
                else { OutF[o] = v; OutB[o] = f2bf(v); }
            }
        }
    }
}

// ---------------------------------------------------------------------------
// One-shot fp32 -> bf16 weight conversion (all weight tensors concatenated).
// segment offsets: dconv 0, W_val 147456, W_off 196608, W_attn 294912,
// W_out 344064, W_ff1 393216, W_ff2 589824, merge 786432, uconv 851968 (end 999424)
// ---------------------------------------------------------------------------
__global__ void convert_weights(
    const float* __restrict__ a, const float* __restrict__ b, const float* __restrict__ c,
    const float* __restrict__ d, const float* __restrict__ e, const float* __restrict__ f,
    const float* __restrict__ g, const float* __restrict__ h, const float* __restrict__ i2,
    unsigned short* __restrict__ dst)
{
    int idx = blockIdx.x * 256 + threadIdx.x;   // < 999424
    const float* src; int rel, base;
    if      (idx < 147456) { src = a;  rel = idx;          base = 0;      }
    else if (idx < 196608) { src = b;  rel = idx - 147456; base = 147456; }
    else if (idx < 294912) { src = c;  rel = idx - 196608; base = 196608; }
    else if (idx < 344064) { src = d;  rel = idx - 294912; base = 294912; }
    else if (idx < 393216) { src = e;  rel = idx - 344064; base = 344064; }
    else if (idx < 589824) { src = f;  rel = idx - 393216; base = 393216; }
    else if (idx < 786432) { src = g;  rel = idx - 589824; base = 589824; }
    else if (idx < 851968) { src = h;  rel = idx - 786432; base = 786432; }
    else                   { src = i2; rel = idx - 851968; base = 851968; }
    dst[base + rel] = f2bf(src[rel]);
}

// im2col (bf16 out) for stride-2 3x3 pad-1 conv, x:(4,128,80,240)
__global__ void im2col_s2(const float* __restrict__ x, unsigned short* __restrict__ col)
{
    unsigned idx = blockIdx.x * 256u + threadIdx.x;   // < 22,118,400
    int k = idx % 1152;
    int row = idx / 1152;
    int cin = k / 9, r = k % 9;
    int ky = r / 3, kx = r % 3;
    int n = row / HWp, pix = row % HWp;
    int oh = pix / WW, ow = pix % WW;
    int iy = oh * 2 + ky - 1, ix = ow * 2 + kx - 1;
    float v = 0.f;
    if ((unsigned)iy < (unsigned)RHs && (unsigned)ix < (unsigned)RWs)
        v = x[(((size_t)n * CCh + cin) * RHs + iy) * RWs + ix];
    col[idx] = f2bf(v);
}

// im2col (bf16 out) for stride-1 3x3 pad-1 conv, ups:(128,80,240)
__global__ void im2col_s1(const float* __restrict__ ups, unsigned short* __restrict__ col)
{
    unsigned idx = blockIdx.x * 256u + threadIdx.x;
    int k = idx % 1152;
    int row = idx / 1152;
    int cin = k / 9, r = k % 9;
    int ky = r / 3, kx = r % 3;
    int y = row / RWs, x = row % RWs;
    int iy = y + ky - 1, ix = x + kx - 1;
    float v = 0.f;
    if ((unsigned)iy < (unsigned)RHs && (unsigned)ix < (unsigned)RWs)
        v = ups[((size_t)cin * RHs + iy) * RWs + ix];
    col[idx] = f2bf(v);
}

// Sine positional + level embedding (fp32)
__global__ void pos_embed(const float* __restrict__ lvl_emb, float* __restrict__ pos)
{
    unsigned idx = blockIdx.x * 256u + threadIdx.x;   // < LQ*128
    int c = idx & 127;
    int q = idx >> 7;
    int n = q / HWp, pix = q % HWp;
    int h = pix / WW, w = pix % WW;
    int cc = (c < 64) ? c : (c - 64);
    float coord = (c < 64) ? (float)(h + 1) : (float)(w + 1);
    float denom = (c < 64) ? 40.0f : 120.0f;
    float e = coord / (denom + 1e-6f) * 6.283185307179586f;
    float expo = (float)(cc & ~1) * (1.0f / 64.0f);
    float dim_t = powf(10000.0f, expo);
    float p = e / dim_t;
    float v = (cc & 1) ? cosf(p) : sinf(p);
    pos[idx] = v + lvl_emb[n * CCh + c];
}

// q = bf16(src + pos), vectorized x4
__global__ void q_add(const float* __restrict__ src, const float* __restrict__ pos,
                      unsigned short* __restrict__ qb)
{
    unsigned idx = blockIdx.x * 256u + threadIdx.x;   // < LQ*128/4
    float4 s = ((const float4*)src)[idx];
    float4 p = ((const float4*)pos)[idx];
    ushort4 o = { f2bf(s.x + p.x), f2bf(s.y + p.y), f2bf(s.z + p.z), f2bf(s.w + p.w) };
    ((ushort4*)qb)[idx] = o;
}

// softmax over 16 consecutive values per (q, head); attn (LQ,128) fp32 in-place
__global__ void softmax16(float* __restrict__ a)
{
    unsigned gid = blockIdx.x * 256u + threadIdx.x;   // < LQ*NH
    float4 v[4];
    float* p = a + (size_t)gid * 16;
    #pragma unroll
    for (int i = 0; i < 4; i++) v[i] = ((float4*)p)[i];
    float* e = (float*)v;
    float m = e[0];
    #pragma unroll
    for (int i = 1; i < 16; i++) m = fmaxf(m, e[i]);
    float s = 0.f;
    #pragma unroll
    for (int i = 0; i < 16; i++) { e[i] = expf(e[i] - m); s += e[i]; }
    float r = 1.0f / s;
    #pragma unroll
    for (int i = 0; i < 16; i++) e[i] *= r;
    #pragma unroll
    for (int i = 0; i < 4; i++) ((float4*)p)[i] = v[i];
}

__device__ inline void fma_u4(float* acc, float w, uint4 v)
{
    acc[0] = fmaf(w, bf2f(v.x & 0xffffu), acc[0]);
    acc[1] = fmaf(w, bf2f(v.x >> 16),     acc[1]);
    acc[2] = fmaf(w, bf2f(v.y & 0xffffu), acc[2]);
    acc[3] = fmaf(w, bf2f(v.y >> 16),     acc[3]);
    acc[4] = fmaf(w, bf2f(v.z & 0xffffu), acc[4]);
    acc[5] = fmaf(w, bf2f(v.z >> 16),     acc[5]);
    acc[6] = fmaf(w, bf2f(v.w & 0xffffu), acc[6]);
    acc[7] = fmaf(w, bf2f(v.w >> 16),     acc[7]);
}
__device__ inline unsigned int pk2(float a, float b)
{ return (unsigned int)f2bf(a) | ((unsigned int)f2bf(b) << 16); }

// ---------------------------------------------------------------------------
// MS deformable attention sampling (bf16 values in/out).
// val:(LQ,128) rows=l*4800+pix bf16; off:(LQ,256) f32; attn:(LQ,128) f32;
// out:(LQ,128) bf16. Sample coord: x = qx + off_x ; y = qy + off_y.
// ---------------------------------------------------------------------------
__global__ __launch_bounds__(256) void deform_sample(
    const unsigned short* __restrict__ val, const float* __restrict__ off,
    const float* __restrict__ attn, unsigned short* __restrict__ out)
{
    unsigned gid = blockIdx.x * 256u + threadIdx.x;   // < LQ*NH
    int q = gid >> 3, h = gid & 7;
    int pix = q % HWp;
    int qy = pix / WW, qx = pix % WW;
    const float* offp = off + (size_t)q * 256 + h * 32;
    const float* ap   = attn + (size_t)q * 128 + h * 16;
    float acc[16] = {};
    for (int l = 0; l < NLv; l++) {
        const unsigned short* vbase = val + (size_t)l * HWp * CCh + h * 16;
        #pragma unroll
        for (int p = 0; p < NPt; p++) {
            float ox = offp[(l * NPt + p) * 2 + 0];
            float oy = offp[(l * NPt + p) * 2 + 1];
            float a = ap[l * NPt + p];
            float x = (float)qx + ox;
            float y = (float)qy + oy;
            float xf = floorf(x), yf = floorf(y);
            int x0 = (int)xf, y0 = (int)yf;
            float wx1 = x - xf, wy1 = y - yf;
            float wx0 = 1.f - wx1, wy0 = 1.f - wy1;
            #pragma unroll
            for (int dy = 0; dy < 2; dy++) {
                int yc = y0 + dy;
                if ((unsigned)yc >= (unsigned)HH) continue;
                float wy = dy ? wy1 : wy0;
                #pragma unroll
                for (int dx = 0; dx < 2; dx++) {
                    int xc = x0 + dx;
                    if ((unsigned)xc >= (unsigned)WW) continue;
                    float wgt = a * wy * (dx ? wx1 : wx0);
                    const uint4* vp = (const uint4*)(vbase + (size_t)(yc * WW + xc) * CCh);
                    fma_u4(acc,     wgt, vp[0]);
                    fma_u4(acc + 8, wgt, vp[1]);
                }
            }
        }
    }
    uint4 o0 = { pk2(acc[0], acc[1]),  pk2(acc[2], acc[3]),
                 pk2(acc[4], acc[5]),  pk2(acc[6], acc[7]) };
    uint4 o1 = { pk2(acc[8], acc[9]),  pk2(acc[10], acc[11]),
                 pk2(acc[12], acc[13]), pk2(acc[14], acc[15]) };
    uint4* op = (uint4*)(out + (size_t)q * CCh + h * 16);
    op[0] = o0; op[1] = o1;
}

// Residual + LayerNorm, writes fp32 src and bf16 srcb. One wave per row.
__global__ __launch_bounds__(256) void ln_residual(
    float* __restrict__ src, unsigned short* __restrict__ srcb,
    const float* __restrict__ delta,
    const float* __restrict__ g, const float* __restrict__ b)
{
    int row = blockIdx.x * 4 + (threadIdx.x >> 6);
    int lane = threadIdx.x & 63;
    float* sp = src + (size_t)row * CCh;
    unsigned short* sb = srcb + (size_t)row * CCh;
    const float* dp = delta + (size_t)row * CCh;
    float x0 = sp[lane] + dp[lane];
    float x1 = sp[lane + 64] + dp[lane + 64];
    float s = x0 + x1, ss = x0 * x0 + x1 * x1;
    #pragma unroll
    for (int o = 32; o > 0; o >>= 1) {
        s += __shfl_down(s, o);
        ss += __shfl_down(ss, o);
    }
    s = __shfl(s, 0); ss = __shfl(ss, 0);
    float mean = s * (1.0f / 128.0f);
    float var = ss * (1.0f / 128.0f) - mean * mean;
    float inv = rsqrtf(var + 1e-5f);
    float y0 = (x0 - mean) * inv * g[lane] + b[lane];
    float y1 = (x1 - mean) * inv * g[lane + 64] + b[lane + 64];
    sp[lane] = y0;       sp[lane + 64] = y1;
    sb[lane] = f2bf(y0); sb[lane + 64] = f2bf(y1);
}

// Gather src (LQ,128) -> A_merge (4800,512) bf16: A[pix][n*128+c] = src[n*4800+pix][c]
__global__ void merge_gather(const float* __restrict__ src, unsigned short* __restrict__ A)
{
    unsigned idx = blockIdx.x * 256u + threadIdx.x;   // < 614400
    unsigned flat = idx * 4;
    int pix = flat >> 9;
    int k = flat & 511;
    int n = k >> 7, c = k & 127;
    float4 s = *(const float4*)(src + ((size_t)(n * HWp + pix)) * CCh + c);
    ushort4 o = { f2bf(s.x), f2bf(s.y), f2bf(s.z), f2bf(s.w) };
    *(ushort4*)(A + flat) = o;
}

// Bilinear 2x upsample (half-pixel, edge clamp): m (128,40,120) -> ups (128,80,240)
__global__ void upsample2x(const float* __restrict__ m, float* __restrict__ ups)
{
    unsigned idx = blockIdx.x * 256u + threadIdx.x;   // < 128*80*240
    int x = idx % RWs;
    int t = idx / RWs;
    int y = t % RHs;
    int c = t / RHs;
    float fy = (y + 0.5f) * 0.5f - 0.5f;
    float fx = (x + 0.5f) * 0.5f - 0.5f;
    float fyf = floorf(fy), fxf = floorf(fx);
    int y0 = (int)fyf, x0 = (int)fxf;
    float wy = fy - fyf, wx = fx - fxf;
    int y0c = max(y0, 0), y1c = min(y0 + 1, HH - 1);
    int x0c = max(x0, 0), x1c = min(x0 + 1, WW - 1);
    const float* mp = m + (size_t)c * HWp;
    float v00 = mp[y0c * WW + x0c], v01 = mp[y0c * WW + x1c];
    float v10 = mp[y1c * WW + x0c], v11 = mp[y1c * WW + x1c];
    ups[idx] = (1.f - wy) * ((1.f - wx) * v00 + wx * v01)
             + wy * ((1.f - wx) * v10 + wx * v11);
}

// ---------------------------------------------------------------------------
extern "C" void kernel_launch(void* const* d_in, const int* in_sizes, int n_in,
                              void* d_out, int out_size, void* d_ws, size_t ws_size,
                              hipStream_t stream)
{
    const float* x       = (const float*)d_in[0];
    const float* dconv_w = (const float*)d_in[1];
    const float* dconv_b = (const float*)d_in[2];
    const float* lvl_emb = (const float*)d_in[3];
    const float* W_off   = (const float*)d_in[4];
    const float* b_off   = (const float*)d_in[5];
    const float* W_attn  = (const float*)d_in[6];
    const float* b_attn  = (const float*)d_in[7];
    const float* W_val   = (const float*)d_in[8];
    const float* b_val   = (const float*)d_in[9];
    const float* W_out   = (const float*)d_in[10];
    const float* b_out   = (const float*)d_in[11];
    const float* ln1_g   = (const float*)d_in[12];
    const float* ln1_b   = (const float*)d_in[13];
    const float* W_ff1   = (const float*)d_in[14];
    const float* b_ff1   = (const float*)d_in[15];
    const float* W_ff2   = (const float*)d_in[16];
    const float* b_ff2   = (const float*)d_in[17];
    const float* ln2_g   = (const float*)d_in[18];
    const float* ln2_b   = (const float*)d_in[19];
    const float* merge_w = (const float*)d_in[20];
    const float* merge_b = (const float*)d_in[21];
    const float* uconv_w = (const float*)d_in[22];
    const float* uconv_b = (const float*)d_in[23];

    char* wsb = (char*)d_ws;
    unsigned short* colb     = (unsigned short*)(wsb);             // 44,236,800 B (19200x1152 bf16)
    float*          src      = (float*)(wsb + 44236800);           //  9,830,400 B
    unsigned short* srcb     = (unsigned short*)(wsb + 54067200);  //  4,915,200 B
    float*          pos      = (float*)(wsb + 58982400);           //  9,830,400 B
    unsigned short* qb       = (unsigned short*)(wsb + 68812800);  //  4,915,200 B
    unsigned short* valb     = (unsigned short*)(wsb + 73728000);  //  4,915,200 B
    float*          attnb    = (float*)(wsb + 78643200);           //  9,830,400 B
    unsigned short* attnoutb = (unsigned short*)(wsb + 88473600);  //  4,915,200 B
    float*          tmp      = (float*)(wsb + 93388800);           //  9,830,400 B
    unsigned short* wb       = (unsigned short*)(wsb + 103219200); //  ~2,000,000 B
    // aliases inside colb during transformer layers (colb idle then):
    float*          offb = (float*)(wsb);                          // 19,660,800 B
    unsigned short* ff1b = (unsigned short*)(wsb + 19660800);      // 19,660,800 B
    // end-stage aliases:
    unsigned short* merge_in = qb;                                 //  4,915,200 B
    float*          mbuf     = (float*)valb;                       //  2,457,600 B
    float*          ups      = attnb;                              //  9,830,400 B
    float* outp = (float*)d_out;

    // bf16 weight table offsets (elements)
    unsigned short* dconv_wb = wb;
    unsigned short* W_val_b  = wb + 147456;
    unsigned short* W_off_b  = wb + 196608;
    unsigned short* W_attn_b = wb + 294912;
    unsigned short* W_out_b  = wb + 344064;
    unsigned short* W_ff1_b  = wb + 393216;
    unsigned short* W_ff2_b  = wb + 589824;
    unsigned short* merge_wb = wb + 786432;
    unsigned short* uconv_wb = wb + 851968;

    convert_weights<<<3904, 256, 0, stream>>>(
        dconv_w, W_val, W_off, W_attn, W_out, W_ff1, W_ff2, merge_w, uconv_w, wb);

    // 1) downsample conv: im2col(bf16) + MFMA GEMM -> src fp32 + srcb bf16, relu
    im2col_s2<<<86400, 256, 0, stream>>>(x, colb);
    gemm_bf16<false, true, 2><<<dim3(2, 150), 256, 0, stream>>>(
        colb, dconv_wb, dconv_b, src, srcb, LQ, 128, 1152);

    // 2) positional + level embedding
    pos_embed<<<9600, 256, 0, stream>>>(lvl_emb, pos);

    // 3) encoder layers
    for (int i = 0; i < 3; i++) {
        q_add<<<2400, 256, 0, stream>>>(src, pos, qb);
        gemm_bf16<false, false, 1><<<dim3(2, 150), 256, 0, stream>>>(
            srcb, W_val_b + (size_t)i * 16384, b_val + i * 128, nullptr, valb, LQ, 128, 128);
        gemm_bf16<false, false, 0><<<dim3(4, 150), 256, 0, stream>>>(
            qb, W_off_b + (size_t)i * 32768, b_off + i * 256, offb, nullptr, LQ, 256, 128);
        gemm_bf16<false, false, 0><<<dim3(2, 150), 256, 0, stream>>>(
            qb, W_attn_b + (size_t)i * 16384, b_attn + i * 128, attnb, nullptr, LQ, 128, 128);
        softmax16<<<600, 256, 0, stream>>>(attnb);
        deform_sample<<<600, 256, 0, stream>>>(valb, offb, attnb, attnoutb);
        gemm_bf16<false, false, 0><<<dim3(2, 150), 256, 0, stream>>>(
            attnoutb, W_out_b + (size_t)i * 16384, b_out + i * 128, tmp, nullptr, LQ, 128, 128);
        ln_residual<<<4800, 256, 0, stream>>>(src, srcb, tmp, ln1_g + i * 128, ln1_b + i * 128);
        gemm_bf16<false, true, 1><<<dim3(8, 150), 256, 0, stream>>>(
            srcb, W_ff1_b + (size_t)i * 65536, b_ff1 + i * 512, nullptr, ff1b, LQ, 512, 128);
        gemm_bf16<false, false, 0><<<dim3(2, 150), 256, 0, stream>>>(
            ff1b, W_ff2_b + (size_t)i * 65536, b_ff2 + i * 128, tmp, nullptr, LQ, 128, 512);
        ln_residual<<<4800, 256, 0, stream>>>(src, srcb, tmp, ln2_g + i * 128, ln2_b + i * 128);
    }

    // 4) merge 1x1 conv, transposed trick: mbuf[128,4800] = merge_w[128,512] @ merge_in[4800,512]^T
    merge_gather<<<2400, 256, 0, stream>>>(src, merge_in);
    gemm_bf16<true, true, 0><<<dim3(75, 1), 256, 0, stream>>>(
        merge_wb, merge_in, merge_b, mbuf, nullptr, 128, 4800, 512);

    // 5) bilinear 2x upsample -> (128,80,240)
    upsample2x<<<9600, 256, 0, stream>>>(mbuf, ups);

    // 6) uconv 3x3, transposed trick: out[128,19200] = uconv_w[128,1152] @ col[19200,1152]^T
    im2col_s1<<<86400, 256, 0, stream>>>(ups, colb);
    gemm_bf16<true, true, 0><<<dim3(300, 1), 256, 0, stream>>>(
        uconv_wb, colb, uconv_b, outp, nullptr, 128, 19200, 1152);
}

// Round 3
// 670.505 us; speedup vs baseline: 2.4181x; 1.0776x over previous
//
#include <hip/hip_runtime.h>
#include <math.h>
#include <cstddef>

// Problem constants
#define LQ   19200          // NL*H*W tokens
#define HH   40
#define WW   120
#define HWp  4800
#define CCh  128
#define NHd  8
#define NLv  4
#define NPt  4
#define RHs  80
#define RWs  240

typedef __attribute__((ext_vector_type(8))) short bf16x8;
typedef __attribute__((ext_vector_type(4))) float f32x4;
typedef __attribute__((address_space(1))) const unsigned int GUI;
typedef __attribute__((address_space(3))) unsigned int LUI;

__device__ inline unsigned short f2bf(float f) {
    unsigned int u = __float_as_uint(f);
    u += 0x7fffu + ((u >> 16) & 1u);        // round-to-nearest-even
    return (unsigned short)(u >> 16);
}
__device__ inline float bf2f(unsigned int lo16) { return __uint_as_float(lo16 << 16); }

// ---------------------------------------------------------------------------
// bf16 MFMA GEMM: Out[M,N] = A[M,K] @ Bw[N,K]^T + bias, opt relu.
// BIAS_ROW: bias indexed by row (weights-as-A transposed trick).
// OMODE: 0 = fp32 out, 1 = bf16 out, 2 = both.
// SMAX: fused softmax over 16-col groups (requires OMODE 0, no relu).
// ---------------------------------------------------------------------------
template<bool BIAS_ROW, bool RELU, int OMODE, bool SMAX>
__global__ __launch_bounds__(256) void gemm_bf16(
    const unsigned short* __restrict__ A,
    const unsigned short* __restrict__ Bw,
    const float* __restrict__ bias,
    float* __restrict__ OutF, unsigned short* __restrict__ OutB,
    int M, int N, int K)
{
    constexpr int BM = 128, BN = 64, BK = 32;
    __shared__ unsigned short As[BM * BK];   // row-major [m][k]
    __shared__ unsigned short Bs[BN * BK];
    const int bm = blockIdx.y * BM, bn = blockIdx.x * BN;
    const int tid = threadIdx.x;
    const int wid = tid >> 6, lane = tid & 63;
    const int wm = (wid & 1) * 64, wn = (wid >> 1) * 32;
    const int lm = lane & 15, lqd = lane >> 4;

    f32x4 acc[4][2] = {};

    const int arow = lane >> 2;          // 0..15 within a 16-row chunk
    const int akc  = (lane & 3) * 8;     // k element offset (16 B granules)
    const unsigned short* aG0 = A  + (size_t)(bm + wid * 32 +      arow) * K + akc;
    const unsigned short* aG1 = A  + (size_t)(bm + wid * 32 + 16 + arow) * K + akc;
    const unsigned short* bG  = Bw + (size_t)(bn + wid * 16 +      arow) * K + akc;
    unsigned short* aL0 = As + wid * 1024 + lane * 8;
    unsigned short* aL1 = As + wid * 1024 + 512 + lane * 8;
    unsigned short* bL  = Bs + wid * 512 + lane * 8;

    for (int k0 = 0; k0 < K; k0 += BK) {
        __builtin_amdgcn_global_load_lds((GUI*)(aG0 + k0), (LUI*)aL0, 16, 0, 0);
        __builtin_amdgcn_global_load_lds((GUI*)(aG1 + k0), (LUI*)aL1, 16, 0, 0);
        __builtin_amdgcn_global_load_lds((GUI*)(bG  + k0), (LUI*)bL,  16, 0, 0);
        __syncthreads();
        bf16x8 a[4], b[2];
        #pragma unroll
        for (int i = 0; i < 4; i++)
            a[i] = *(const bf16x8*)(As + (wm + i * 16 + lm) * BK + lqd * 8);
        #pragma unroll
        for (int j = 0; j < 2; j++)
            b[j] = *(const bf16x8*)(Bs + (wn + j * 16 + lm) * BK + lqd * 8);
        #pragma unroll
        for (int i = 0; i < 4; i++)
            #pragma unroll
            for (int j = 0; j < 2; j++)
                acc[i][j] = __builtin_amdgcn_mfma_f32_16x16x32_bf16(a[i], b[j], acc[i][j], 0, 0, 0);
        __syncthreads();
    }

    #pragma unroll
    for (int i = 0; i < 4; i++) {
        int row0 = bm + wm + i * 16 + lqd * 4;
        #pragma unroll
        for (int j = 0; j < 2; j++) {
            int col = bn + wn + j * 16 + lm;
            if constexpr (SMAX) {
                float bc = bias[col];
                #pragma unroll
                for (int r = 0; r < 4; r++) {
                    float v = acc[i][j][r] + bc;
                    float m = v;
                    #pragma unroll
                    for (int msk = 1; msk < 16; msk <<= 1)
                        m = fmaxf(m, __shfl_xor(m, msk));
                    float e = __expf(v - m);
                    float s = e;
                    #pragma unroll
                    for (int msk = 1; msk < 16; msk <<= 1)
                        s += __shfl_xor(s, msk);
                    OutF[(size_t)(row0 + r) * N + col] = e / s;
                }
            } else {
                float bc = BIAS_ROW ? 0.f : bias[col];
                #pragma unroll
                for (int r = 0; r < 4; r++) {
                    int row = row0 + r;
                    float v = acc[i][j][r] + (BIAS_ROW ? bias[row] : bc);
                    if (RELU) v = fmaxf(v, 0.f);
                    size_t o = (size_t)row * N + col;
                    if (OMODE == 0) OutF[o] = v;
                    else if (OMODE == 1) OutB[o] = f2bf(v);
                    else { OutF[o] = v; OutB[o] = f2bf(v); }
                }
            }
        }
    }
}

// ---------------------------------------------------------------------------
// Implicit-GEMM 3x3 conv from padded NHWC bf16 input, tap-major weights.
// MODE 0: dconv  — X:(4,82,242,128), stride 2, M=19200 rows=(n,oh,ow),
//                  out: src fp32 + srcb bf16 (LQ,128) row-major, relu.
// MODE 1: uconv  — X:(82,242,128), stride 1, M=19200 rows=(y,x),
//                  out: d_out fp32 (128,19200) via LDS-transposed store, relu.
// Wp: [128][9*128] with k = tap*128+cin. K=1152, BK=32 (36 chunks).
// ---------------------------------------------------------------------------
template<int MODE>
__global__ __launch_bounds__(256) void conv3x3_gemm(
    const unsigned short* __restrict__ X,
    const unsigned short* __restrict__ Wp,
    const float* __restrict__ bias,
    float* __restrict__ OutF, unsigned short* __restrict__ OutB)
{
    constexpr int BM = 128, BN = 64, BK = 32;
    constexpr int SMEM = (MODE == 1) ? 33792 : 12288;
    __shared__ __align__(16) unsigned char smem[SMEM];
    unsigned short* As = (unsigned short*)smem;            // 128*32
    unsigned short* Bs = (unsigned short*)(smem + 8192);   // 64*32
    const int bm = blockIdx.y * BM, bn = blockIdx.x * BN;
    const int tid = threadIdx.x;
    const int wid = tid >> 6, lane = tid & 63;
    const int wm = (wid & 1) * 64, wn = (wid >> 1) * 32;
    const int lm = lane & 15, lqd = lane >> 4;

    f32x4 acc[4][2] = {};

    const int arow = lane >> 2;
    const int akc  = (lane & 3) * 8;
    // per-lane row decode for the two staged A rows
    const int r0 = bm + wid * 32 + arow;
    const int r1 = r0 + 16;
    size_t bA0, bA1;
    if (MODE == 0) {
        int n0 = r0 / HWp, rem0 = r0 % HWp, oh0 = rem0 / WW, ow0 = rem0 % WW;
        int n1 = r1 / HWp, rem1 = r1 % HWp, oh1 = rem1 / WW, ow1 = rem1 % WW;
        bA0 = ((size_t)(n0 * 82 + oh0 * 2) * 242 + ow0 * 2) * 128;
        bA1 = ((size_t)(n1 * 82 + oh1 * 2) * 242 + ow1 * 2) * 128;
    } else {
        int y0 = r0 / RWs, x0 = r0 % RWs;
        int y1 = r1 / RWs, x1 = r1 % RWs;
        bA0 = ((size_t)y0 * 242 + x0) * 128;
        bA1 = ((size_t)y1 * 242 + x1) * 128;
    }
    const unsigned short* bG = Wp + (size_t)(bn + wid * 16 + arow) * 1152 + akc;
    unsigned short* aL0 = As + wid * 1024 + lane * 8;
    unsigned short* aL1 = As + wid * 1024 + 512 + lane * 8;
    unsigned short* bL  = Bs + wid * 512 + lane * 8;

    for (int chunk = 0; chunk < 36; chunk++) {
        int tap = chunk >> 2;
        int cpart = (chunk & 3) << 5;
        int ky = tap / 3, kx = tap % 3;
        int toff = (ky * 242 + kx) * 128 + cpart + akc;
        __builtin_amdgcn_global_load_lds((GUI*)(X + bA0 + toff), (LUI*)aL0, 16, 0, 0);
        __builtin_amdgcn_global_load_lds((GUI*)(X + bA1 + toff), (LUI*)aL1, 16, 0, 0);
        __builtin_amdgcn_global_load_lds((GUI*)(bG + chunk * 32), (LUI*)bL, 16, 0, 0);
        __syncthreads();
        bf16x8 a[4], b[2];
        #pragma unroll
        for (int i = 0; i < 4; i++)
            a[i] = *(const bf16x8*)(As + (wm + i * 16 + lm) * BK + lqd * 8);
        #pragma unroll
        for (int j = 0; j < 2; j++)
            b[j] = *(const bf16x8*)(Bs + (wn + j * 16 + lm) * BK + lqd * 8);
        #pragma unroll
        for (int i = 0; i < 4; i++)
            #pragma unroll
            for (int j = 0; j < 2; j++)
                acc[i][j] = __builtin_amdgcn_mfma_f32_16x16x32_bf16(a[i], b[j], acc[i][j], 0, 0, 0);
        __syncthreads();
    }

    if (MODE == 0) {
        #pragma unroll
        for (int i = 0; i < 4; i++) {
            int row0 = bm + wm + i * 16 + lqd * 4;
            #pragma unroll
            for (int j = 0; j < 2; j++) {
                int col = bn + wn + j * 16 + lm;
                float bc = bias[col];
                #pragma unroll
                for (int r = 0; r < 4; r++) {
                    float v = fmaxf(acc[i][j][r] + bc, 0.f);
                    size_t o = (size_t)(row0 + r) * 128 + col;
                    OutF[o] = v;
                    OutB[o] = f2bf(v);
                }
            }
        }
    } else {
        // stage into LDS as [local_col][local_row] then store coalesced
        float* Ts = (float*)smem;                 // 64 x 132 floats
        #pragma unroll
        for (int i = 0; i < 4; i++) {
            int lr0 = wm + i * 16 + lqd * 4;
            #pragma unroll
            for (int j = 0; j < 2; j++) {
                int lc = wn + j * 16 + lm;
                float bc = bias[bn + lc];
                #pragma unroll
                for (int r = 0; r < 4; r++)
                    Ts[lc * 132 + lr0 + r] = fmaxf(acc[i][j][r] + bc, 0.f);
            }
        }
        __syncthreads();
        for (int f = tid; f < 64 * 32; f += 256) {
            int ch = f >> 5, p4 = (f & 31) << 2;
            float4 v4 = *(const float4*)(Ts + ch * 132 + p4);
            *(float4*)(OutF + (size_t)(bn + ch) * 19200 + bm + p4) = v4;
        }
    }
}

// ---------------------------------------------------------------------------
// fp32 -> bf16 conversion for linear-layer weights (concatenated).
// offsets: W_val 0, W_off 49152, W_attn 147456, W_out 196608, W_ff1 245760,
// W_ff2 442368, merge 638976 (end 704512)
// ---------------------------------------------------------------------------
__global__ void convert_weights(
    const float* __restrict__ a, const float* __restrict__ b, const float* __restrict__ c,
    const float* __restrict__ d, const float* __restrict__ e, const float* __restrict__ f,
    const float* __restrict__ g, unsigned short* __restrict__ dst)
{
    int idx = blockIdx.x * 256 + threadIdx.x;   // < 704512
    const float* src; int rel;
    if      (idx <  49152) { src = a; rel = idx;          }
    else if (idx < 147456) { src = b; rel = idx - 49152;  }
    else if (idx < 196608) { src = c; rel = idx - 147456; }
    else if (idx < 245760) { src = d; rel = idx - 196608; }
    else if (idx < 442368) { src = e; rel = idx - 245760; }
    else if (idx < 638976) { src = f; rel = idx - 442368; }
    else                   { src = g; rel = idx - 638976; }
    dst[idx] = f2bf(src[rel]);
}

// conv weight (128,128,3,3) fp32 -> bf16 tap-major [cout][tap*128+cin]
__global__ void convert_conv_w(const float* __restrict__ w, unsigned short* __restrict__ o)
{
    int idx = blockIdx.x * 256 + threadIdx.x;   // < 147456
    int cout = idx / 1152, k = idx % 1152;
    int tap = k >> 7, cin = k & 127;
    o[idx] = f2bf(w[(cout * 128 + cin) * 9 + tap]);
}

__global__ void zero_buf(uint4* __restrict__ p, int n4)
{
    int i = blockIdx.x * 256 + threadIdx.x;
    if (i < n4) { uint4 z = {0, 0, 0, 0}; p[i] = z; }
}

// NCHW fp32 (4,128,80,240) -> padded NHWC bf16 (4,82,242,128); one block per (n,y)
__global__ __launch_bounds__(256) void nchw_to_nhwc_pad(
    const float* __restrict__ x, unsigned short* __restrict__ xp)
{
    __shared__ unsigned short t[240 * 132];      // [x][c] padded
    int b = blockIdx.x;                          // 0..319
    int n = b / 80, y = b % 80;
    for (int f = threadIdx.x; f < 128 * 240; f += 256) {
        int c = f / 240, xc = f % 240;
        t[xc * 132 + c] = f2bf(x[(((size_t)n * 128 + c) * 80 + y) * 240 + xc]);
    }
    __syncthreads();
    unsigned short* out = xp + (((size_t)n * 82 + y + 1) * 242 + 1) * 128;
    for (int f = threadIdx.x; f < 240 * 32; f += 256) {
        int xc = f >> 5, c4 = (f & 31) << 2;
        ushort4 v = *(const ushort4*)(t + xc * 132 + c4);
        *(ushort4*)(out + (size_t)xc * 128 + c4) = v;
    }
}

// Sine positional + level embedding (fp32)
__global__ void pos_embed(const float* __restrict__ lvl_emb, float* __restrict__ pos)
{
    unsigned idx = blockIdx.x * 256u + threadIdx.x;   // < LQ*128
    int c = idx & 127;
    int q = idx >> 7;
    int n = q / HWp, pix = q % HWp;
    int h = pix / WW, w = pix % WW;
    int cc = (c < 64) ? c : (c - 64);
    float coord = (c < 64) ? (float)(h + 1) : (float)(w + 1);
    float denom = (c < 64) ? 40.0f : 120.0f;
    float e = coord / (denom + 1e-6f) * 6.283185307179586f;
    float expo = (float)(cc & ~1) * (1.0f / 64.0f);
    float dim_t = powf(10000.0f, expo);
    float p = e / dim_t;
    float v = (cc & 1) ? cosf(p) : sinf(p);
    pos[idx] = v + lvl_emb[n * CCh + c];
}

// q = bf16(src + pos), vectorized x4
__global__ void q_add(const float* __restrict__ src, const float* __restrict__ pos,
                      unsigned short* __restrict__ qb)
{
    unsigned idx = blockIdx.x * 256u + threadIdx.x;   // < LQ*128/4
    float4 s = ((const float4*)src)[idx];
    float4 p = ((const float4*)pos)[idx];
    ushort4 o = { f2bf(s.x + p.x), f2bf(s.y + p.y), f2bf(s.z + p.z), f2bf(s.w + p.w) };
    ((ushort4*)qb)[idx] = o;
}

__device__ inline void fma_u4(float* acc, float w, uint4 v)
{
    acc[0] = fmaf(w, bf2f(v.x & 0xffffu), acc[0]);
    acc[1] = fmaf(w, bf2f(v.x >> 16),     acc[1]);
    acc[2] = fmaf(w, bf2f(v.y & 0xffffu), acc[2]);
    acc[3] = fmaf(w, bf2f(v.y >> 16),     acc[3]);
    acc[4] = fmaf(w, bf2f(v.z & 0xffffu), acc[4]);
    acc[5] = fmaf(w, bf2f(v.z >> 16),     acc[5]);
    acc[6] = fmaf(w, bf2f(v.w & 0xffffu), acc[6]);
    acc[7] = fmaf(w, bf2f(v.w >> 16),     acc[7]);
}
__device__ inline unsigned int pk2(float a, float b)
{ return (unsigned int)f2bf(a) | ((unsigned int)f2bf(b) << 16); }

// MS deformable attention sampling (bf16 values in/out).
__global__ __launch_bounds__(256) void deform_sample(
    const unsigned short* __restrict__ val, const float* __restrict__ off,
    const float* __restrict__ attn, unsigned short* __restrict__ out)
{
    unsigned gid = blockIdx.x * 256u + threadIdx.x;   // < LQ*NH
    int q = gid >> 3, h = gid & 7;
    int pix = q % HWp;
    int qy = pix / WW, qx = pix % WW;
    const float* offp = off + (size_t)q * 256 + h * 32;
    const float* ap   = attn + (size_t)q * 128 + h * 16;
    float acc[16] = {};
    for (int l = 0; l < NLv; l++) {
        const unsigned short* vbase = val + (size_t)l * HWp * CCh + h * 16;
        #pragma unroll
        for (int p = 0; p < NPt; p++) {
            float ox = offp[(l * NPt + p) * 2 + 0];
            float oy = offp[(l * NPt + p) * 2 + 1];
            float a = ap[l * NPt + p];
            float x = (float)qx + ox;
            float y = (float)qy + oy;
            float xf = floorf(x), yf = floorf(y);
            int x0 = (int)xf, y0 = (int)yf;
            float wx1 = x - xf, wy1 = y - yf;
            float wx0 = 1.f - wx1, wy0 = 1.f - wy1;
            #pragma unroll
            for (int dy = 0; dy < 2; dy++) {
                int yc = y0 + dy;
                if ((unsigned)yc >= (unsigned)HH) continue;
                float wy = dy ? wy1 : wy0;
                #pragma unroll
                for (int dx = 0; dx < 2; dx++) {
                    int xc = x0 + dx;
                    if ((unsigned)xc >= (unsigned)WW) continue;
                    float wgt = a * wy * (dx ? wx1 : wx0);
                    const uint4* vp = (const uint4*)(vbase + (size_t)(yc * WW + xc) * CCh);
                    fma_u4(acc,     wgt, vp[0]);
                    fma_u4(acc + 8, wgt, vp[1]);
                }
            }
        }
    }
    uint4 o0 = { pk2(acc[0], acc[1]),  pk2(acc[2], acc[3]),
                 pk2(acc[4], acc[5]),  pk2(acc[6], acc[7]) };
    uint4 o1 = { pk2(acc[8], acc[9]),  pk2(acc[10], acc[11]),
                 pk2(acc[12], acc[13]), pk2(acc[14], acc[15]) };
    uint4* op = (uint4*)(out + (size_t)q * CCh + h * 16);
    op[0] = o0; op[1] = o1;
}

// Residual + LayerNorm, writes fp32 src and bf16 srcb. One wave per row.
__global__ __launch_bounds__(256) void ln_residual(
    float* __restrict__ src, unsigned short* __restrict__ srcb,
    const float* __restrict__ delta,
    const float* __restrict__ g, const float* __restrict__ b)
{
    int row = blockIdx.x * 4 + (threadIdx.x >> 6);
    int lane = threadIdx.x & 63;
    float* sp = src + (size_t)row * CCh;
    unsigned short* sb = srcb + (size_t)row * CCh;
    const float* dp = delta + (size_t)row * CCh;
    float x0 = sp[lane] + dp[lane];
    float x1 = sp[lane + 64] + dp[lane + 64];
    float s = x0 + x1, ss = x0 * x0 + x1 * x1;
    #pragma unroll
    for (int o = 32; o > 0; o >>= 1) {
        s += __shfl_down(s, o);
        ss += __shfl_down(ss, o);
    }
    s = __shfl(s, 0); ss = __shfl(ss, 0);
    float mean = s * (1.0f / 128.0f);
    float var = ss * (1.0f / 128.0f) - mean * mean;
    float inv = rsqrtf(var + 1e-5f);
    float y0 = (x0 - mean) * inv * g[lane] + b[lane];
    float y1 = (x1 - mean) * inv * g[lane + 64] + b[lane + 64];
    sp[lane] = y0;       sp[lane + 64] = y1;
    sb[lane] = f2bf(y0); sb[lane + 64] = f2bf(y1);
}

// Gather src (LQ,128) -> A_merge (4800,512) bf16
__global__ void merge_gather(const float* __restrict__ src, unsigned short* __restrict__ A)
{
    unsigned idx = blockIdx.x * 256u + threadIdx.x;   // < 614400
    unsigned flat = idx * 4;
    int pix = flat >> 9;
    int k = flat & 511;
    int n = k >> 7, c = k & 127;
    float4 s = *(const float4*)(src + ((size_t)(n * HWp + pix)) * CCh + c);
    ushort4 o = { f2bf(s.x), f2bf(s.y), f2bf(s.z), f2bf(s.w) };
    *(ushort4*)(A + flat) = o;
}

// Bilinear 2x upsample -> padded NHWC bf16 (82,242,128), halo zeroed
__global__ void upsample_nhwc(const float* __restrict__ m, unsigned short* __restrict__ up)
{
    unsigned idx = blockIdx.x * 256u + threadIdx.x;   // < 82*242*32
    if (idx >= 82u * 242u * 32u) return;
    int c4 = (idx & 31) << 2;
    int p = idx >> 5;
    int px = p % 242, py = p / 242;
    ushort4 o = {0, 0, 0, 0};
    if (py >= 1 && py <= RHs && px >= 1 && px <= RWs) {
        int y = py - 1, x = px - 1;
        float fy = (y + 0.5f) * 0.5f - 0.5f;
        float fx = (x + 0.5f) * 0.5f - 0.5f;
        float fyf = floorf(fy), fxf = floorf(fx);
        int y0 = (int)fyf, x0 = (int)fxf;
        float wy = fy - fyf, wx = fx - fxf;
        int y0c = max(y0, 0), y1c = min(y0 + 1, HH - 1);
        int x0c = max(x0, 0), x1c = min(x0 + 1, WW - 1);
        unsigned short r[4];
        #pragma unroll
        for (int cc = 0; cc < 4; cc++) {
            const float* mp = m + (size_t)(c4 + cc) * HWp;
            float v00 = mp[y0c * WW + x0c], v01 = mp[y0c * WW + x1c];
            float v10 = mp[y1c * WW + x0c], v11 = mp[y1c * WW + x1c];
            float v = (1.f - wy) * ((1.f - wx) * v00 + wx * v01)
                    + wy * ((1.f - wx) * v10 + wx * v11);
            r[cc] = f2bf(v);
        }
        o.x = r[0]; o.y = r[1]; o.z = r[2]; o.w = r[3];
    }
    *(ushort4*)(up + (size_t)p * 128 + c4) = o;
}

// ---------------------------------------------------------------------------
extern "C" void kernel_launch(void* const* d_in, const int* in_sizes, int n_in,
                              void* d_out, int out_size, void* d_ws, size_t ws_size,
                              hipStream_t stream)
{
    const float* x       = (const float*)d_in[0];
    const float* dconv_w = (const float*)d_in[1];
    const float* dconv_b = (const float*)d_in[2];
    const float* lvl_emb = (const float*)d_in[3];
    const float* W_off   = (const float*)d_in[4];
    const float* b_off   = (const float*)d_in[5];
    const float* W_attn  = (const float*)d_in[6];
    const float* b_attn  = (const float*)d_in[7];
    const float* W_val   = (const float*)d_in[8];
    const float* b_val   = (const float*)d_in[9];
    const float* W_out   = (const float*)d_in[10];
    const float* b_out   = (const float*)d_in[11];
    const float* ln1_g   = (const float*)d_in[12];
    const float* ln1_b   = (const float*)d_in[13];
    const float* W_ff1   = (const float*)d_in[14];
    const float* b_ff1   = (const float*)d_in[15];
    const float* W_ff2   = (const float*)d_in[16];
    const float* b_ff2   = (const float*)d_in[17];
    const float* ln2_g   = (const float*)d_in[18];
    const float* ln2_b   = (const float*)d_in[19];
    const float* merge_w = (const float*)d_in[20];
    const float* merge_b = (const float*)d_in[21];
    const float* uconv_w = (const float*)d_in[22];
    const float* uconv_b = (const float*)d_in[23];

    char* wsb = (char*)d_ws;
    unsigned short* xp       = (unsigned short*)(wsb);               // 20,320,256 B (4,82,242,128)
    unsigned short* up       = (unsigned short*)(wsb + 20320256);    //  5,080,064 B (82,242,128)
    float*          src      = (float*)(wsb + 25400320);             //  9,830,400 B
    unsigned short* srcb     = (unsigned short*)(wsb + 35230720);    //  4,915,200 B
    float*          pos      = (float*)(wsb + 40145920);             //  9,830,400 B
    unsigned short* qb       = (unsigned short*)(wsb + 49976320);    //  4,915,200 B
    unsigned short* valb     = (unsigned short*)(wsb + 54891520);    //  4,915,200 B
    float*          attnb    = (float*)(wsb + 59806720);             //  9,830,400 B
    unsigned short* attnoutb = (unsigned short*)(wsb + 69637120);    //  4,915,200 B
    float*          tmp      = (float*)(wsb + 74552320);             //  9,830,400 B
    unsigned short* ff1b     = (unsigned short*)(wsb + 84382720);    // 19,660,800 B
    unsigned short* wb       = (unsigned short*)(wsb + 104043520);   //  1,409,024 B
    unsigned short* dconv_wb = (unsigned short*)(wsb + 105452544);   //    294,912 B
    unsigned short* uconv_wb = (unsigned short*)(wsb + 105747456);   //    294,912 B (end 106,042,368)
    // aliases (lifetimes disjoint):
    float*          offb     = (float*)xp;       // layers: xp dead after dconv gemm
    unsigned short* merge_in = up;               // before upsample writes up
    float*          mbuf     = (float*)valb;     // after layers
    float* outp = (float*)d_out;

    // bf16 linear weight table offsets (elements)
    unsigned short* W_val_b  = wb;
    unsigned short* W_off_b  = wb + 49152;
    unsigned short* W_attn_b = wb + 147456;
    unsigned short* W_out_b  = wb + 196608;
    unsigned short* W_ff1_b  = wb + 245760;
    unsigned short* W_ff2_b  = wb + 442368;
    unsigned short* merge_wb = wb + 638976;

    // 0) weight conversion + input transpose
    zero_buf<<<4961, 256, 0, stream>>>((uint4*)xp, 1270016);
    convert_weights<<<2752, 256, 0, stream>>>(
        W_val, W_off, W_attn, W_out, W_ff1, W_ff2, merge_w, wb);
    convert_conv_w<<<576, 256, 0, stream>>>(dconv_w, dconv_wb);
    convert_conv_w<<<576, 256, 0, stream>>>(uconv_w, uconv_wb);
    nchw_to_nhwc_pad<<<320, 256, 0, stream>>>(x, xp);

    // 1) downsample conv (implicit GEMM) -> src fp32 + srcb bf16, relu
    conv3x3_gemm<0><<<dim3(2, 150), 256, 0, stream>>>(
        xp, dconv_wb, dconv_b, src, srcb);

    // 2) positional + level embedding
    pos_embed<<<9600, 256, 0, stream>>>(lvl_emb, pos);

    // 3) encoder layers
    for (int i = 0; i < 3; i++) {
        q_add<<<2400, 256, 0, stream>>>(src, pos, qb);
        gemm_bf16<false, false, 1, false><<<dim3(2, 150), 256, 0, stream>>>(
            srcb, W_val_b + (size_t)i * 16384, b_val + i * 128, nullptr, valb, LQ, 128, 128);
        gemm_bf16<false, false, 0, false><<<dim3(4, 150), 256, 0, stream>>>(
            qb, W_off_b + (size_t)i * 32768, b_off + i * 256, offb, nullptr, LQ, 256, 128);
        gemm_bf16<false, false, 0, true><<<dim3(2, 150), 256, 0, stream>>>(
            qb, W_attn_b + (size_t)i * 16384, b_attn + i * 128, attnb, nullptr, LQ, 128, 128);
        deform_sample<<<600, 256, 0, stream>>>(valb, offb, attnb, attnoutb);
        gemm_bf16<false, false, 0, false><<<dim3(2, 150), 256, 0, stream>>>(
            attnoutb, W_out_b + (size_t)i * 16384, b_out + i * 128, tmp, nullptr, LQ, 128, 128);
        ln_residual<<<4800, 256, 0, stream>>>(src, srcb, tmp, ln1_g + i * 128, ln1_b + i * 128);
        gemm_bf16<false, true, 1, false><<<dim3(8, 150), 256, 0, stream>>>(
            srcb, W_ff1_b + (size_t)i * 65536, b_ff1 + i * 512, nullptr, ff1b, LQ, 512, 128);
        gemm_bf16<false, false, 0, false><<<dim3(2, 150), 256, 0, stream>>>(
            ff1b, W_ff2_b + (size_t)i * 65536, b_ff2 + i * 128, tmp, nullptr, LQ, 128, 512);
        ln_residual<<<4800, 256, 0, stream>>>(src, srcb, tmp, ln2_g + i * 128, ln2_b + i * 128);
    }

    // 4) merge 1x1 conv, weights-as-A trick: mbuf[128,4800]
    merge_gather<<<2400, 256, 0, stream>>>(src, merge_in);
    gemm_bf16<true, true, 0, false><<<dim3(75, 1), 256, 0, stream>>>(
        merge_wb, merge_in, merge_b, mbuf, nullptr, 128, 4800, 512);

    // 5) bilinear 2x upsample -> padded NHWC bf16
    upsample_nhwc<<<2482, 256, 0, stream>>>(mbuf, up);

    // 6) uconv (implicit GEMM, transposed store) -> d_out (128,19200), relu
    conv3x3_gemm<1><<<dim3(2, 150), 256, 0, stream>>>(
        up, uconv_wb, uconv_b, outp, nullptr);
}

// Round 4
// 598.719 us; speedup vs baseline: 2.7080x; 1.1199x over previous
//
#include <hip/hip_runtime.h>
#include <math.h>
#include <cstddef>

// Problem constants
#define LQ   19200          // NL*H*W tokens
#define HH   40
#define WW   120
#define HWp  4800
#define CCh  128
#define NHd  8
#define NLv  4
#define NPt  4
#define RHs  80
#define RWs  240

typedef __attribute__((ext_vector_type(8))) short bf16x8;
typedef __attribute__((ext_vector_type(4))) float f32x4;
typedef __attribute__((ext_vector_type(8))) _Float16 h16x8;
typedef __attribute__((ext_vector_type(4))) _Float16 h16x4;
typedef __attribute__((address_space(1))) const unsigned int GUI;
typedef __attribute__((address_space(3))) unsigned int LUI;

__device__ inline unsigned short f2bf(float f) {
    unsigned int u = __float_as_uint(f);
    u += 0x7fffu + ((u >> 16) & 1u);        // round-to-nearest-even
    return (unsigned short)(u >> 16);
}
__device__ inline float bf2f(unsigned int lo16) { return __uint_as_float(lo16 << 16); }

// ---------------------------------------------------------------------------
// bf16 MFMA GEMM: Out[M,N] = A[M,K] @ Bw[N,K]^T + bias, opt relu.
// BIAS_ROW: bias indexed by row (weights-as-A transposed trick).
// OMODE: 0 = fp32 OutF; 1 = bf16 OutB; 2 = both;
//        3 = bf16 OutB in deform plane layout [l][h][4800][16] (val proj);
//        4 = split off/attn: col<256 -> fp16 OutH (stride 256),
//            col>=256 -> softmax16 -> fp16 OutH2 (stride 128). N must be 384.
// ---------------------------------------------------------------------------
template<bool BIAS_ROW, bool RELU, int OMODE>
__global__ __launch_bounds__(256) void gemm_bf16(
    const unsigned short* __restrict__ A,
    const unsigned short* __restrict__ Bw,
    const float* __restrict__ bias,
    float* __restrict__ OutF, unsigned short* __restrict__ OutB,
    _Float16* __restrict__ OutH, _Float16* __restrict__ OutH2,
    int M, int N, int K)
{
    constexpr int BM = 128, BN = 64, BK = 32;
    __shared__ unsigned short As[BM * BK];   // row-major [m][k]
    __shared__ unsigned short Bs[BN * BK];
    const int bm = blockIdx.y * BM, bn = blockIdx.x * BN;
    const int tid = threadIdx.x;
    const int wid = tid >> 6, lane = tid & 63;
    const int wm = (wid & 1) * 64, wn = (wid >> 1) * 32;
    const int lm = lane & 15, lqd = lane >> 4;

    f32x4 acc[4][2] = {};

    const int arow = lane >> 2;          // 0..15 within a 16-row chunk
    const int akc  = (lane & 3) * 8;     // k element offset (16 B granules)
    const unsigned short* aG0 = A  + (size_t)(bm + wid * 32 +      arow) * K + akc;
    const unsigned short* aG1 = A  + (size_t)(bm + wid * 32 + 16 + arow) * K + akc;
    const unsigned short* bG  = Bw + (size_t)(bn + wid * 16 +      arow) * K + akc;
    unsigned short* aL0 = As + wid * 1024 + lane * 8;
    unsigned short* aL1 = As + wid * 1024 + 512 + lane * 8;
    unsigned short* bL  = Bs + wid * 512 + lane * 8;

    for (int k0 = 0; k0 < K; k0 += BK) {
        __builtin_amdgcn_global_load_lds((GUI*)(aG0 + k0), (LUI*)aL0, 16, 0, 0);
        __builtin_amdgcn_global_load_lds((GUI*)(aG1 + k0), (LUI*)aL1, 16, 0, 0);
        __builtin_amdgcn_global_load_lds((GUI*)(bG  + k0), (LUI*)bL,  16, 0, 0);
        __syncthreads();
        bf16x8 a[4], b[2];
        #pragma unroll
        for (int i = 0; i < 4; i++)
            a[i] = *(const bf16x8*)(As + (wm + i * 16 + lm) * BK + lqd * 8);
        #pragma unroll
        for (int j = 0; j < 2; j++)
            b[j] = *(const bf16x8*)(Bs + (wn + j * 16 + lm) * BK + lqd * 8);
        #pragma unroll
        for (int i = 0; i < 4; i++)
            #pragma unroll
            for (int j = 0; j < 2; j++)
                acc[i][j] = __builtin_amdgcn_mfma_f32_16x16x32_bf16(a[i], b[j], acc[i][j], 0, 0, 0);
        __syncthreads();
    }

    #pragma unroll
    for (int i = 0; i < 4; i++) {
        int row0 = bm + wm + i * 16 + lqd * 4;
        #pragma unroll
        for (int j = 0; j < 2; j++) {
            int col = bn + wn + j * 16 + lm;
            if constexpr (OMODE == 4) {
                float bc = bias[col];
                if (col < 256) {
                    #pragma unroll
                    for (int r = 0; r < 4; r++)
                        OutH[(size_t)(row0 + r) * 256 + col] = (_Float16)(acc[i][j][r] + bc);
                } else {
                    #pragma unroll
                    for (int r = 0; r < 4; r++) {
                        float v = acc[i][j][r] + bc;
                        float m = v;
                        #pragma unroll
                        for (int msk = 1; msk < 16; msk <<= 1)
                            m = fmaxf(m, __shfl_xor(m, msk));
                        float e = __expf(v - m);
                        float s = e;
                        #pragma unroll
                        for (int msk = 1; msk < 16; msk <<= 1)
                            s += __shfl_xor(s, msk);
                        OutH2[(size_t)(row0 + r) * 128 + (col - 256)] = (_Float16)(e / s);
                    }
                }
            } else {
                float bc = BIAS_ROW ? 0.f : bias[col];
                #pragma unroll
                for (int r = 0; r < 4; r++) {
                    int row = row0 + r;
                    float v = acc[i][j][r] + (BIAS_ROW ? bias[row] : bc);
                    if (RELU) v = fmaxf(v, 0.f);
                    if constexpr (OMODE == 3) {
                        int plane = (row / HWp) * 8 + (col >> 4);
                        size_t o = ((size_t)plane * HWp + (row % HWp)) * 16 + (col & 15);
                        OutB[o] = f2bf(v);
                    } else {
                        size_t o = (size_t)row * N + col;
                        if (OMODE == 0) OutF[o] = v;
                        else if (OMODE == 1) OutB[o] = f2bf(v);
                        else { OutF[o] = v; OutB[o] = f2bf(v); }
                    }
                }
            }
        }
    }
}

// ---------------------------------------------------------------------------
// Implicit-GEMM 3x3 conv from padded NHWC bf16 input, tap-major weights.
// MODE 0: dconv  — X:(4,82,242,128), stride 2, out: src fp32 + srcb bf16 +
//                  qb = bf16(src+pos), relu.
// MODE 1: uconv  — X:(82,242,128), stride 1, out: d_out fp32 (128,19200)
//                  via LDS-transposed store, relu.
// ---------------------------------------------------------------------------
template<int MODE>
__global__ __launch_bounds__(256) void conv3x3_gemm(
    const unsigned short* __restrict__ X,
    const unsigned short* __restrict__ Wp,
    const float* __restrict__ bias,
    float* __restrict__ OutF, unsigned short* __restrict__ OutB,
    const float* __restrict__ pos, unsigned short* __restrict__ Qb)
{
    constexpr int BM = 128, BN = 64, BK = 32;
    constexpr int SMEM = (MODE == 1) ? 33792 : 12288;
    __shared__ __align__(16) unsigned char smem[SMEM];
    unsigned short* As = (unsigned short*)smem;            // 128*32
    unsigned short* Bs = (unsigned short*)(smem + 8192);   // 64*32
    const int bm = blockIdx.y * BM, bn = blockIdx.x * BN;
    const int tid = threadIdx.x;
    const int wid = tid >> 6, lane = tid & 63;
    const int wm = (wid & 1) * 64, wn = (wid >> 1) * 32;
    const int lm = lane & 15, lqd = lane >> 4;

    f32x4 acc[4][2] = {};

    const int arow = lane >> 2;
    const int akc  = (lane & 3) * 8;
    const int r0 = bm + wid * 32 + arow;
    const int r1 = r0 + 16;
    size_t bA0, bA1;
    if (MODE == 0) {
        int n0 = r0 / HWp, rem0 = r0 % HWp, oh0 = rem0 / WW, ow0 = rem0 % WW;
        int n1 = r1 / HWp, rem1 = r1 % HWp, oh1 = rem1 / WW, ow1 = rem1 % WW;
        bA0 = ((size_t)(n0 * 82 + oh0 * 2) * 242 + ow0 * 2) * 128;
        bA1 = ((size_t)(n1 * 82 + oh1 * 2) * 242 + ow1 * 2) * 128;
    } else {
        int y0 = r0 / RWs, x0 = r0 % RWs;
        int y1 = r1 / RWs, x1 = r1 % RWs;
        bA0 = ((size_t)y0 * 242 + x0) * 128;
        bA1 = ((size_t)y1 * 242 + x1) * 128;
    }
    const unsigned short* bG = Wp + (size_t)(bn + wid * 16 + arow) * 1152 + akc;
    unsigned short* aL0 = As + wid * 1024 + lane * 8;
    unsigned short* aL1 = As + wid * 1024 + 512 + lane * 8;
    unsigned short* bL  = Bs + wid * 512 + lane * 8;

    for (int chunk = 0; chunk < 36; chunk++) {
        int tap = chunk >> 2;
        int cpart = (chunk & 3) << 5;
        int ky = tap / 3, kx = tap % 3;
        int toff = (ky * 242 + kx) * 128 + cpart + akc;
        __builtin_amdgcn_global_load_lds((GUI*)(X + bA0 + toff), (LUI*)aL0, 16, 0, 0);
        __builtin_amdgcn_global_load_lds((GUI*)(X + bA1 + toff), (LUI*)aL1, 16, 0, 0);
        __builtin_amdgcn_global_load_lds((GUI*)(bG + chunk * 32), (LUI*)bL, 16, 0, 0);
        __syncthreads();
        bf16x8 a[4], b[2];
        #pragma unroll
        for (int i = 0; i < 4; i++)
            a[i] = *(const bf16x8*)(As + (wm + i * 16 + lm) * BK + lqd * 8);
        #pragma unroll
        for (int j = 0; j < 2; j++)
            b[j] = *(const bf16x8*)(Bs + (wn + j * 16 + lm) * BK + lqd * 8);
        #pragma unroll
        for (int i = 0; i < 4; i++)
            #pragma unroll
            for (int j = 0; j < 2; j++)
                acc[i][j] = __builtin_amdgcn_mfma_f32_16x16x32_bf16(a[i], b[j], acc[i][j], 0, 0, 0);
        __syncthreads();
    }

    if (MODE == 0) {
        #pragma unroll
        for (int i = 0; i < 4; i++) {
            int row0 = bm + wm + i * 16 + lqd * 4;
            #pragma unroll
            for (int j = 0; j < 2; j++) {
                int col = bn + wn + j * 16 + lm;
                float bc = bias[col];
                #pragma unroll
                for (int r = 0; r < 4; r++) {
                    float v = fmaxf(acc[i][j][r] + bc, 0.f);
                    size_t o = (size_t)(row0 + r) * 128 + col;
                    OutF[o] = v;
                    OutB[o] = f2bf(v);
                    Qb[o] = f2bf(v + pos[o]);
                }
            }
        }
    } else {
        float* Ts = (float*)smem;                 // 64 x 132 floats
        #pragma unroll
        for (int i = 0; i < 4; i++) {
            int lr0 = wm + i * 16 + lqd * 4;
            #pragma unroll
            for (int j = 0; j < 2; j++) {
                int lc = wn + j * 16 + lm;
                float bc = bias[bn + lc];
                #pragma unroll
                for (int r = 0; r < 4; r++)
                    Ts[lc * 132 + lr0 + r] = fmaxf(acc[i][j][r] + bc, 0.f);
            }
        }
        __syncthreads();
        for (int f = tid; f < 64 * 32; f += 256) {
            int ch = f >> 5, p4 = (f & 31) << 2;
            float4 v4 = *(const float4*)(Ts + ch * 132 + p4);
            *(float4*)(OutF + (size_t)(bn + ch) * 19200 + bm + p4) = v4;
        }
    }
}

// ---------------------------------------------------------------------------
// fp32 -> bf16 conversion for linear-layer weights (concatenated).
// offsets: W_val 0, W_out 49152, W_ff1 98304, W_ff2 294912, merge 491520 (end 557056)
// ---------------------------------------------------------------------------
__global__ void convert_weights(
    const float* __restrict__ a, const float* __restrict__ b, const float* __restrict__ c,
    const float* __restrict__ d, const float* __restrict__ e,
    unsigned short* __restrict__ dst)
{
    int idx = blockIdx.x * 256 + threadIdx.x;   // < 557056
    if (idx >= 557056) return;
    const float* src; int rel;
    if      (idx <  49152) { src = a; rel = idx;          }
    else if (idx <  98304) { src = b; rel = idx - 49152;  }
    else if (idx < 294912) { src = c; rel = idx - 98304;  }
    else if (idx < 491520) { src = d; rel = idx - 294912; }
    else                   { src = e; rel = idx - 491520; }
    dst[idx] = f2bf(src[rel]);
}

// Build concatenated [W_off; W_attn] bf16 (3 x 384 x 128) + bias (3 x 384)
__global__ void build_oa(const float* __restrict__ Woff, const float* __restrict__ boff,
                         const float* __restrict__ Wattn, const float* __restrict__ battn,
                         unsigned short* __restrict__ wcat, float* __restrict__ bcat)
{
    int idx = blockIdx.x * 256 + threadIdx.x;   // < 147456 + 1152
    if (idx < 147456) {
        int layer = idx / 49152, r = (idx / 128) % 384, c = idx & 127;
        float v = (r < 256) ? Woff[((size_t)layer * 256 + r) * 128 + c]
                            : Wattn[((size_t)layer * 128 + (r - 256)) * 128 + c];
        wcat[idx] = f2bf(v);
    } else if (idx < 148608) {
        int j = idx - 147456;
        int layer = j / 384, r = j % 384;
        bcat[j] = (r < 256) ? boff[layer * 256 + r] : battn[layer * 128 + (r - 256)];
    }
}

// conv weight (128,128,3,3) fp32 -> bf16 tap-major [cout][tap*128+cin]
__global__ void convert_conv_w(const float* __restrict__ w, unsigned short* __restrict__ o)
{
    int idx = blockIdx.x * 256 + threadIdx.x;   // < 147456
    int cout = idx / 1152, k = idx % 1152;
    int tap = k >> 7, cin = k & 127;
    o[idx] = f2bf(w[(cout * 128 + cin) * 9 + tap]);
}

__global__ void zero_buf(uint4* __restrict__ p, int n4)
{
    int i = blockIdx.x * 256 + threadIdx.x;
    if (i < n4) { uint4 z = {0, 0, 0, 0}; p[i] = z; }
}

// NCHW fp32 (4,128,80,240) -> padded NHWC bf16 (4,82,242,128); one block per (n,y)
__global__ __launch_bounds__(256) void nchw_to_nhwc_pad(
    const float* __restrict__ x, unsigned short* __restrict__ xp)
{
    __shared__ unsigned short t[240 * 132];      // [x][c] padded
    int b = blockIdx.x;                          // 0..319
    int n = b / 80, y = b % 80;
    for (int f = threadIdx.x; f < 128 * 240; f += 256) {
        int c = f / 240, xc = f % 240;
        t[xc * 132 + c] = f2bf(x[(((size_t)n * 128 + c) * 80 + y) * 240 + xc]);
    }
    __syncthreads();
    unsigned short* out = xp + (((size_t)n * 82 + y + 1) * 242 + 1) * 128;
    for (int f = threadIdx.x; f < 240 * 32; f += 256) {
        int xc = f >> 5, c4 = (f & 31) << 2;
        ushort4 v = *(const ushort4*)(t + xc * 132 + c4);
        *(ushort4*)(out + (size_t)xc * 128 + c4) = v;
    }
}

// Sine positional + level embedding (fp32)
__global__ void pos_embed(const float* __restrict__ lvl_emb, float* __restrict__ pos)
{
    unsigned idx = blockIdx.x * 256u + threadIdx.x;   // < LQ*128
    int c = idx & 127;
    int q = idx >> 7;
    int n = q / HWp, pix = q % HWp;
    int h = pix / WW, w = pix % WW;
    int cc = (c < 64) ? c : (c - 64);
    float coord = (c < 64) ? (float)(h + 1) : (float)(w + 1);
    float denom = (c < 64) ? 40.0f : 120.0f;
    float e = coord / (denom + 1e-6f) * 6.283185307179586f;
    float expo = (float)(cc & ~1) * (1.0f / 64.0f);
    float dim_t = powf(10000.0f, expo);
    float p = e / dim_t;
    float v = (cc & 1) ? cosf(p) : sinf(p);
    pos[idx] = v + lvl_emb[n * CCh + c];
}

__device__ inline void fma_u4(float* acc, float w, uint4 v)
{
    acc[0] = fmaf(w, bf2f(v.x & 0xffffu), acc[0]);
    acc[1] = fmaf(w, bf2f(v.x >> 16),     acc[1]);
    acc[2] = fmaf(w, bf2f(v.y & 0xffffu), acc[2]);
    acc[3] = fmaf(w, bf2f(v.y >> 16),     acc[3]);
    acc[4] = fmaf(w, bf2f(v.z & 0xffffu), acc[4]);
    acc[5] = fmaf(w, bf2f(v.z >> 16),     acc[5]);
    acc[6] = fmaf(w, bf2f(v.w & 0xffffu), acc[6]);
    acc[7] = fmaf(w, bf2f(v.w >> 16),     acc[7]);
}
__device__ inline unsigned int pk2(float a, float b)
{ return (unsigned int)f2bf(a) | ((unsigned int)f2bf(b) << 16); }

// ---------------------------------------------------------------------------
// MS deformable attention sampling, one thread per (q, h, l).
// val: plane layout [l][h][4800][16] bf16; off: (LQ,256) fp16 [(h,l,p),2];
// attn: (LQ,128) fp16 softmaxed [(h),(l,p)]; out: (LQ,128) bf16 [(h),(d)].
// Lanes l=0..3 (adjacent) reduce via shfl_xor; lane l==0 writes.
// ---------------------------------------------------------------------------
__global__ __launch_bounds__(256) void deform_sample(
    const unsigned short* __restrict__ val, const _Float16* __restrict__ off,
    const _Float16* __restrict__ attn, unsigned short* __restrict__ out)
{
    unsigned gid = blockIdx.x * 256u + threadIdx.x;   // < LQ*NH*NLv
    int l = gid & 3;
    int h = (gid >> 2) & 7;
    int q = gid >> 5;
    int pix = q % HWp;
    int qy = pix / WW, qx = pix % WW;
    h16x8 ov = *(const h16x8*)(off + (size_t)q * 256 + h * 32 + l * 8);
    h16x4 av = *(const h16x4*)(attn + (size_t)q * 128 + h * 16 + l * 4);
    const unsigned short* vbase = val + (size_t)(l * 8 + h) * HWp * 16;
    float acc[16] = {};
    #pragma unroll
    for (int p = 0; p < NPt; p++) {
        float ox = (float)ov[2 * p], oy = (float)ov[2 * p + 1];
        float a = (float)av[p];
        float x = (float)qx + ox;
        float y = (float)qy + oy;
        float xf = floorf(x), yf = floorf(y);
        int x0 = (int)xf, y0 = (int)yf;
        float wx1 = x - xf, wy1 = y - yf;
        float wx0 = 1.f - wx1, wy0 = 1.f - wy1;
        #pragma unroll
        for (int dy = 0; dy < 2; dy++) {
            int yc = y0 + dy;
            if ((unsigned)yc >= (unsigned)HH) continue;
            float wy = dy ? wy1 : wy0;
            const unsigned short* rowp = vbase + (size_t)(yc * WW) * 16;
            #pragma unroll
            for (int dx = 0; dx < 2; dx++) {
                int xc = x0 + dx;
                if ((unsigned)xc >= (unsigned)WW) continue;
                float wgt = a * wy * (dx ? wx1 : wx0);
                const uint4* vp = (const uint4*)(rowp + xc * 16);
                fma_u4(acc,     wgt, vp[0]);
                fma_u4(acc + 8, wgt, vp[1]);
            }
        }
    }
    #pragma unroll
    for (int i = 0; i < 16; i++) {
        acc[i] += __shfl_xor(acc[i], 1);
        acc[i] += __shfl_xor(acc[i], 2);
    }
    if (l == 0) {
        uint4 o0 = { pk2(acc[0], acc[1]),   pk2(acc[2], acc[3]),
                     pk2(acc[4], acc[5]),   pk2(acc[6], acc[7]) };
        uint4 o1 = { pk2(acc[8], acc[9]),   pk2(acc[10], acc[11]),
                     pk2(acc[12], acc[13]), pk2(acc[14], acc[15]) };
        uint4* op = (uint4*)(out + (size_t)q * CCh + h * 16);
        op[0] = o0; op[1] = o1;
    }
}

// Residual + LayerNorm, writes fp32 src and bf16 srcb (+ optionally qb=src+pos).
template<bool WQ>
__global__ __launch_bounds__(256) void ln_residual(
    float* __restrict__ src, unsigned short* __restrict__ srcb,
    const float* __restrict__ delta,
    const float* __restrict__ g, const float* __restrict__ b,
    const float* __restrict__ pos, unsigned short* __restrict__ qb)
{
    int row = blockIdx.x * 4 + (threadIdx.x >> 6);
    int lane = threadIdx.x & 63;
    float* sp = src + (size_t)row * CCh;
    unsigned short* sb = srcb + (size_t)row * CCh;
    const float* dp = delta + (size_t)row * CCh;
    float x0 = sp[lane] + dp[lane];
    float x1 = sp[lane + 64] + dp[lane + 64];
    float s = x0 + x1, ss = x0 * x0 + x1 * x1;
    #pragma unroll
    for (int o = 32; o > 0; o >>= 1) {
        s += __shfl_down(s, o);
        ss += __shfl_down(ss, o);
    }
    s = __shfl(s, 0); ss = __shfl(ss, 0);
    float mean = s * (1.0f / 128.0f);
    float var = ss * (1.0f / 128.0f) - mean * mean;
    float inv = rsqrtf(var + 1e-5f);
    float y0 = (x0 - mean) * inv * g[lane] + b[lane];
    float y1 = (x1 - mean) * inv * g[lane + 64] + b[lane + 64];
    sp[lane] = y0;       sp[lane + 64] = y1;
    sb[lane] = f2bf(y0); sb[lane + 64] = f2bf(y1);
    if constexpr (WQ) {
        const float* pp = pos + (size_t)row * CCh;
        qb[(size_t)row * CCh + lane]      = f2bf(y0 + pp[lane]);
        qb[(size_t)row * CCh + lane + 64] = f2bf(y1 + pp[lane + 64]);
    }
}

// Gather src (LQ,128) -> A_merge (4800,512) bf16
__global__ void merge_gather(const float* __restrict__ src, unsigned short* __restrict__ A)
{
    unsigned idx = blockIdx.x * 256u + threadIdx.x;   // < 614400
    unsigned flat = idx * 4;
    int pix = flat >> 9;
    int k = flat & 511;
    int n = k >> 7, c = k & 127;
    float4 s = *(const float4*)(src + ((size_t)(n * HWp + pix)) * CCh + c);
    ushort4 o = { f2bf(s.x), f2bf(s.y), f2bf(s.z), f2bf(s.w) };
    *(ushort4*)(A + flat) = o;
}

// Bilinear 2x upsample -> padded NHWC bf16 (82,242,128), halo zeroed
__global__ void upsample_nhwc(const float* __restrict__ m, unsigned short* __restrict__ up)
{
    unsigned idx = blockIdx.x * 256u + threadIdx.x;   // < 82*242*32
    if (idx >= 82u * 242u * 32u) return;
    int c4 = (idx & 31) << 2;
    int p = idx >> 5;
    int px = p % 242, py = p / 242;
    ushort4 o = {0, 0, 0, 0};
    if (py >= 1 && py <= RHs && px >= 1 && px <= RWs) {
        int y = py - 1, x = px - 1;
        float fy = (y + 0.5f) * 0.5f - 0.5f;
        float fx = (x + 0.5f) * 0.5f - 0.5f;
        float fyf = floorf(fy), fxf = floorf(fx);
        int y0 = (int)fyf, x0 = (int)fxf;
        float wy = fy - fyf, wx = fx - fxf;
        int y0c = max(y0, 0), y1c = min(y0 + 1, HH - 1);
        int x0c = max(x0, 0), x1c = min(x0 + 1, WW - 1);
        unsigned short r[4];
        #pragma unroll
        for (int cc = 0; cc < 4; cc++) {
            const float* mp = m + (size_t)(c4 + cc) * HWp;
            float v00 = mp[y0c * WW + x0c], v01 = mp[y0c * WW + x1c];
            float v10 = mp[y1c * WW + x0c], v11 = mp[y1c * WW + x1c];
            float v = (1.f - wy) * ((1.f - wx) * v00 + wx * v01)
                    + wy * ((1.f - wx) * v10 + wx * v11);
            r[cc] = f2bf(v);
        }
        o.x = r[0]; o.y = r[1]; o.z = r[2]; o.w = r[3];
    }
    *(ushort4*)(up + (size_t)p * 128 + c4) = o;
}

// ---------------------------------------------------------------------------
extern "C" void kernel_launch(void* const* d_in, const int* in_sizes, int n_in,
                              void* d_out, int out_size, void* d_ws, size_t ws_size,
                              hipStream_t stream)
{
    const float* x       = (const float*)d_in[0];
    const float* dconv_w = (const float*)d_in[1];
    const float* dconv_b = (const float*)d_in[2];
    const float* lvl_emb = (const float*)d_in[3];
    const float* W_off   = (const float*)d_in[4];
    const float* b_off   = (const float*)d_in[5];
    const float* W_attn  = (const float*)d_in[6];
    const float* b_attn  = (const float*)d_in[7];
    const float* W_val   = (const float*)d_in[8];
    const float* b_val   = (const float*)d_in[9];
    const float* W_out   = (const float*)d_in[10];
    const float* b_out   = (const float*)d_in[11];
    const float* ln1_g   = (const float*)d_in[12];
    const float* ln1_b   = (const float*)d_in[13];
    const float* W_ff1   = (const float*)d_in[14];
    const float* b_ff1   = (const float*)d_in[15];
    const float* W_ff2   = (const float*)d_in[16];
    const float* b_ff2   = (const float*)d_in[17];
    const float* ln2_g   = (const float*)d_in[18];
    const float* ln2_b   = (const float*)d_in[19];
    const float* merge_w = (const float*)d_in[20];
    const float* merge_b = (const float*)d_in[21];
    const float* uconv_w = (const float*)d_in[22];
    const float* uconv_b = (const float*)d_in[23];

    char* wsb = (char*)d_ws;
    unsigned short* xp       = (unsigned short*)(wsb);               // 20,320,256 B (4,82,242,128)
    unsigned short* up       = (unsigned short*)(wsb + 20320256);    //  5,080,064 B (82,242,128)
    float*          src      = (float*)(wsb + 25400320);             //  9,830,400 B
    unsigned short* srcb     = (unsigned short*)(wsb + 35230720);    //  4,915,200 B
    float*          pos      = (float*)(wsb + 40145920);             //  9,830,400 B
    unsigned short* qb       = (unsigned short*)(wsb + 49976320);    //  4,915,200 B
    unsigned short* valb     = (unsigned short*)(wsb + 54891520);    //  4,915,200 B
    _Float16*       attnh    = (_Float16*)(wsb + 59806720);          //  4,915,200 B
    unsigned short* attnoutb = (unsigned short*)(wsb + 69637120);    //  4,915,200 B
    float*          tmp      = (float*)(wsb + 74552320);             //  9,830,400 B
    unsigned short* ff1b     = (unsigned short*)(wsb + 84382720);    // 19,660,800 B
    unsigned short* wb       = (unsigned short*)(wsb + 104043520);   //  1,114,112 B
    unsigned short* dconv_wb = (unsigned short*)(wsb + 105452544);   //    294,912 B
    unsigned short* uconv_wb = (unsigned short*)(wsb + 105747456);   //    294,912 B
    unsigned short* wcat     = (unsigned short*)(wsb + 106042368);   //    294,912 B
    float*          bcat     = (float*)(wsb + 106337280);            //      4,608 B (end 106,341,888)
    // aliases (lifetimes disjoint):
    _Float16*       offh     = (_Float16*)xp;    // layers: xp dead after dconv gemm (9.83 MB)
    unsigned short* merge_in = up;               // before upsample writes up
    float*          mbuf     = (float*)valb;     // after layers
    float* outp = (float*)d_out;

    // bf16 linear weight table offsets (elements)
    unsigned short* W_val_b  = wb;
    unsigned short* W_out_b  = wb + 49152;
    unsigned short* W_ff1_b  = wb + 98304;
    unsigned short* W_ff2_b  = wb + 294912;
    unsigned short* merge_wb = wb + 491520;

    // 0) weight conversion + input transpose + positional embedding
    zero_buf<<<4961, 256, 0, stream>>>((uint4*)xp, 1270016);
    convert_weights<<<2176, 256, 0, stream>>>(W_val, W_out, W_ff1, W_ff2, merge_w, wb);
    build_oa<<<581, 256, 0, stream>>>(W_off, b_off, W_attn, b_attn, wcat, bcat);
    convert_conv_w<<<576, 256, 0, stream>>>(dconv_w, dconv_wb);
    convert_conv_w<<<576, 256, 0, stream>>>(uconv_w, uconv_wb);
    nchw_to_nhwc_pad<<<320, 256, 0, stream>>>(x, xp);
    pos_embed<<<9600, 256, 0, stream>>>(lvl_emb, pos);

    // 1) downsample conv (implicit GEMM) -> src fp32 + srcb bf16 + qb, relu
    conv3x3_gemm<0><<<dim3(2, 150), 256, 0, stream>>>(
        xp, dconv_wb, dconv_b, src, srcb, pos, qb);

    // 2) encoder layers
    for (int i = 0; i < 3; i++) {
        gemm_bf16<false, false, 4><<<dim3(6, 150), 256, 0, stream>>>(
            qb, wcat + (size_t)i * 49152, bcat + i * 384,
            nullptr, nullptr, offh, attnh, LQ, 384, 128);
        gemm_bf16<false, false, 3><<<dim3(2, 150), 256, 0, stream>>>(
            srcb, W_val_b + (size_t)i * 16384, b_val + i * 128,
            nullptr, valb, nullptr, nullptr, LQ, 128, 128);
        deform_sample<<<2400, 256, 0, stream>>>(valb, offh, attnh, attnoutb);
        gemm_bf16<false, false, 0><<<dim3(2, 150), 256, 0, stream>>>(
            attnoutb, W_out_b + (size_t)i * 16384, b_out + i * 128,
            tmp, nullptr, nullptr, nullptr, LQ, 128, 128);
        ln_residual<false><<<4800, 256, 0, stream>>>(
            src, srcb, tmp, ln1_g + i * 128, ln1_b + i * 128, nullptr, nullptr);
        gemm_bf16<false, true, 1><<<dim3(8, 150), 256, 0, stream>>>(
            srcb, W_ff1_b + (size_t)i * 65536, b_ff1 + i * 512,
            nullptr, ff1b, nullptr, nullptr, LQ, 512, 128);
        gemm_bf16<false, false, 0><<<dim3(2, 150), 256, 0, stream>>>(
            ff1b, W_ff2_b + (size_t)i * 65536, b_ff2 + i * 128,
            tmp, nullptr, nullptr, nullptr, LQ, 128, 512);
        ln_residual<true><<<4800, 256, 0, stream>>>(
            src, srcb, tmp, ln2_g + i * 128, ln2_b + i * 128, pos, qb);
    }

    // 3) merge 1x1 conv, weights-as-A trick: mbuf[128,4800]
    merge_gather<<<2400, 256, 0, stream>>>(src, merge_in);
    gemm_bf16<true, true, 0><<<dim3(75, 1), 256, 0, stream>>>(
        merge_wb, merge_in, merge_b, mbuf, nullptr, nullptr, nullptr, 128, 4800, 512);

    // 4) bilinear 2x upsample -> padded NHWC bf16
    upsample_nhwc<<<2482, 256, 0, stream>>>(mbuf, up);

    // 5) uconv (implicit GEMM, transposed store) -> d_out (128,19200), relu
    conv3x3_gemm<1><<<dim3(2, 150), 256, 0, stream>>>(
        up, uconv_wb, uconv_b, outp, nullptr, nullptr, nullptr);
}

// Round 5
// 560.970 us; speedup vs baseline: 2.8903x; 1.0673x over previous
//
#include <hip/hip_runtime.h>
#include <math.h>
#include <cstddef>

// Problem constants
#define LQ   19200          // NL*H*W tokens
#define HH   40
#define WW   120
#define HWp  4800
#define CCh  128
#define NHd  8
#define NLv  4
#define NPt  4
#define RHs  80
#define RWs  240

typedef __attribute__((ext_vector_type(8))) short bf16x8;
typedef __attribute__((ext_vector_type(4))) float f32x4;
typedef __attribute__((ext_vector_type(8))) _Float16 h16x8;
typedef __attribute__((ext_vector_type(4))) _Float16 h16x4;
typedef __attribute__((address_space(1))) const unsigned int GUI;
typedef __attribute__((address_space(3))) unsigned int LUI;

__device__ inline unsigned short f2bf(float f) {
    unsigned int u = __float_as_uint(f);
    u += 0x7fffu + ((u >> 16) & 1u);        // round-to-nearest-even
    return (unsigned short)(u >> 16);
}
__device__ inline float bf2f(unsigned int lo16) { return __uint_as_float(lo16 << 16); }

// ---------------------------------------------------------------------------
// bf16 MFMA GEMM: Out[M,N] = A[M,K] @ Bw[N,K]^T + bias, opt relu.
// BIAS_ROW: bias indexed by row (weights-as-A transposed trick).
// OMODE: 0 = fp32 OutF; 1 = bf16 OutB; 2 = both;
//        3 = bf16 OutB in deform plane layout [l][h][4800][16] (val proj);
//        4 = split off/attn: col<256 -> fp16 OutH (stride 256),
//            col>=256 -> softmax16 -> fp16 OutH2 (stride 128). N must be 384.
// ---------------------------------------------------------------------------
template<bool BIAS_ROW, bool RELU, int OMODE>
__global__ __launch_bounds__(256) void gemm_bf16(
    const unsigned short* __restrict__ A,
    const unsigned short* __restrict__ Bw,
    const float* __restrict__ bias,
    float* __restrict__ OutF, unsigned short* __restrict__ OutB,
    _Float16* __restrict__ OutH, _Float16* __restrict__ OutH2,
    int M, int N, int K)
{
    constexpr int BM = 128, BN = 64, BK = 32;
    __shared__ unsigned short As[BM * BK];   // row-major [m][k]
    __shared__ unsigned short Bs[BN * BK];
    const int bm = blockIdx.y * BM, bn = blockIdx.x * BN;
    const int tid = threadIdx.x;
    const int wid = tid >> 6, lane = tid & 63;
    const int wm = (wid & 1) * 64, wn = (wid >> 1) * 32;
    const int lm = lane & 15, lqd = lane >> 4;

    f32x4 acc[4][2] = {};

    const int arow = lane >> 2;          // 0..15 within a 16-row chunk
    const int akc  = (lane & 3) * 8;     // k element offset (16 B granules)
    const unsigned short* aG0 = A  + (size_t)(bm + wid * 32 +      arow) * K + akc;
    const unsigned short* aG1 = A  + (size_t)(bm + wid * 32 + 16 + arow) * K + akc;
    const unsigned short* bG  = Bw + (size_t)(bn + wid * 16 +      arow) * K + akc;
    unsigned short* aL0 = As + wid * 1024 + lane * 8;
    unsigned short* aL1 = As + wid * 1024 + 512 + lane * 8;
    unsigned short* bL  = Bs + wid * 512 + lane * 8;

    for (int k0 = 0; k0 < K; k0 += BK) {
        __builtin_amdgcn_global_load_lds((GUI*)(aG0 + k0), (LUI*)aL0, 16, 0, 0);
        __builtin_amdgcn_global_load_lds((GUI*)(aG1 + k0), (LUI*)aL1, 16, 0, 0);
        __builtin_amdgcn_global_load_lds((GUI*)(bG  + k0), (LUI*)bL,  16, 0, 0);
        __syncthreads();
        bf16x8 a[4], b[2];
        #pragma unroll
        for (int i = 0; i < 4; i++)
            a[i] = *(const bf16x8*)(As + (wm + i * 16 + lm) * BK + lqd * 8);
        #pragma unroll
        for (int j = 0; j < 2; j++)
            b[j] = *(const bf16x8*)(Bs + (wn + j * 16 + lm) * BK + lqd * 8);
        #pragma unroll
        for (int i = 0; i < 4; i++)
            #pragma unroll
            for (int j = 0; j < 2; j++)
                acc[i][j] = __builtin_amdgcn_mfma_f32_16x16x32_bf16(a[i], b[j], acc[i][j], 0, 0, 0);
        __syncthreads();
    }

    #pragma unroll
    for (int i = 0; i < 4; i++) {
        int row0 = bm + wm + i * 16 + lqd * 4;
        #pragma unroll
        for (int j = 0; j < 2; j++) {
            int col = bn + wn + j * 16 + lm;
            if constexpr (OMODE == 4) {
                float bc = bias[col];
                if (col < 256) {
                    #pragma unroll
                    for (int r = 0; r < 4; r++)
                        OutH[(size_t)(row0 + r) * 256 + col] = (_Float16)(acc[i][j][r] + bc);
                } else {
                    #pragma unroll
                    for (int r = 0; r < 4; r++) {
                        float v = acc[i][j][r] + bc;
                        float m = v;
                        #pragma unroll
                        for (int msk = 1; msk < 16; msk <<= 1)
                            m = fmaxf(m, __shfl_xor(m, msk));
                        float e = __expf(v - m);
                        float s = e;
                        #pragma unroll
                        for (int msk = 1; msk < 16; msk <<= 1)
                            s += __shfl_xor(s, msk);
                        OutH2[(size_t)(row0 + r) * 128 + (col - 256)] = (_Float16)(e / s);
                    }
                }
            } else {
                float bc = BIAS_ROW ? 0.f : bias[col];
                #pragma unroll
                for (int r = 0; r < 4; r++) {
                    int row = row0 + r;
                    float v = acc[i][j][r] + (BIAS_ROW ? bias[row] : bc);
                    if (RELU) v = fmaxf(v, 0.f);
                    if constexpr (OMODE == 3) {
                        int plane = (row / HWp) * 8 + (col >> 4);
                        size_t o = ((size_t)plane * HWp + (row % HWp)) * 16 + (col & 15);
                        OutB[o] = f2bf(v);
                    } else {
                        size_t o = (size_t)row * N + col;
                        if (OMODE == 0) OutF[o] = v;
                        else if (OMODE == 1) OutB[o] = f2bf(v);
                        else { OutF[o] = v; OutB[o] = f2bf(v); }
                    }
                }
            }
        }
    }
}

// ---------------------------------------------------------------------------
// LN-fused GEMM: delta[M,128] = A[M,K] @ Bw[128,K]^T + bias; then
// y = LayerNorm(srcF + delta) * g + b2; writes srcF(fp32), srcB(bf16),
// and (WQ) qb = bf16(y + pos). BM=64, BN=128 (block holds full rows).
// ---------------------------------------------------------------------------
template<bool WQ>
__global__ __launch_bounds__(256) void gemm_ln(
    const unsigned short* __restrict__ A,
    const unsigned short* __restrict__ Bw,
    const float* __restrict__ bias,
    const float* __restrict__ g, const float* __restrict__ b2,
    float* __restrict__ srcF, unsigned short* __restrict__ srcB,
    const float* __restrict__ pos, unsigned short* __restrict__ qb,
    int K)
{
    __shared__ __align__(16) unsigned char smem[12288];
    unsigned short* As = (unsigned short*)smem;            // 64 x 32
    unsigned short* Bs = (unsigned short*)(smem + 4096);   // 128 x 32
    const int bm = blockIdx.x * 64;
    const int tid = threadIdx.x;
    const int wid = tid >> 6, lane = tid & 63;
    const int wm = (wid & 1) * 32, wn = (wid >> 1) * 64;
    const int lm = lane & 15, lqd = lane >> 4;

    f32x4 acc[2][4] = {};

    const int srow = lane >> 2;
    const int skc  = (lane & 3) * 8;
    const unsigned short* aG  = A  + (size_t)(bm + wid * 16 + srow) * K + skc;
    const unsigned short* bG0 = Bw + (size_t)(wid * 16 + srow) * K + skc;
    const unsigned short* bG1 = Bw + (size_t)(64 + wid * 16 + srow) * K + skc;
    unsigned short* aL  = As + wid * 512 + lane * 8;
    unsigned short* bL0 = Bs + wid * 512 + lane * 8;
    unsigned short* bL1 = Bs + 2048 + wid * 512 + lane * 8;

    for (int k0 = 0; k0 < K; k0 += 32) {
        __builtin_amdgcn_global_load_lds((GUI*)(aG  + k0), (LUI*)aL,  16, 0, 0);
        __builtin_amdgcn_global_load_lds((GUI*)(bG0 + k0), (LUI*)bL0, 16, 0, 0);
        __builtin_amdgcn_global_load_lds((GUI*)(bG1 + k0), (LUI*)bL1, 16, 0, 0);
        __syncthreads();
        bf16x8 a[2], b[4];
        #pragma unroll
        for (int i = 0; i < 2; i++)
            a[i] = *(const bf16x8*)(As + (wm + i * 16 + lm) * 32 + lqd * 8);
        #pragma unroll
        for (int j = 0; j < 4; j++)
            b[j] = *(const bf16x8*)(Bs + (wn + j * 16 + lm) * 32 + lqd * 8);
        #pragma unroll
        for (int i = 0; i < 2; i++)
            #pragma unroll
            for (int j = 0; j < 4; j++)
                acc[i][j] = __builtin_amdgcn_mfma_f32_16x16x32_bf16(a[i], b[j], acc[i][j], 0, 0, 0);
        __syncthreads();
    }

    // z = delta + src (fp32 residual)
    float z[2][4][4];
    #pragma unroll
    for (int i = 0; i < 2; i++) {
        #pragma unroll
        for (int j = 0; j < 4; j++) {
            int col = wn + j * 16 + lm;
            float bc = bias[col];
            #pragma unroll
            for (int r = 0; r < 4; r++) {
                int row = bm + wm + i * 16 + lqd * 4 + r;
                z[i][j][r] = acc[i][j][r] + bc + srcF[(size_t)row * 128 + col];
            }
        }
    }

    // row-wise reduction: 64 cols per wave via shfl, cross-wave via LDS
    float* red = (float*)smem;      // [half][ sums(64) | sq(64) ] = 256 floats
    #pragma unroll
    for (int i = 0; i < 2; i++) {
        #pragma unroll
        for (int r = 0; r < 4; r++) {
            float s = z[i][0][r] + z[i][1][r] + z[i][2][r] + z[i][3][r];
            float q = z[i][0][r] * z[i][0][r] + z[i][1][r] * z[i][1][r]
                    + z[i][2][r] * z[i][2][r] + z[i][3][r] * z[i][3][r];
            #pragma unroll
            for (int msk = 1; msk < 16; msk <<= 1) {
                s += __shfl_xor(s, msk);
                q += __shfl_xor(q, msk);
            }
            if (lm == 0) {
                int rl = wm + i * 16 + lqd * 4 + r;
                red[(wid >> 1) * 128 + rl] = s;
                red[(wid >> 1) * 128 + 64 + rl] = q;
            }
        }
    }
    __syncthreads();

    float mean[2][4], inv[2][4];
    #pragma unroll
    for (int i = 0; i < 2; i++) {
        #pragma unroll
        for (int r = 0; r < 4; r++) {
            int rl = wm + i * 16 + lqd * 4 + r;
            float s = red[rl] + red[128 + rl];
            float q = red[64 + rl] + red[192 + rl];
            float m = s * (1.0f / 128.0f);
            float v = q * (1.0f / 128.0f) - m * m;
            mean[i][r] = m;
            inv[i][r] = rsqrtf(v + 1e-5f);
        }
    }

    #pragma unroll
    for (int i = 0; i < 2; i++) {
        #pragma unroll
        for (int j = 0; j < 4; j++) {
            int col = wn + j * 16 + lm;
            float gc = g[col], bc2 = b2[col];
            #pragma unroll
            for (int r = 0; r < 4; r++) {
                int row = bm + wm + i * 16 + lqd * 4 + r;
                float y = (z[i][j][r] - mean[i][r]) * inv[i][r] * gc + bc2;
                size_t o = (size_t)row * 128 + col;
                srcF[o] = y;
                srcB[o] = f2bf(y);
                if constexpr (WQ) qb[o] = f2bf(y + pos[o]);
            }
        }
    }
}

// ---------------------------------------------------------------------------
// Implicit-GEMM 3x3 conv from padded NHWC bf16 input, tap-major weights.
// MODE 0: dconv  — X:(4,82,242,128), stride 2, out: src fp32 + srcb bf16 +
//                  qb = bf16(src+pos), relu.
// MODE 1: uconv  — X:(82,242,128), stride 1, out: d_out fp32 (128,19200)
//                  via LDS-transposed store, relu.
// ---------------------------------------------------------------------------
template<int MODE>
__global__ __launch_bounds__(256) void conv3x3_gemm(
    const unsigned short* __restrict__ X,
    const unsigned short* __restrict__ Wp,
    const float* __restrict__ bias,
    float* __restrict__ OutF, unsigned short* __restrict__ OutB,
    const float* __restrict__ pos, unsigned short* __restrict__ Qb)
{
    constexpr int BM = 128, BN = 64, BK = 32;
    constexpr int SMEM = (MODE == 1) ? 33792 : 12288;
    __shared__ __align__(16) unsigned char smem[SMEM];
    unsigned short* As = (unsigned short*)smem;            // 128*32
    unsigned short* Bs = (unsigned short*)(smem + 8192);   // 64*32
    const int bm = blockIdx.y * BM, bn = blockIdx.x * BN;
    const int tid = threadIdx.x;
    const int wid = tid >> 6, lane = tid & 63;
    const int wm = (wid & 1) * 64, wn = (wid >> 1) * 32;
    const int lm = lane & 15, lqd = lane >> 4;

    f32x4 acc[4][2] = {};

    const int arow = lane >> 2;
    const int akc  = (lane & 3) * 8;
    const int r0 = bm + wid * 32 + arow;
    const int r1 = r0 + 16;
    size_t bA0, bA1;
    if (MODE == 0) {
        int n0 = r0 / HWp, rem0 = r0 % HWp, oh0 = rem0 / WW, ow0 = rem0 % WW;
        int n1 = r1 / HWp, rem1 = r1 % HWp, oh1 = rem1 / WW, ow1 = rem1 % WW;
        bA0 = ((size_t)(n0 * 82 + oh0 * 2) * 242 + ow0 * 2) * 128;
        bA1 = ((size_t)(n1 * 82 + oh1 * 2) * 242 + ow1 * 2) * 128;
    } else {
        int y0 = r0 / RWs, x0 = r0 % RWs;
        int y1 = r1 / RWs, x1 = r1 % RWs;
        bA0 = ((size_t)y0 * 242 + x0) * 128;
        bA1 = ((size_t)y1 * 242 + x1) * 128;
    }
    const unsigned short* bG = Wp + (size_t)(bn + wid * 16 + arow) * 1152 + akc;
    unsigned short* aL0 = As + wid * 1024 + lane * 8;
    unsigned short* aL1 = As + wid * 1024 + 512 + lane * 8;
    unsigned short* bL  = Bs + wid * 512 + lane * 8;

    for (int chunk = 0; chunk < 36; chunk++) {
        int tap = chunk >> 2;
        int cpart = (chunk & 3) << 5;
        int ky = tap / 3, kx = tap % 3;
        int toff = (ky * 242 + kx) * 128 + cpart + akc;
        __builtin_amdgcn_global_load_lds((GUI*)(X + bA0 + toff), (LUI*)aL0, 16, 0, 0);
        __builtin_amdgcn_global_load_lds((GUI*)(X + bA1 + toff), (LUI*)aL1, 16, 0, 0);
        __builtin_amdgcn_global_load_lds((GUI*)(bG + chunk * 32), (LUI*)bL, 16, 0, 0);
        __syncthreads();
        bf16x8 a[4], b[2];
        #pragma unroll
        for (int i = 0; i < 4; i++)
            a[i] = *(const bf16x8*)(As + (wm + i * 16 + lm) * BK + lqd * 8);
        #pragma unroll
        for (int j = 0; j < 2; j++)
            b[j] = *(const bf16x8*)(Bs + (wn + j * 16 + lm) * BK + lqd * 8);
        #pragma unroll
        for (int i = 0; i < 4; i++)
            #pragma unroll
            for (int j = 0; j < 2; j++)
                acc[i][j] = __builtin_amdgcn_mfma_f32_16x16x32_bf16(a[i], b[j], acc[i][j], 0, 0, 0);
        __syncthreads();
    }

    if (MODE == 0) {
        #pragma unroll
        for (int i = 0; i < 4; i++) {
            int row0 = bm + wm + i * 16 + lqd * 4;
            #pragma unroll
            for (int j = 0; j < 2; j++) {
                int col = bn + wn + j * 16 + lm;
                float bc = bias[col];
                #pragma unroll
                for (int r = 0; r < 4; r++) {
                    float v = fmaxf(acc[i][j][r] + bc, 0.f);
                    size_t o = (size_t)(row0 + r) * 128 + col;
                    OutF[o] = v;
                    OutB[o] = f2bf(v);
                    Qb[o] = f2bf(v + pos[o]);
                }
            }
        }
    } else {
        float* Ts = (float*)smem;                 // 64 x 132 floats
        #pragma unroll
        for (int i = 0; i < 4; i++) {
            int lr0 = wm + i * 16 + lqd * 4;
            #pragma unroll
            for (int j = 0; j < 2; j++) {
                int lc = wn + j * 16 + lm;
                float bc = bias[bn + lc];
                #pragma unroll
                for (int r = 0; r < 4; r++)
                    Ts[lc * 132 + lr0 + r] = fmaxf(acc[i][j][r] + bc, 0.f);
            }
        }
        __syncthreads();
        for (int f = tid; f < 64 * 32; f += 256) {
            int ch = f >> 5, p4 = (f & 31) << 2;
            float4 v4 = *(const float4*)(Ts + ch * 132 + p4);
            *(float4*)(OutF + (size_t)(bn + ch) * 19200 + bm + p4) = v4;
        }
    }
}

// ---------------------------------------------------------------------------
// fp32 -> bf16 conversion for linear-layer weights (concatenated).
// offsets: W_val 0, W_out 49152, W_ff1 98304, W_ff2 294912, merge 491520 (end 557056)
// ---------------------------------------------------------------------------
__global__ void convert_weights(
    const float* __restrict__ a, const float* __restrict__ b, const float* __restrict__ c,
    const float* __restrict__ d, const float* __restrict__ e,
    unsigned short* __restrict__ dst)
{
    int idx = blockIdx.x * 256 + threadIdx.x;   // < 557056
    if (idx >= 557056) return;
    const float* src; int rel;
    if      (idx <  49152) { src = a; rel = idx;          }
    else if (idx <  98304) { src = b; rel = idx - 49152;  }
    else if (idx < 294912) { src = c; rel = idx - 98304;  }
    else if (idx < 491520) { src = d; rel = idx - 294912; }
    else                   { src = e; rel = idx - 491520; }
    dst[idx] = f2bf(src[rel]);
}

// Build concatenated [W_off; W_attn] bf16 (3 x 384 x 128) + bias (3 x 384)
__global__ void build_oa(const float* __restrict__ Woff, const float* __restrict__ boff,
                         const float* __restrict__ Wattn, const float* __restrict__ battn,
                         unsigned short* __restrict__ wcat, float* __restrict__ bcat)
{
    int idx = blockIdx.x * 256 + threadIdx.x;   // < 147456 + 1152
    if (idx < 147456) {
        int layer = idx / 49152, r = (idx / 128) % 384, c = idx & 127;
        float v = (r < 256) ? Woff[((size_t)layer * 256 + r) * 128 + c]
                            : Wattn[((size_t)layer * 128 + (r - 256)) * 128 + c];
        wcat[idx] = f2bf(v);
    } else if (idx < 148608) {
        int j = idx - 147456;
        int layer = j / 384, r = j % 384;
        bcat[j] = (r < 256) ? boff[layer * 256 + r] : battn[layer * 128 + (r - 256)];
    }
}

// conv weight (128,128,3,3) fp32 -> bf16 tap-major [cout][tap*128+cin]
__global__ void convert_conv_w(const float* __restrict__ w, unsigned short* __restrict__ o)
{
    int idx = blockIdx.x * 256 + threadIdx.x;   // < 147456
    int cout = idx / 1152, k = idx % 1152;
    int tap = k >> 7, cin = k & 127;
    o[idx] = f2bf(w[(cout * 128 + cin) * 9 + tap]);
}

// Zero only the 1-pixel halo ring of xp (4,82,242,128)
__global__ void halo_zero(unsigned short* __restrict__ xp)
{
    int idx = blockIdx.x * 256 + threadIdx.x;   // < 4*644*32
    if (idx >= 4 * 644 * 32) return;
    int c4 = (idx & 31) << 2;
    int t = idx >> 5;
    int p = t % 644, n = t / 644;
    int y, x;
    if (p < 242)      { y = 0;       x = p;       }
    else if (p < 484) { y = 81;      x = p - 242; }
    else if (p < 564) { y = p - 483; x = 0;       }
    else              { y = p - 563; x = 241;     }
    ushort4 z = {0, 0, 0, 0};
    *(ushort4*)(xp + (((size_t)(n * 82 + y)) * 242 + x) * 128 + c4) = z;
}

// NCHW fp32 (4,128,80,240) -> padded NHWC bf16 (4,82,242,128)
// One block per (n, y, 32-channel tile): grid 4*80*4 = 1280.
__global__ __launch_bounds__(256) void nchw_to_nhwc_pad(
    const float* __restrict__ x, unsigned short* __restrict__ xp)
{
    __shared__ unsigned short t[240 * 36];       // [x][c] pad to 36
    int b = blockIdx.x;
    int ct = b & 3;
    int tmp = b >> 2;
    int y = tmp % 80, n = tmp / 80;
    const float* xin = x + (((size_t)(n * 128 + ct * 32)) * 80 + y) * 240;
    for (int f = threadIdx.x; f < 32 * 240; f += 256) {
        int c = f / 240, xc = f % 240;
        t[xc * 36 + c] = f2bf(xin[(size_t)c * 19200 + xc]);
    }
    __syncthreads();
    unsigned short* out = xp + (((size_t)(n * 82 + y + 1)) * 242 + 1) * 128 + ct * 32;
    for (int f = threadIdx.x; f < 240 * 8; f += 256) {
        int xc = f >> 3, c4 = (f & 7) << 2;
        ushort4 v = *(const ushort4*)(t + xc * 36 + c4);
        *(ushort4*)(out + (size_t)xc * 128 + c4) = v;
    }
}

// Sine positional + level embedding (fp32)
__global__ void pos_embed(const float* __restrict__ lvl_emb, float* __restrict__ pos)
{
    unsigned idx = blockIdx.x * 256u + threadIdx.x;   // < LQ*128
    int c = idx & 127;
    int q = idx >> 7;
    int n = q / HWp, pix = q % HWp;
    int h = pix / WW, w = pix % WW;
    int cc = (c < 64) ? c : (c - 64);
    float coord = (c < 64) ? (float)(h + 1) : (float)(w + 1);
    float denom = (c < 64) ? 40.0f : 120.0f;
    float e = coord / (denom + 1e-6f) * 6.283185307179586f;
    float expo = (float)(cc & ~1) * (1.0f / 64.0f);
    float dim_t = __expf(expo * 9.2103403719761836f);   // 10000^expo
    float p = e / dim_t;
    float v = (cc & 1) ? __cosf(p) : __sinf(p);
    pos[idx] = v + lvl_emb[n * CCh + c];
}

__device__ inline void fma_u4(float* acc, float w, uint4 v)
{
    acc[0] = fmaf(w, bf2f(v.x & 0xffffu), acc[0]);
    acc[1] = fmaf(w, bf2f(v.x >> 16),     acc[1]);
    acc[2] = fmaf(w, bf2f(v.y & 0xffffu), acc[2]);
    acc[3] = fmaf(w, bf2f(v.y >> 16),     acc[3]);
    acc[4] = fmaf(w, bf2f(v.z & 0xffffu), acc[4]);
    acc[5] = fmaf(w, bf2f(v.z >> 16),     acc[5]);
    acc[6] = fmaf(w, bf2f(v.w & 0xffffu), acc[6]);
    acc[7] = fmaf(w, bf2f(v.w >> 16),     acc[7]);
}
__device__ inline unsigned int pk2(float a, float b)
{ return (unsigned int)f2bf(a) | ((unsigned int)f2bf(b) << 16); }

// ---------------------------------------------------------------------------
// MS deformable attention sampling, one thread per (q, h, l).
// val: plane layout [l][h][4800][16] bf16; off: (LQ,256) fp16 [(h,l,p),2];
// attn: (LQ,128) fp16 softmaxed [(h),(l,p)]; out: (LQ,128) bf16 [(h),(d)].
// ---------------------------------------------------------------------------
__global__ __launch_bounds__(256) void deform_sample(
    const unsigned short* __restrict__ val, const _Float16* __restrict__ off,
    const _Float16* __restrict__ attn, unsigned short* __restrict__ out)
{
    unsigned gid = blockIdx.x * 256u + threadIdx.x;   // < LQ*NH*NLv
    int l = gid & 3;
    int h = (gid >> 2) & 7;
    int q = gid >> 5;
    int pix = q % HWp;
    int qy = pix / WW, qx = pix % WW;
    h16x8 ov = *(const h16x8*)(off + (size_t)q * 256 + h * 32 + l * 8);
    h16x4 av = *(const h16x4*)(attn + (size_t)q * 128 + h * 16 + l * 4);
    const unsigned short* vbase = val + (size_t)(l * 8 + h) * HWp * 16;
    float acc[16] = {};
    #pragma unroll
    for (int p = 0; p < NPt; p++) {
        float ox = (float)ov[2 * p], oy = (float)ov[2 * p + 1];
        float a = (float)av[p];
        float x = (float)qx + ox;
        float y = (float)qy + oy;
        float xf = floorf(x), yf = floorf(y);
        int x0 = (int)xf, y0 = (int)yf;
        float wx1 = x - xf, wy1 = y - yf;
        float wx0 = 1.f - wx1, wy0 = 1.f - wy1;
        #pragma unroll
        for (int dy = 0; dy < 2; dy++) {
            int yc = y0 + dy;
            if ((unsigned)yc >= (unsigned)HH) continue;
            float wy = dy ? wy1 : wy0;
            const unsigned short* rowp = vbase + (size_t)(yc * WW) * 16;
            #pragma unroll
            for (int dx = 0; dx < 2; dx++) {
                int xc = x0 + dx;
                if ((unsigned)xc >= (unsigned)WW) continue;
                float wgt = a * wy * (dx ? wx1 : wx0);
                const uint4* vp = (const uint4*)(rowp + xc * 16);
                fma_u4(acc,     wgt, vp[0]);
                fma_u4(acc + 8, wgt, vp[1]);
            }
        }
    }
    #pragma unroll
    for (int i = 0; i < 16; i++) {
        acc[i] += __shfl_xor(acc[i], 1);
        acc[i] += __shfl_xor(acc[i], 2);
    }
    if (l == 0) {
        uint4 o0 = { pk2(acc[0], acc[1]),   pk2(acc[2], acc[3]),
                     pk2(acc[4], acc[5]),   pk2(acc[6], acc[7]) };
        uint4 o1 = { pk2(acc[8], acc[9]),   pk2(acc[10], acc[11]),
                     pk2(acc[12], acc[13]), pk2(acc[14], acc[15]) };
        uint4* op = (uint4*)(out + (size_t)q * CCh + h * 16);
        op[0] = o0; op[1] = o1;
    }
}

// Gather src (LQ,128) -> A_merge (4800,512) bf16
__global__ void merge_gather(const float* __restrict__ src, unsigned short* __restrict__ A)
{
    unsigned idx = blockIdx.x * 256u + threadIdx.x;   // < 614400
    unsigned flat = idx * 4;
    int pix = flat >> 9;
    int k = flat & 511;
    int n = k >> 7, c = k & 127;
    float4 s = *(const float4*)(src + ((size_t)(n * HWp + pix)) * CCh + c);
    ushort4 o = { f2bf(s.x), f2bf(s.y), f2bf(s.z), f2bf(s.w) };
    *(ushort4*)(A + flat) = o;
}

// Bilinear 2x upsample -> padded NHWC bf16 (82,242,128), halo zeroed
__global__ void upsample_nhwc(const float* __restrict__ m, unsigned short* __restrict__ up)
{
    unsigned idx = blockIdx.x * 256u + threadIdx.x;   // < 82*242*32
    if (idx >= 82u * 242u * 32u) return;
    int c4 = (idx & 31) << 2;
    int p = idx >> 5;
    int px = p % 242, py = p / 242;
    ushort4 o = {0, 0, 0, 0};
    if (py >= 1 && py <= RHs && px >= 1 && px <= RWs) {
        int y = py - 1, x = px - 1;
        float fy = (y + 0.5f) * 0.5f - 0.5f;
        float fx = (x + 0.5f) * 0.5f - 0.5f;
        float fyf = floorf(fy), fxf = floorf(fx);
        int y0 = (int)fyf, x0 = (int)fxf;
        float wy = fy - fyf, wx = fx - fxf;
        int y0c = max(y0, 0), y1c = min(y0 + 1, HH - 1);
        int x0c = max(x0, 0), x1c = min(x0 + 1, WW - 1);
        unsigned short r[4];
        #pragma unroll
        for (int cc = 0; cc < 4; cc++) {
            const float* mp = m + (size_t)(c4 + cc) * HWp;
            float v00 = mp[y0c * WW + x0c], v01 = mp[y0c * WW + x1c];
            float v10 = mp[y1c * WW + x0c], v11 = mp[y1c * WW + x1c];
            float v = (1.f - wy) * ((1.f - wx) * v00 + wx * v01)
                    + wy * ((1.f - wx) * v10 + wx * v11);
            r[cc] = f2bf(v);
        }
        o.x = r[0]; o.y = r[1]; o.z = r[2]; o.w = r[3];
    }
    *(ushort4*)(up + (size_t)p * 128 + c4) = o;
}

// ---------------------------------------------------------------------------
extern "C" void kernel_launch(void* const* d_in, const int* in_sizes, int n_in,
                              void* d_out, int out_size, void* d_ws, size_t ws_size,
                              hipStream_t stream)
{
    const float* x       = (const float*)d_in[0];
    const float* dconv_w = (const float*)d_in[1];
    const float* dconv_b = (const float*)d_in[2];
    const float* lvl_emb = (const float*)d_in[3];
    const float* W_off   = (const float*)d_in[4];
    const float* b_off   = (const float*)d_in[5];
    const float* W_attn  = (const float*)d_in[6];
    const float* b_attn  = (const float*)d_in[7];
    const float* W_val   = (const float*)d_in[8];
    const float* b_val   = (const float*)d_in[9];
    const float* W_out   = (const float*)d_in[10];
    const float* b_out   = (const float*)d_in[11];
    const float* ln1_g   = (const float*)d_in[12];
    const float* ln1_b   = (const float*)d_in[13];
    const float* W_ff1   = (const float*)d_in[14];
    const float* b_ff1   = (const float*)d_in[15];
    const float* W_ff2   = (const float*)d_in[16];
    const float* b_ff2   = (const float*)d_in[17];
    const float* ln2_g   = (const float*)d_in[18];
    const float* ln2_b   = (const float*)d_in[19];
    const float* merge_w = (const float*)d_in[20];
    const float* merge_b = (const float*)d_in[21];
    const float* uconv_w = (const float*)d_in[22];
    const float* uconv_b = (const float*)d_in[23];

    char* wsb = (char*)d_ws;
    unsigned short* xp       = (unsigned short*)(wsb);               // 20,320,256 B (4,82,242,128)
    unsigned short* up       = (unsigned short*)(wsb + 20320256);    //  5,080,064 B (82,242,128)
    float*          src      = (float*)(wsb + 25400320);             //  9,830,400 B
    unsigned short* srcb     = (unsigned short*)(wsb + 35230720);    //  4,915,200 B
    float*          pos      = (float*)(wsb + 40145920);             //  9,830,400 B
    unsigned short* qb       = (unsigned short*)(wsb + 49976320);    //  4,915,200 B
    unsigned short* valb     = (unsigned short*)(wsb + 54891520);    //  4,915,200 B
    _Float16*       attnh    = (_Float16*)(wsb + 59806720);          //  4,915,200 B
    unsigned short* attnoutb = (unsigned short*)(wsb + 69637120);    //  4,915,200 B
    unsigned short* ff1b     = (unsigned short*)(wsb + 84382720);    // 19,660,800 B
    unsigned short* wb       = (unsigned short*)(wsb + 104043520);   //  1,114,112 B
    unsigned short* dconv_wb = (unsigned short*)(wsb + 105452544);   //    294,912 B
    unsigned short* uconv_wb = (unsigned short*)(wsb + 105747456);   //    294,912 B
    unsigned short* wcat     = (unsigned short*)(wsb + 106042368);   //    294,912 B
    float*          bcat     = (float*)(wsb + 106337280);            //      4,608 B (end 106,341,888)
    // aliases (lifetimes disjoint):
    _Float16*       offh     = (_Float16*)xp;    // layers: xp dead after dconv gemm
    unsigned short* merge_in = up;               // before upsample writes up
    float*          mbuf     = (float*)valb;     // after layers
    float* outp = (float*)d_out;

    // bf16 linear weight table offsets (elements)
    unsigned short* W_val_b  = wb;
    unsigned short* W_out_b  = wb + 49152;
    unsigned short* W_ff1_b  = wb + 98304;
    unsigned short* W_ff2_b  = wb + 294912;
    unsigned short* merge_wb = wb + 491520;

    // 0) weight conversion + input transpose + positional embedding
    halo_zero<<<322, 256, 0, stream>>>(xp);
    convert_weights<<<2176, 256, 0, stream>>>(W_val, W_out, W_ff1, W_ff2, merge_w, wb);
    build_oa<<<581, 256, 0, stream>>>(W_off, b_off, W_attn, b_attn, wcat, bcat);
    convert_conv_w<<<576, 256, 0, stream>>>(dconv_w, dconv_wb);
    convert_conv_w<<<576, 256, 0, stream>>>(uconv_w, uconv_wb);
    nchw_to_nhwc_pad<<<1280, 256, 0, stream>>>(x, xp);
    pos_embed<<<9600, 256, 0, stream>>>(lvl_emb, pos);

    // 1) downsample conv (implicit GEMM) -> src fp32 + srcb bf16 + qb, relu
    conv3x3_gemm<0><<<dim3(2, 150), 256, 0, stream>>>(
        xp, dconv_wb, dconv_b, src, srcb, pos, qb);

    // 2) encoder layers
    for (int i = 0; i < 3; i++) {
        gemm_bf16<false, false, 4><<<dim3(6, 150), 256, 0, stream>>>(
            qb, wcat + (size_t)i * 49152, bcat + i * 384,
            nullptr, nullptr, offh, attnh, LQ, 384, 128);
        gemm_bf16<false, false, 3><<<dim3(2, 150), 256, 0, stream>>>(
            srcb, W_val_b + (size_t)i * 16384, b_val + i * 128,
            nullptr, valb, nullptr, nullptr, LQ, 128, 128);
        deform_sample<<<2400, 256, 0, stream>>>(valb, offh, attnh, attnoutb);
        gemm_ln<false><<<300, 256, 0, stream>>>(
            attnoutb, W_out_b + (size_t)i * 16384, b_out + i * 128,
            ln1_g + i * 128, ln1_b + i * 128, src, srcb, nullptr, nullptr, 128);
        gemm_bf16<false, true, 1><<<dim3(8, 150), 256, 0, stream>>>(
            srcb, W_ff1_b + (size_t)i * 65536, b_ff1 + i * 512,
            nullptr, ff1b, nullptr, nullptr, LQ, 512, 128);
        gemm_ln<true><<<300, 256, 0, stream>>>(
            ff1b, W_ff2_b + (size_t)i * 65536, b_ff2 + i * 128,
            ln2_g + i * 128, ln2_b + i * 128, src, srcb, pos, qb, 512);
    }

    // 3) merge 1x1 conv, weights-as-A trick: mbuf[128,4800]
    merge_gather<<<2400, 256, 0, stream>>>(src, merge_in);
    gemm_bf16<true, true, 0><<<dim3(75, 1), 256, 0, stream>>>(
        merge_wb, merge_in, merge_b, mbuf, nullptr, nullptr, nullptr, 128, 4800, 512);

    // 4) bilinear 2x upsample -> padded NHWC bf16
    upsample_nhwc<<<2482, 256, 0, stream>>>(mbuf, up);

    // 5) uconv (implicit GEMM, transposed store) -> d_out (128,19200), relu
    conv3x3_gemm<1><<<dim3(2, 150), 256, 0, stream>>>(
        up, uconv_wb, uconv_b, outp, nullptr, nullptr, nullptr);
}

// Round 6
// 530.482 us; speedup vs baseline: 3.0564x; 1.0575x over previous
//
#include <hip/hip_runtime.h>
#include <math.h>
#include <cstddef>

// Problem constants
#define LQ   19200          // NL*H*W tokens
#define HH   40
#define WW   120
#define HWp  4800
#define CCh  128
#define NHd  8
#define NLv  4
#define NPt  4
#define RHs  80
#define RWs  240

typedef __attribute__((ext_vector_type(8))) short bf16x8;
typedef __attribute__((ext_vector_type(4))) float f32x4;
typedef __attribute__((ext_vector_type(8))) _Float16 h16x8;
typedef __attribute__((address_space(1))) const unsigned int GUI;
typedef __attribute__((address_space(3))) unsigned int LUI;

__device__ inline unsigned short f2bf(float f) {
    unsigned int u = __float_as_uint(f);
    u += 0x7fffu + ((u >> 16) & 1u);        // round-to-nearest-even
    return (unsigned short)(u >> 16);
}
__device__ inline float bf2f(unsigned int lo16) { return __uint_as_float(lo16 << 16); }

// ---------------------------------------------------------------------------
// bf16 MFMA GEMM: Out[M,N] = A[M,K] @ Bw[N,K]^T + bias, opt relu.
// BIAS_ROW: bias indexed by row (weights-as-A transposed trick).
// OMODE: 0 = fp32 OutF; 1 = bf16 OutB; 2 = both.
// ---------------------------------------------------------------------------
template<bool BIAS_ROW, bool RELU, int OMODE>
__global__ __launch_bounds__(256) void gemm_bf16(
    const unsigned short* __restrict__ A,
    const unsigned short* __restrict__ Bw,
    const float* __restrict__ bias,
    float* __restrict__ OutF, unsigned short* __restrict__ OutB,
    int M, int N, int K)
{
    constexpr int BM = 128, BN = 64, BK = 32;
    __shared__ unsigned short As[BM * BK];   // row-major [m][k]
    __shared__ unsigned short Bs[BN * BK];
    const int bm = blockIdx.y * BM, bn = blockIdx.x * BN;
    const int tid = threadIdx.x;
    const int wid = tid >> 6, lane = tid & 63;
    const int wm = (wid & 1) * 64, wn = (wid >> 1) * 32;
    const int lm = lane & 15, lqd = lane >> 4;

    f32x4 acc[4][2] = {};

    const int arow = lane >> 2;          // 0..15 within a 16-row chunk
    const int akc  = (lane & 3) * 8;     // k element offset (16 B granules)
    const unsigned short* aG0 = A  + (size_t)(bm + wid * 32 +      arow) * K + akc;
    const unsigned short* aG1 = A  + (size_t)(bm + wid * 32 + 16 + arow) * K + akc;
    const unsigned short* bG  = Bw + (size_t)(bn + wid * 16 +      arow) * K + akc;
    unsigned short* aL0 = As + wid * 1024 + lane * 8;
    unsigned short* aL1 = As + wid * 1024 + 512 + lane * 8;
    unsigned short* bL  = Bs + wid * 512 + lane * 8;

    for (int k0 = 0; k0 < K; k0 += BK) {
        __builtin_amdgcn_global_load_lds((GUI*)(aG0 + k0), (LUI*)aL0, 16, 0, 0);
        __builtin_amdgcn_global_load_lds((GUI*)(aG1 + k0), (LUI*)aL1, 16, 0, 0);
        __builtin_amdgcn_global_load_lds((GUI*)(bG  + k0), (LUI*)bL,  16, 0, 0);
        __syncthreads();
        bf16x8 a[4], b[2];
        #pragma unroll
        for (int i = 0; i < 4; i++)
            a[i] = *(const bf16x8*)(As + (wm + i * 16 + lm) * BK + lqd * 8);
        #pragma unroll
        for (int j = 0; j < 2; j++)
            b[j] = *(const bf16x8*)(Bs + (wn + j * 16 + lm) * BK + lqd * 8);
        #pragma unroll
        for (int i = 0; i < 4; i++)
            #pragma unroll
            for (int j = 0; j < 2; j++)
                acc[i][j] = __builtin_amdgcn_mfma_f32_16x16x32_bf16(a[i], b[j], acc[i][j], 0, 0, 0);
        __syncthreads();
    }

    #pragma unroll
    for (int i = 0; i < 4; i++) {
        int row0 = bm + wm + i * 16 + lqd * 4;
        #pragma unroll
        for (int j = 0; j < 2; j++) {
            int col = bn + wn + j * 16 + lm;
            float bc = BIAS_ROW ? 0.f : bias[col];
            #pragma unroll
            for (int r = 0; r < 4; r++) {
                int row = row0 + r;
                float v = acc[i][j][r] + (BIAS_ROW ? bias[row] : bc);
                if (RELU) v = fmaxf(v, 0.f);
                size_t o = (size_t)row * N + col;
                if (OMODE == 0) OutF[o] = v;
                else if (OMODE == 1) OutB[o] = f2bf(v);
                else { OutF[o] = v; OutB[o] = f2bf(v); }
            }
        }
    }
}

// ---------------------------------------------------------------------------
// Merged off/attn + val GEMM for one layer. Grid dim3(8, 150), BM=128, K=128.
// bx<6: A=qb, W=Woa(384x128): col<256 -> fp16 off (stride 256);
//       col>=256 -> softmax16 -> fp16 attn (stride 128).
// bx>=6: A=srcb, W=Wv(128x128): bf16 val in plane layout [l][h][4800][16].
// ---------------------------------------------------------------------------
__global__ __launch_bounds__(256) void gemm_oav(
    const unsigned short* __restrict__ Aq,
    const unsigned short* __restrict__ Asrc,
    const unsigned short* __restrict__ Woa, const float* __restrict__ boa,
    const unsigned short* __restrict__ Wv,  const float* __restrict__ bv,
    _Float16* __restrict__ OutH, _Float16* __restrict__ OutH2,
    unsigned short* __restrict__ OutV)
{
    constexpr int BK = 32, K = 128;
    __shared__ unsigned short As[128 * BK];
    __shared__ unsigned short Bs[64 * BK];
    const int bx = blockIdx.x;
    const bool isv = bx >= 6;
    const unsigned short* A  = isv ? Asrc : Aq;
    const unsigned short* Bw = isv ? Wv : Woa;
    const float* bias = isv ? bv : boa;
    const int bn = isv ? (bx - 6) * 64 : bx * 64;
    const int bm = blockIdx.y * 128;
    const int tid = threadIdx.x;
    const int wid = tid >> 6, lane = tid & 63;
    const int wm = (wid & 1) * 64, wn = (wid >> 1) * 32;
    const int lm = lane & 15, lqd = lane >> 4;

    f32x4 acc[4][2] = {};

    const int arow = lane >> 2;
    const int akc  = (lane & 3) * 8;
    const unsigned short* aG0 = A  + (size_t)(bm + wid * 32 +      arow) * K + akc;
    const unsigned short* aG1 = A  + (size_t)(bm + wid * 32 + 16 + arow) * K + akc;
    const unsigned short* bG  = Bw + (size_t)(bn + wid * 16 +      arow) * K + akc;
    unsigned short* aL0 = As + wid * 1024 + lane * 8;
    unsigned short* aL1 = As + wid * 1024 + 512 + lane * 8;
    unsigned short* bL  = Bs + wid * 512 + lane * 8;

    for (int k0 = 0; k0 < K; k0 += BK) {
        __builtin_amdgcn_global_load_lds((GUI*)(aG0 + k0), (LUI*)aL0, 16, 0, 0);
        __builtin_amdgcn_global_load_lds((GUI*)(aG1 + k0), (LUI*)aL1, 16, 0, 0);
        __builtin_amdgcn_global_load_lds((GUI*)(bG  + k0), (LUI*)bL,  16, 0, 0);
        __syncthreads();
        bf16x8 a[4], b[2];
        #pragma unroll
        for (int i = 0; i < 4; i++)
            a[i] = *(const bf16x8*)(As + (wm + i * 16 + lm) * BK + lqd * 8);
        #pragma unroll
        for (int j = 0; j < 2; j++)
            b[j] = *(const bf16x8*)(Bs + (wn + j * 16 + lm) * BK + lqd * 8);
        #pragma unroll
        for (int i = 0; i < 4; i++)
            #pragma unroll
            for (int j = 0; j < 2; j++)
                acc[i][j] = __builtin_amdgcn_mfma_f32_16x16x32_bf16(a[i], b[j], acc[i][j], 0, 0, 0);
        __syncthreads();
    }

    #pragma unroll
    for (int i = 0; i < 4; i++) {
        int row0 = bm + wm + i * 16 + lqd * 4;
        #pragma unroll
        for (int j = 0; j < 2; j++) {
            int col = bn + wn + j * 16 + lm;
            float bc = bias[col];
            if (!isv) {
                if (col < 256) {
                    #pragma unroll
                    for (int r = 0; r < 4; r++)
                        OutH[(size_t)(row0 + r) * 256 + col] = (_Float16)(acc[i][j][r] + bc);
                } else {
                    #pragma unroll
                    for (int r = 0; r < 4; r++) {
                        float v = acc[i][j][r] + bc;
                        float m = v;
                        #pragma unroll
                        for (int msk = 1; msk < 16; msk <<= 1)
                            m = fmaxf(m, __shfl_xor(m, msk));
                        float e = __expf(v - m);
                        float s = e;
                        #pragma unroll
                        for (int msk = 1; msk < 16; msk <<= 1)
                            s += __shfl_xor(s, msk);
                        OutH2[(size_t)(row0 + r) * 128 + (col - 256)] = (_Float16)(e / s);
                    }
                }
            } else {
                #pragma unroll
                for (int r = 0; r < 4; r++) {
                    int row = row0 + r;
                    int plane = (row / HWp) * 8 + (col >> 4);
                    size_t o = ((size_t)plane * HWp + (row % HWp)) * 16 + (col & 15);
                    OutV[o] = f2bf(acc[i][j][r] + bc);
                }
            }
        }
    }
}

// ---------------------------------------------------------------------------
// LN-fused GEMM: delta[M,128] = A[M,K] @ Bw[128,K]^T + bias; then
// y = LayerNorm(srcF + delta) * g + b2; writes srcF(fp32), srcB(bf16),
// and (WQ) qb = bf16(y + pos). BM=64, BN=128 (block holds full rows).
// ---------------------------------------------------------------------------
template<bool WQ>
__global__ __launch_bounds__(256) void gemm_ln(
    const unsigned short* __restrict__ A,
    const unsigned short* __restrict__ Bw,
    const float* __restrict__ bias,
    const float* __restrict__ g, const float* __restrict__ b2,
    float* __restrict__ srcF, unsigned short* __restrict__ srcB,
    const float* __restrict__ pos, unsigned short* __restrict__ qb,
    int K)
{
    __shared__ __align__(16) unsigned char smem[12288];
    unsigned short* As = (unsigned short*)smem;            // 64 x 32
    unsigned short* Bs = (unsigned short*)(smem + 4096);   // 128 x 32
    const int bm = blockIdx.x * 64;
    const int tid = threadIdx.x;
    const int wid = tid >> 6, lane = tid & 63;
    const int wm = (wid & 1) * 32, wn = (wid >> 1) * 64;
    const int lm = lane & 15, lqd = lane >> 4;

    f32x4 acc[2][4] = {};

    const int srow = lane >> 2;
    const int skc  = (lane & 3) * 8;
    const unsigned short* aG  = A  + (size_t)(bm + wid * 16 + srow) * K + skc;
    const unsigned short* bG0 = Bw + (size_t)(wid * 16 + srow) * K + skc;
    const unsigned short* bG1 = Bw + (size_t)(64 + wid * 16 + srow) * K + skc;
    unsigned short* aL  = As + wid * 512 + lane * 8;
    unsigned short* bL0 = Bs + wid * 512 + lane * 8;
    unsigned short* bL1 = Bs + 2048 + wid * 512 + lane * 8;

    for (int k0 = 0; k0 < K; k0 += 32) {
        __builtin_amdgcn_global_load_lds((GUI*)(aG  + k0), (LUI*)aL,  16, 0, 0);
        __builtin_amdgcn_global_load_lds((GUI*)(bG0 + k0), (LUI*)bL0, 16, 0, 0);
        __builtin_amdgcn_global_load_lds((GUI*)(bG1 + k0), (LUI*)bL1, 16, 0, 0);
        __syncthreads();
        bf16x8 a[2], b[4];
        #pragma unroll
        for (int i = 0; i < 2; i++)
            a[i] = *(const bf16x8*)(As + (wm + i * 16 + lm) * 32 + lqd * 8);
        #pragma unroll
        for (int j = 0; j < 4; j++)
            b[j] = *(const bf16x8*)(Bs + (wn + j * 16 + lm) * 32 + lqd * 8);
        #pragma unroll
        for (int i = 0; i < 2; i++)
            #pragma unroll
            for (int j = 0; j < 4; j++)
                acc[i][j] = __builtin_amdgcn_mfma_f32_16x16x32_bf16(a[i], b[j], acc[i][j], 0, 0, 0);
        __syncthreads();
    }

    // z = delta + src (fp32 residual)
    float z[2][4][4];
    #pragma unroll
    for (int i = 0; i < 2; i++) {
        #pragma unroll
        for (int j = 0; j < 4; j++) {
            int col = wn + j * 16 + lm;
            float bc = bias[col];
            #pragma unroll
            for (int r = 0; r < 4; r++) {
                int row = bm + wm + i * 16 + lqd * 4 + r;
                z[i][j][r] = acc[i][j][r] + bc + srcF[(size_t)row * 128 + col];
            }
        }
    }

    // row-wise reduction: 64 cols per wave via shfl, cross-wave via LDS
    float* red = (float*)smem;      // [half][ sums(64) | sq(64) ] = 256 floats
    #pragma unroll
    for (int i = 0; i < 2; i++) {
        #pragma unroll
        for (int r = 0; r < 4; r++) {
            float s = z[i][0][r] + z[i][1][r] + z[i][2][r] + z[i][3][r];
            float q = z[i][0][r] * z[i][0][r] + z[i][1][r] * z[i][1][r]
                    + z[i][2][r] * z[i][2][r] + z[i][3][r] * z[i][3][r];
            #pragma unroll
            for (int msk = 1; msk < 16; msk <<= 1) {
                s += __shfl_xor(s, msk);
                q += __shfl_xor(q, msk);
            }
            if (lm == 0) {
                int rl = wm + i * 16 + lqd * 4 + r;
                red[(wid >> 1) * 128 + rl] = s;
                red[(wid >> 1) * 128 + 64 + rl] = q;
            }
        }
    }
    __syncthreads();

    float mean[2][4], inv[2][4];
    #pragma unroll
    for (int i = 0; i < 2; i++) {
        #pragma unroll
        for (int r = 0; r < 4; r++) {
            int rl = wm + i * 16 + lqd * 4 + r;
            float s = red[rl] + red[128 + rl];
            float q = red[64 + rl] + red[192 + rl];
            float m = s * (1.0f / 128.0f);
            float v = q * (1.0f / 128.0f) - m * m;
            mean[i][r] = m;
            inv[i][r] = rsqrtf(v + 1e-5f);
        }
    }

    #pragma unroll
    for (int i = 0; i < 2; i++) {
        #pragma unroll
        for (int j = 0; j < 4; j++) {
            int col = wn + j * 16 + lm;
            float gc = g[col], bc2 = b2[col];
            #pragma unroll
            for (int r = 0; r < 4; r++) {
                int row = bm + wm + i * 16 + lqd * 4 + r;
                float y = (z[i][j][r] - mean[i][r]) * inv[i][r] * gc + bc2;
                size_t o = (size_t)row * 128 + col;
                srcF[o] = y;
                srcB[o] = f2bf(y);
                if constexpr (WQ) qb[o] = f2bf(y + pos[o]);
            }
        }
    }
}

// ---------------------------------------------------------------------------
// Implicit-GEMM 3x3 conv from padded NHWC bf16 input, tap-major weights.
// MODE 0: dconv  — X:(4,82,242,128), stride 2, out: src fp32 + srcb bf16 +
//                  qb = bf16(src+pos), relu.
// MODE 1: uconv  — X:(82,242,128), stride 1, out: d_out fp32 (128,19200)
//                  via LDS-transposed store, relu.
// ---------------------------------------------------------------------------
template<int MODE>
__global__ __launch_bounds__(256) void conv3x3_gemm(
    const unsigned short* __restrict__ X,
    const unsigned short* __restrict__ Wp,
    const float* __restrict__ bias,
    float* __restrict__ OutF, unsigned short* __restrict__ OutB,
    const float* __restrict__ pos, unsigned short* __restrict__ Qb)
{
    constexpr int BM = 128, BN = 64, BK = 32;
    constexpr int SMEM = (MODE == 1) ? 33792 : 12288;
    __shared__ __align__(16) unsigned char smem[SMEM];
    unsigned short* As = (unsigned short*)smem;            // 128*32
    unsigned short* Bs = (unsigned short*)(smem + 8192);   // 64*32
    const int bm = blockIdx.y * BM, bn = blockIdx.x * BN;
    const int tid = threadIdx.x;
    const int wid = tid >> 6, lane = tid & 63;
    const int wm = (wid & 1) * 64, wn = (wid >> 1) * 32;
    const int lm = lane & 15, lqd = lane >> 4;

    f32x4 acc[4][2] = {};

    const int arow = lane >> 2;
    const int akc  = (lane & 3) * 8;
    const int r0 = bm + wid * 32 + arow;
    const int r1 = r0 + 16;
    size_t bA0, bA1;
    if (MODE == 0) {
        int n0 = r0 / HWp, rem0 = r0 % HWp, oh0 = rem0 / WW, ow0 = rem0 % WW;
        int n1 = r1 / HWp, rem1 = r1 % HWp, oh1 = rem1 / WW, ow1 = rem1 % WW;
        bA0 = ((size_t)(n0 * 82 + oh0 * 2) * 242 + ow0 * 2) * 128;
        bA1 = ((size_t)(n1 * 82 + oh1 * 2) * 242 + ow1 * 2) * 128;
    } else {
        int y0 = r0 / RWs, x0 = r0 % RWs;
        int y1 = r1 / RWs, x1 = r1 % RWs;
        bA0 = ((size_t)y0 * 242 + x0) * 128;
        bA1 = ((size_t)y1 * 242 + x1) * 128;
    }
    const unsigned short* bG = Wp + (size_t)(bn + wid * 16 + arow) * 1152 + akc;
    unsigned short* aL0 = As + wid * 1024 + lane * 8;
    unsigned short* aL1 = As + wid * 1024 + 512 + lane * 8;
    unsigned short* bL  = Bs + wid * 512 + lane * 8;

    for (int chunk = 0; chunk < 36; chunk++) {
        int tap = chunk >> 2;
        int cpart = (chunk & 3) << 5;
        int ky = tap / 3, kx = tap % 3;
        int toff = (ky * 242 + kx) * 128 + cpart + akc;
        __builtin_amdgcn_global_load_lds((GUI*)(X + bA0 + toff), (LUI*)aL0, 16, 0, 0);
        __builtin_amdgcn_global_load_lds((GUI*)(X + bA1 + toff), (LUI*)aL1, 16, 0, 0);
        __builtin_amdgcn_global_load_lds((GUI*)(bG + chunk * 32), (LUI*)bL, 16, 0, 0);
        __syncthreads();
        bf16x8 a[4], b[2];
        #pragma unroll
        for (int i = 0; i < 4; i++)
            a[i] = *(const bf16x8*)(As + (wm + i * 16 + lm) * BK + lqd * 8);
        #pragma unroll
        for (int j = 0; j < 2; j++)
            b[j] = *(const bf16x8*)(Bs + (wn + j * 16 + lm) * BK + lqd * 8);
        #pragma unroll
        for (int i = 0; i < 4; i++)
            #pragma unroll
            for (int j = 0; j < 2; j++)
                acc[i][j] = __builtin_amdgcn_mfma_f32_16x16x32_bf16(a[i], b[j], acc[i][j], 0, 0, 0);
        __syncthreads();
    }

    if (MODE == 0) {
        #pragma unroll
        for (int i = 0; i < 4; i++) {
            int row0 = bm + wm + i * 16 + lqd * 4;
            #pragma unroll
            for (int j = 0; j < 2; j++) {
                int col = bn + wn + j * 16 + lm;
                float bc = bias[col];
                #pragma unroll
                for (int r = 0; r < 4; r++) {
                    float v = fmaxf(acc[i][j][r] + bc, 0.f);
                    size_t o = (size_t)(row0 + r) * 128 + col;
                    OutF[o] = v;
                    OutB[o] = f2bf(v);
                    Qb[o] = f2bf(v + pos[o]);
                }
            }
        }
    } else {
        float* Ts = (float*)smem;                 // 64 x 132 floats
        #pragma unroll
        for (int i = 0; i < 4; i++) {
            int lr0 = wm + i * 16 + lqd * 4;
            #pragma unroll
            for (int j = 0; j < 2; j++) {
                int lc = wn + j * 16 + lm;
                float bc = bias[bn + lc];
                #pragma unroll
                for (int r = 0; r < 4; r++)
                    Ts[lc * 132 + lr0 + r] = fmaxf(acc[i][j][r] + bc, 0.f);
            }
        }
        __syncthreads();
        for (int f = tid; f < 64 * 32; f += 256) {
            int ch = f >> 5, p4 = (f & 31) << 2;
            float4 v4 = *(const float4*)(Ts + ch * 132 + p4);
            *(float4*)(OutF + (size_t)(bn + ch) * 19200 + bm + p4) = v4;
        }
    }
}

// ---------------------------------------------------------------------------
// One-dispatch prep: linear weights -> bf16, [W_off;W_attn] concat, conv
// weights tap-major, halo zero, pos embed.
// S0 [0,557056)          wb: W_val 0, W_out 49152, W_ff1 98304,
//                            W_ff2 294912, merge 491520
// S1 [557056,705664)     wcat 147456 + bcat 1152
// S2 [705664,853120)     dconv_wb
// S3 [853120,1000576)    uconv_wb
// S4 [1000576,1083008)   halo zero of xp (82432 ushort4 stores)
// S5 [1083008,3540608)   pos embed (2457600)
// ---------------------------------------------------------------------------
__global__ void prep_all(
    const float* __restrict__ W_val, const float* __restrict__ W_out,
    const float* __restrict__ W_ff1, const float* __restrict__ W_ff2,
    const float* __restrict__ merge_w,
    const float* __restrict__ Woff, const float* __restrict__ boff,
    const float* __restrict__ Wattn, const float* __restrict__ battn,
    const float* __restrict__ dconv_w, const float* __restrict__ uconv_w,
    const float* __restrict__ lvl_emb,
    unsigned short* __restrict__ wb, unsigned short* __restrict__ wcat,
    float* __restrict__ bcat, unsigned short* __restrict__ dconv_wb,
    unsigned short* __restrict__ uconv_wb, unsigned short* __restrict__ xp,
    float* __restrict__ pos)
{
    int idx = blockIdx.x * 256 + threadIdx.x;
    if (idx < 557056) {
        const float* src; int rel;
        if      (idx <  49152) { src = W_val;   rel = idx;          }
        else if (idx <  98304) { src = W_out;   rel = idx - 49152;  }
        else if (idx < 294912) { src = W_ff1;   rel = idx - 98304;  }
        else if (idx < 491520) { src = W_ff2;   rel = idx - 294912; }
        else                   { src = merge_w; rel = idx - 491520; }
        wb[idx] = f2bf(src[rel]);
    } else if (idx < 705664) {
        int j = idx - 557056;
        if (j < 147456) {
            int layer = j / 49152, r = (j / 128) % 384, c = j & 127;
            float v = (r < 256) ? Woff[((size_t)layer * 256 + r) * 128 + c]
                                : Wattn[((size_t)layer * 128 + (r - 256)) * 128 + c];
            wcat[j] = f2bf(v);
        } else if (j < 148608) {
            int k = j - 147456;
            int layer = k / 384, r = k % 384;
            bcat[k] = (r < 256) ? boff[layer * 256 + r] : battn[layer * 128 + (r - 256)];
        }
    } else if (idx < 853120) {
        int j = idx - 705664;
        int cout = j / 1152, k = j % 1152;
        int tap = k >> 7, cin = k & 127;
        dconv_wb[j] = f2bf(dconv_w[(cout * 128 + cin) * 9 + tap]);
    } else if (idx < 1000576) {
        int j = idx - 853120;
        int cout = j / 1152, k = j % 1152;
        int tap = k >> 7, cin = k & 127;
        uconv_wb[j] = f2bf(uconv_w[(cout * 128 + cin) * 9 + tap]);
    } else if (idx < 1083008) {
        int j = idx - 1000576;                 // < 4*644*32
        int c4 = (j & 31) << 2;
        int t = j >> 5;
        int p = t % 644, n = t / 644;
        int y, x;
        if (p < 242)      { y = 0;       x = p;       }
        else if (p < 484) { y = 81;      x = p - 242; }
        else if (p < 564) { y = p - 483; x = 0;       }
        else              { y = p - 563; x = 241;     }
        ushort4 z = {0, 0, 0, 0};
        *(ushort4*)(xp + (((size_t)(n * 82 + y)) * 242 + x) * 128 + c4) = z;
    } else if (idx < 3540608) {
        int j = idx - 1083008;                 // < LQ*128
        int c = j & 127;
        int q = j >> 7;
        int n = q / HWp, pix = q % HWp;
        int h = pix / WW, w = pix % WW;
        int cc = (c < 64) ? c : (c - 64);
        float coord = (c < 64) ? (float)(h + 1) : (float)(w + 1);
        float denom = (c < 64) ? 40.0f : 120.0f;
        float e = coord / (denom + 1e-6f) * 6.283185307179586f;
        float expo = (float)(cc & ~1) * (1.0f / 64.0f);
        float dim_t = __expf(expo * 9.2103403719761836f);   // 10000^expo
        float p = e / dim_t;
        float v = (cc & 1) ? __cosf(p) : __sinf(p);
        pos[j] = v + lvl_emb[n * CCh + c];
    }
}

// NCHW fp32 (4,128,80,240) -> padded NHWC bf16 (4,82,242,128)
// One block per (n, y, 32-channel tile): grid 4*80*4 = 1280.
__global__ __launch_bounds__(256) void nchw_to_nhwc_pad(
    const float* __restrict__ x, unsigned short* __restrict__ xp)
{
    __shared__ unsigned short t[240 * 36];       // [x][c] pad to 36
    int b = blockIdx.x;
    int ct = b & 3;
    int tmp = b >> 2;
    int y = tmp % 80, n = tmp / 80;
    const float* xin = x + (((size_t)(n * 128 + ct * 32)) * 80 + y) * 240;
    for (int f = threadIdx.x; f < 32 * 240; f += 256) {
        int c = f / 240, xc = f % 240;
        t[xc * 36 + c] = f2bf(xin[(size_t)c * 19200 + xc]);
    }
    __syncthreads();
    unsigned short* out = xp + (((size_t)(n * 82 + y + 1)) * 242 + 1) * 128 + ct * 32;
    for (int f = threadIdx.x; f < 240 * 8; f += 256) {
        int xc = f >> 3, c4 = (f & 7) << 2;
        ushort4 v = *(const ushort4*)(t + xc * 36 + c4);
        *(ushort4*)(out + (size_t)xc * 128 + c4) = v;
    }
}

__device__ inline void fma8(float* acc, float w, uint4 v)
{
    acc[0] = fmaf(w, __uint_as_float(v.x << 16),          acc[0]);
    acc[1] = fmaf(w, __uint_as_float(v.x & 0xffff0000u),  acc[1]);
    acc[2] = fmaf(w, __uint_as_float(v.y << 16),          acc[2]);
    acc[3] = fmaf(w, __uint_as_float(v.y & 0xffff0000u),  acc[3]);
    acc[4] = fmaf(w, __uint_as_float(v.z << 16),          acc[4]);
    acc[5] = fmaf(w, __uint_as_float(v.z & 0xffff0000u),  acc[5]);
    acc[6] = fmaf(w, __uint_as_float(v.w << 16),          acc[6]);
    acc[7] = fmaf(w, __uint_as_float(v.w & 0xffff0000u),  acc[7]);
}
__device__ inline unsigned int pk2(float a, float b)
{ return (unsigned int)f2bf(a) | ((unsigned int)f2bf(b) << 16); }

// ---------------------------------------------------------------------------
// MS deformable attention sampling. Grid dim3(150, 8): blockIdx.y = head.
// Thread = (query, channel-half): lane pairs share a pixel's 32 B row and
// consecutive lanes are consecutive queries -> gathers share cache lines.
// Each thread loops all 4 levels x 4 points (no cross-lane reduction).
// val: [l][h][4800][16] bf16; off: (LQ,256) fp16; attn: (LQ,128) fp16;
// out: (LQ,128) bf16.
// ---------------------------------------------------------------------------
__global__ __launch_bounds__(256) void deform_sample(
    const unsigned short* __restrict__ val, const _Float16* __restrict__ off,
    const _Float16* __restrict__ attn, unsigned short* __restrict__ out)
{
    int t = threadIdx.x;
    int q = blockIdx.x * 128 + (t >> 1);
    int half = t & 1;
    int h = blockIdx.y;
    int pix = q % HWp;
    int qy = pix / WW, qx = pix % WW;
    const _Float16* offp = off + (size_t)q * 256 + h * 32;
    const _Float16* ap   = attn + (size_t)q * 128 + h * 16;
    h16x8 ovv[4];
    ovv[0] = *(const h16x8*)(offp);
    ovv[1] = *(const h16x8*)(offp + 8);
    ovv[2] = *(const h16x8*)(offp + 16);
    ovv[3] = *(const h16x8*)(offp + 24);
    h16x8 avv[2];
    avv[0] = *(const h16x8*)(ap);
    avv[1] = *(const h16x8*)(ap + 8);
    const unsigned short* vh = val + half * 8;
    float acc[8] = {};
    #pragma unroll
    for (int l = 0; l < 4; l++) {
        const unsigned short* vb = vh + (size_t)(l * 8 + h) * (HWp * 16);
        #pragma unroll
        for (int p = 0; p < 4; p++) {
            float ox = (float)ovv[l][2 * p];
            float oy = (float)ovv[l][2 * p + 1];
            int ai = l * 4 + p;
            float a = (float)avv[ai >> 3][ai & 7];
            float x = (float)qx + ox;
            float y = (float)qy + oy;
            float xf = floorf(x), yf = floorf(y);
            int x0 = (int)xf, y0 = (int)yf;
            float wx1 = x - xf, wy1 = y - yf;
            float wx0 = 1.f - wx1, wy0 = 1.f - wy1;
            #pragma unroll
            for (int dy = 0; dy < 2; dy++) {
                int yc = y0 + dy;
                bool vy = (unsigned)yc < (unsigned)HH;
                int yci = min(max(yc, 0), HH - 1);
                float wyv = dy ? wy1 : wy0;
                #pragma unroll
                for (int dx = 0; dx < 2; dx++) {
                    int xc = x0 + dx;
                    bool vld = vy && ((unsigned)xc < (unsigned)WW);
                    int xci = min(max(xc, 0), WW - 1);
                    float wgt = vld ? a * wyv * (dx ? wx1 : wx0) : 0.f;
                    uint4 v = *(const uint4*)(vb + (size_t)(yci * WW + xci) * 16);
                    fma8(acc, wgt, v);
                }
            }
        }
    }
    uint4 o = { pk2(acc[0], acc[1]), pk2(acc[2], acc[3]),
                pk2(acc[4], acc[5]), pk2(acc[6], acc[7]) };
    *(uint4*)(out + (size_t)q * CCh + h * 16 + half * 8) = o;
}

// Gather src (LQ,128) -> A_merge (4800,512) bf16
__global__ void merge_gather(const float* __restrict__ src, unsigned short* __restrict__ A)
{
    unsigned idx = blockIdx.x * 256u + threadIdx.x;   // < 614400
    unsigned flat = idx * 4;
    int pix = flat >> 9;
    int k = flat & 511;
    int n = k >> 7, c = k & 127;
    float4 s = *(const float4*)(src + ((size_t)(n * HWp + pix)) * CCh + c);
    ushort4 o = { f2bf(s.x), f2bf(s.y), f2bf(s.z), f2bf(s.w) };
    *(ushort4*)(A + flat) = o;
}

// Bilinear 2x upsample -> padded NHWC bf16 (82,242,128), halo zeroed
__global__ void upsample_nhwc(const float* __restrict__ m, unsigned short* __restrict__ up)
{
    unsigned idx = blockIdx.x * 256u + threadIdx.x;   // < 82*242*32
    if (idx >= 82u * 242u * 32u) return;
    int c4 = (idx & 31) << 2;
    int p = idx >> 5;
    int px = p % 242, py = p / 242;
    ushort4 o = {0, 0, 0, 0};
    if (py >= 1 && py <= RHs && px >= 1 && px <= RWs) {
        int y = py - 1, x = px - 1;
        float fy = (y + 0.5f) * 0.5f - 0.5f;
        float fx = (x + 0.5f) * 0.5f - 0.5f;
        float fyf = floorf(fy), fxf = floorf(fx);
        int y0 = (int)fyf, x0 = (int)fxf;
        float wy = fy - fyf, wx = fx - fxf;
        int y0c = max(y0, 0), y1c = min(y0 + 1, HH - 1);
        int x0c = max(x0, 0), x1c = min(x0 + 1, WW - 1);
        unsigned short r[4];
        #pragma unroll
        for (int cc = 0; cc < 4; cc++) {
            const float* mp = m + (size_t)(c4 + cc) * HWp;
            float v00 = mp[y0c * WW + x0c], v01 = mp[y0c * WW + x1c];
            float v10 = mp[y1c * WW + x0c], v11 = mp[y1c * WW + x1c];
            float v = (1.f - wy) * ((1.f - wx) * v00 + wx * v01)
                    + wy * ((1.f - wx) * v10 + wx * v11);
            r[cc] = f2bf(v);
        }
        o.x = r[0]; o.y = r[1]; o.z = r[2]; o.w = r[3];
    }
    *(ushort4*)(up + (size_t)p * 128 + c4) = o;
}

// ---------------------------------------------------------------------------
extern "C" void kernel_launch(void* const* d_in, const int* in_sizes, int n_in,
                              void* d_out, int out_size, void* d_ws, size_t ws_size,
                              hipStream_t stream)
{
    const float* x       = (const float*)d_in[0];
    const float* dconv_w = (const float*)d_in[1];
    const float* dconv_b = (const float*)d_in[2];
    const float* lvl_emb = (const float*)d_in[3];
    const float* W_off   = (const float*)d_in[4];
    const float* b_off   = (const float*)d_in[5];
    const float* W_attn  = (const float*)d_in[6];
    const float* b_attn  = (const float*)d_in[7];
    const float* W_val   = (const float*)d_in[8];
    const float* b_val   = (const float*)d_in[9];
    const float* W_out   = (const float*)d_in[10];
    const float* b_out   = (const float*)d_in[11];
    const float* ln1_g   = (const float*)d_in[12];
    const float* ln1_b   = (const float*)d_in[13];
    const float* W_ff1   = (const float*)d_in[14];
    const float* b_ff1   = (const float*)d_in[15];
    const float* W_ff2   = (const float*)d_in[16];
    const float* b_ff2   = (const float*)d_in[17];
    const float* ln2_g   = (const float*)d_in[18];
    const float* ln2_b   = (const float*)d_in[19];
    const float* merge_w = (const float*)d_in[20];
    const float* merge_b = (const float*)d_in[21];
    const float* uconv_w = (const float*)d_in[22];
    const float* uconv_b = (const float*)d_in[23];

    char* wsb = (char*)d_ws;
    unsigned short* xp       = (unsigned short*)(wsb);               // 20,320,256 B (4,82,242,128)
    unsigned short* up       = (unsigned short*)(wsb + 20320256);    //  5,080,064 B (82,242,128)
    float*          src      = (float*)(wsb + 25400320);             //  9,830,400 B
    unsigned short* srcb     = (unsigned short*)(wsb + 35230720);    //  4,915,200 B
    float*          pos      = (float*)(wsb + 40145920);             //  9,830,400 B
    unsigned short* qb       = (unsigned short*)(wsb + 49976320);    //  4,915,200 B
    unsigned short* valb     = (unsigned short*)(wsb + 54891520);    //  4,915,200 B
    _Float16*       attnh    = (_Float16*)(wsb + 59806720);          //  4,915,200 B
    unsigned short* attnoutb = (unsigned short*)(wsb + 69637120);    //  4,915,200 B
    unsigned short* ff1b     = (unsigned short*)(wsb + 84382720);    // 19,660,800 B
    unsigned short* wb       = (unsigned short*)(wsb + 104043520);   //  1,114,112 B
    unsigned short* dconv_wb = (unsigned short*)(wsb + 105452544);   //    294,912 B
    unsigned short* uconv_wb = (unsigned short*)(wsb + 105747456);   //    294,912 B
    unsigned short* wcat     = (unsigned short*)(wsb + 106042368);   //    294,912 B
    float*          bcat     = (float*)(wsb + 106337280);            //      4,608 B (end 106,341,888)
    // aliases (lifetimes disjoint):
    _Float16*       offh     = (_Float16*)xp;    // layers: xp dead after dconv gemm
    unsigned short* merge_in = up;               // before upsample writes up
    float*          mbuf     = (float*)valb;     // after layers
    float* outp = (float*)d_out;

    // bf16 linear weight table offsets (elements)
    unsigned short* W_val_b  = wb;
    unsigned short* W_out_b  = wb + 49152;
    unsigned short* W_ff1_b  = wb + 98304;
    unsigned short* W_ff2_b  = wb + 294912;
    unsigned short* merge_wb = wb + 491520;

    // 0) one-dispatch prep (weights, halo, pos) + input transpose
    prep_all<<<13831, 256, 0, stream>>>(
        W_val, W_out, W_ff1, W_ff2, merge_w, W_off, b_off, W_attn, b_attn,
        dconv_w, uconv_w, lvl_emb,
        wb, wcat, bcat, dconv_wb, uconv_wb, xp, pos);
    nchw_to_nhwc_pad<<<1280, 256, 0, stream>>>(x, xp);

    // 1) downsample conv (implicit GEMM) -> src fp32 + srcb bf16 + qb, relu
    conv3x3_gemm<0><<<dim3(2, 150), 256, 0, stream>>>(
        xp, dconv_wb, dconv_b, src, srcb, pos, qb);

    // 2) encoder layers
    for (int i = 0; i < 3; i++) {
        gemm_oav<<<dim3(8, 150), 256, 0, stream>>>(
            qb, srcb,
            wcat + (size_t)i * 49152, bcat + i * 384,
            W_val_b + (size_t)i * 16384, b_val + i * 128,
            offh, attnh, valb);
        deform_sample<<<dim3(150, 8), 256, 0, stream>>>(valb, offh, attnh, attnoutb);
        gemm_ln<false><<<300, 256, 0, stream>>>(
            attnoutb, W_out_b + (size_t)i * 16384, b_out + i * 128,
            ln1_g + i * 128, ln1_b + i * 128, src, srcb, nullptr, nullptr, 128);
        gemm_bf16<false, true, 1><<<dim3(8, 150), 256, 0, stream>>>(
            srcb, W_ff1_b + (size_t)i * 65536, b_ff1 + i * 512,
            nullptr, ff1b, LQ, 512, 128);
        gemm_ln<true><<<300, 256, 0, stream>>>(
            ff1b, W_ff2_b + (size_t)i * 65536, b_ff2 + i * 128,
            ln2_g + i * 128, ln2_b + i * 128, src, srcb, pos, qb, 512);
    }

    // 3) merge 1x1 conv, weights-as-A trick: mbuf[128,4800]
    merge_gather<<<2400, 256, 0, stream>>>(src, merge_in);
    gemm_bf16<true, true, 0><<<dim3(75, 1), 256, 0, stream>>>(
        merge_wb, merge_in, merge_b, mbuf, nullptr, 128, 4800, 512);

    // 4) bilinear 2x upsample -> padded NHWC bf16
    upsample_nhwc<<<2482, 256, 0, stream>>>(mbuf, up);

    // 5) uconv (implicit GEMM, transposed store) -> d_out (128,19200), relu
    conv3x3_gemm<1><<<dim3(2, 150), 256, 0, stream>>>(
        up, uconv_wb, uconv_b, outp, nullptr, nullptr, nullptr);
}

// Round 7
// 507.142 us; speedup vs baseline: 3.1970x; 1.0460x over previous
//
#include <hip/hip_runtime.h>
#include <math.h>
#include <cstddef>

// Problem constants
#define LQ   19200          // NL*H*W tokens
#define HH   40
#define WW   120
#define HWp  4800
#define CCh  128
#define NHd  8
#define NLv  4
#define NPt  4
#define RHs  80
#define RWs  240

typedef __attribute__((ext_vector_type(8))) short bf16x8;
typedef __attribute__((ext_vector_type(4))) float f32x4;
typedef __attribute__((ext_vector_type(8))) _Float16 h16x8;
typedef __attribute__((address_space(1))) const unsigned int GUI;
typedef __attribute__((address_space(3))) unsigned int LUI;

__device__ inline unsigned short f2bf(float f) {
    unsigned int u = __float_as_uint(f);
    u += 0x7fffu + ((u >> 16) & 1u);        // round-to-nearest-even
    return (unsigned short)(u >> 16);
}
__device__ inline float bf2f(unsigned int lo16) { return __uint_as_float(lo16 << 16); }

// ---------------------------------------------------------------------------
// bf16 MFMA GEMM: Out[M,N] = A[M,K] @ Bw[N,K]^T + bias, opt relu.
// BIAS_ROW: bias indexed by row (weights-as-A transposed trick).
// OMODE: 0 = fp32 OutF; 1 = bf16 OutB; 2 = both.
// ---------------------------------------------------------------------------
template<bool BIAS_ROW, bool RELU, int OMODE>
__global__ __launch_bounds__(256) void gemm_bf16(
    const unsigned short* __restrict__ A,
    const unsigned short* __restrict__ Bw,
    const float* __restrict__ bias,
    float* __restrict__ OutF, unsigned short* __restrict__ OutB,
    int M, int N, int K)
{
    constexpr int BM = 128, BN = 64, BK = 32;
    __shared__ unsigned short As[BM * BK];   // row-major [m][k]
    __shared__ unsigned short Bs[BN * BK];
    const int bm = blockIdx.y * BM, bn = blockIdx.x * BN;
    const int tid = threadIdx.x;
    const int wid = tid >> 6, lane = tid & 63;
    const int wm = (wid & 1) * 64, wn = (wid >> 1) * 32;
    const int lm = lane & 15, lqd = lane >> 4;

    f32x4 acc[4][2] = {};

    const int arow = lane >> 2;          // 0..15 within a 16-row chunk
    const int akc  = (lane & 3) * 8;     // k element offset (16 B granules)
    const unsigned short* aG0 = A  + (size_t)(bm + wid * 32 +      arow) * K + akc;
    const unsigned short* aG1 = A  + (size_t)(bm + wid * 32 + 16 + arow) * K + akc;
    const unsigned short* bG  = Bw + (size_t)(bn + wid * 16 +      arow) * K + akc;
    unsigned short* aL0 = As + wid * 1024 + lane * 8;
    unsigned short* aL1 = As + wid * 1024 + 512 + lane * 8;
    unsigned short* bL  = Bs + wid * 512 + lane * 8;

    for (int k0 = 0; k0 < K; k0 += BK) {
        __builtin_amdgcn_global_load_lds((GUI*)(aG0 + k0), (LUI*)aL0, 16, 0, 0);
        __builtin_amdgcn_global_load_lds((GUI*)(aG1 + k0), (LUI*)aL1, 16, 0, 0);
        __builtin_amdgcn_global_load_lds((GUI*)(bG  + k0), (LUI*)bL,  16, 0, 0);
        __syncthreads();
        bf16x8 a[4], b[2];
        #pragma unroll
        for (int i = 0; i < 4; i++)
            a[i] = *(const bf16x8*)(As + (wm + i * 16 + lm) * BK + lqd * 8);
        #pragma unroll
        for (int j = 0; j < 2; j++)
            b[j] = *(const bf16x8*)(Bs + (wn + j * 16 + lm) * BK + lqd * 8);
        #pragma unroll
        for (int i = 0; i < 4; i++)
            #pragma unroll
            for (int j = 0; j < 2; j++)
                acc[i][j] = __builtin_amdgcn_mfma_f32_16x16x32_bf16(a[i], b[j], acc[i][j], 0, 0, 0);
        __syncthreads();
    }

    #pragma unroll
    for (int i = 0; i < 4; i++) {
        int row0 = bm + wm + i * 16 + lqd * 4;
        #pragma unroll
        for (int j = 0; j < 2; j++) {
            int col = bn + wn + j * 16 + lm;
            float bc = BIAS_ROW ? 0.f : bias[col];
            #pragma unroll
            for (int r = 0; r < 4; r++) {
                int row = row0 + r;
                float v = acc[i][j][r] + (BIAS_ROW ? bias[row] : bc);
                if (RELU) v = fmaxf(v, 0.f);
                size_t o = (size_t)row * N + col;
                if (OMODE == 0) OutF[o] = v;
                else if (OMODE == 1) OutB[o] = f2bf(v);
                else { OutF[o] = v; OutB[o] = f2bf(v); }
            }
        }
    }
}

// ---------------------------------------------------------------------------
// Merged off/attn + val GEMM for one layer. Grid dim3(8, 150), BM=128, K=128.
// bx<6: A=qb, W=Woa(384x128): col<256 -> fp16 off (stride 256);
//       col>=256 -> softmax16 -> fp16 attn (stride 128).
// bx>=6: A=srcb, W=Wv(128x128): bf16 val in plane layout [l][h][4800][16].
// ---------------------------------------------------------------------------
__global__ __launch_bounds__(256) void gemm_oav(
    const unsigned short* __restrict__ Aq,
    const unsigned short* __restrict__ Asrc,
    const unsigned short* __restrict__ Woa, const float* __restrict__ boa,
    const unsigned short* __restrict__ Wv,  const float* __restrict__ bv,
    _Float16* __restrict__ OutH, _Float16* __restrict__ OutH2,
    unsigned short* __restrict__ OutV)
{
    constexpr int BK = 32, K = 128;
    __shared__ unsigned short As[128 * BK];
    __shared__ unsigned short Bs[64 * BK];
    const int bx = blockIdx.x;
    const bool isv = bx >= 6;
    const unsigned short* A  = isv ? Asrc : Aq;
    const unsigned short* Bw = isv ? Wv : Woa;
    const float* bias = isv ? bv : boa;
    const int bn = isv ? (bx - 6) * 64 : bx * 64;
    const int bm = blockIdx.y * 128;
    const int tid = threadIdx.x;
    const int wid = tid >> 6, lane = tid & 63;
    const int wm = (wid & 1) * 64, wn = (wid >> 1) * 32;
    const int lm = lane & 15, lqd = lane >> 4;

    f32x4 acc[4][2] = {};

    const int arow = lane >> 2;
    const int akc  = (lane & 3) * 8;
    const unsigned short* aG0 = A  + (size_t)(bm + wid * 32 +      arow) * K + akc;
    const unsigned short* aG1 = A  + (size_t)(bm + wid * 32 + 16 + arow) * K + akc;
    const unsigned short* bG  = Bw + (size_t)(bn + wid * 16 +      arow) * K + akc;
    unsigned short* aL0 = As + wid * 1024 + lane * 8;
    unsigned short* aL1 = As + wid * 1024 + 512 + lane * 8;
    unsigned short* bL  = Bs + wid * 512 + lane * 8;

    for (int k0 = 0; k0 < K; k0 += BK) {
        __builtin_amdgcn_global_load_lds((GUI*)(aG0 + k0), (LUI*)aL0, 16, 0, 0);
        __builtin_amdgcn_global_load_lds((GUI*)(aG1 + k0), (LUI*)aL1, 16, 0, 0);
        __builtin_amdgcn_global_load_lds((GUI*)(bG  + k0), (LUI*)bL,  16, 0, 0);
        __syncthreads();
        bf16x8 a[4], b[2];
        #pragma unroll
        for (int i = 0; i < 4; i++)
            a[i] = *(const bf16x8*)(As + (wm + i * 16 + lm) * BK + lqd * 8);
        #pragma unroll
        for (int j = 0; j < 2; j++)
            b[j] = *(const bf16x8*)(Bs + (wn + j * 16 + lm) * BK + lqd * 8);
        #pragma unroll
        for (int i = 0; i < 4; i++)
            #pragma unroll
            for (int j = 0; j < 2; j++)
                acc[i][j] = __builtin_amdgcn_mfma_f32_16x16x32_bf16(a[i], b[j], acc[i][j], 0, 0, 0);
        __syncthreads();
    }

    #pragma unroll
    for (int i = 0; i < 4; i++) {
        int row0 = bm + wm + i * 16 + lqd * 4;
        #pragma unroll
        for (int j = 0; j < 2; j++) {
            int col = bn + wn + j * 16 + lm;
            float bc = bias[col];
            if (!isv) {
                if (col < 256) {
                    #pragma unroll
                    for (int r = 0; r < 4; r++)
                        OutH[(size_t)(row0 + r) * 256 + col] = (_Float16)(acc[i][j][r] + bc);
                } else {
                    #pragma unroll
                    for (int r = 0; r < 4; r++) {
                        float v = acc[i][j][r] + bc;
                        float m = v;
                        #pragma unroll
                        for (int msk = 1; msk < 16; msk <<= 1)
                            m = fmaxf(m, __shfl_xor(m, msk));
                        float e = __expf(v - m);
                        float s = e;
                        #pragma unroll
                        for (int msk = 1; msk < 16; msk <<= 1)
                            s += __shfl_xor(s, msk);
                        OutH2[(size_t)(row0 + r) * 128 + (col - 256)] = (_Float16)(e / s);
                    }
                }
            } else {
                #pragma unroll
                for (int r = 0; r < 4; r++) {
                    int row = row0 + r;
                    int plane = (row / HWp) * 8 + (col >> 4);
                    size_t o = ((size_t)plane * HWp + (row % HWp)) * 16 + (col & 15);
                    OutV[o] = f2bf(acc[i][j][r] + bc);
                }
            }
        }
    }
}

// ---------------------------------------------------------------------------
// LN-fused GEMM: delta[M,128] = A[M,K] @ Bw[128,K]^T + bias; then
// y = LayerNorm(srcF + delta) * g + b2; writes srcF(fp32), srcB(bf16).
// BM=64, BN=128 (block holds full rows). Used for the out-proj + LN1.
// ---------------------------------------------------------------------------
__global__ __launch_bounds__(256) void gemm_ln(
    const unsigned short* __restrict__ A,
    const unsigned short* __restrict__ Bw,
    const float* __restrict__ bias,
    const float* __restrict__ g, const float* __restrict__ b2,
    float* __restrict__ srcF, unsigned short* __restrict__ srcB,
    int K)
{
    __shared__ __align__(16) unsigned char smem[12288];
    unsigned short* As = (unsigned short*)smem;            // 64 x 32
    unsigned short* Bs = (unsigned short*)(smem + 4096);   // 128 x 32
    const int bm = blockIdx.x * 64;
    const int tid = threadIdx.x;
    const int wid = tid >> 6, lane = tid & 63;
    const int wm = (wid & 1) * 32, wn = (wid >> 1) * 64;
    const int lm = lane & 15, lqd = lane >> 4;

    f32x4 acc[2][4] = {};

    const int srow = lane >> 2;
    const int skc  = (lane & 3) * 8;
    const unsigned short* aG  = A  + (size_t)(bm + wid * 16 + srow) * K + skc;
    const unsigned short* bG0 = Bw + (size_t)(wid * 16 + srow) * K + skc;
    const unsigned short* bG1 = Bw + (size_t)(64 + wid * 16 + srow) * K + skc;
    unsigned short* aL  = As + wid * 512 + lane * 8;
    unsigned short* bL0 = Bs + wid * 512 + lane * 8;
    unsigned short* bL1 = Bs + 2048 + wid * 512 + lane * 8;

    for (int k0 = 0; k0 < K; k0 += 32) {
        __builtin_amdgcn_global_load_lds((GUI*)(aG  + k0), (LUI*)aL,  16, 0, 0);
        __builtin_amdgcn_global_load_lds((GUI*)(bG0 + k0), (LUI*)bL0, 16, 0, 0);
        __builtin_amdgcn_global_load_lds((GUI*)(bG1 + k0), (LUI*)bL1, 16, 0, 0);
        __syncthreads();
        bf16x8 a[2], b[4];
        #pragma unroll
        for (int i = 0; i < 2; i++)
            a[i] = *(const bf16x8*)(As + (wm + i * 16 + lm) * 32 + lqd * 8);
        #pragma unroll
        for (int j = 0; j < 4; j++)
            b[j] = *(const bf16x8*)(Bs + (wn + j * 16 + lm) * 32 + lqd * 8);
        #pragma unroll
        for (int i = 0; i < 2; i++)
            #pragma unroll
            for (int j = 0; j < 4; j++)
                acc[i][j] = __builtin_amdgcn_mfma_f32_16x16x32_bf16(a[i], b[j], acc[i][j], 0, 0, 0);
        __syncthreads();
    }

    float z[2][4][4];
    #pragma unroll
    for (int i = 0; i < 2; i++) {
        #pragma unroll
        for (int j = 0; j < 4; j++) {
            int col = wn + j * 16 + lm;
            float bc = bias[col];
            #pragma unroll
            for (int r = 0; r < 4; r++) {
                int row = bm + wm + i * 16 + lqd * 4 + r;
                z[i][j][r] = acc[i][j][r] + bc + srcF[(size_t)row * 128 + col];
            }
        }
    }

    float* red = (float*)smem;      // 256 floats
    #pragma unroll
    for (int i = 0; i < 2; i++) {
        #pragma unroll
        for (int r = 0; r < 4; r++) {
            float s = z[i][0][r] + z[i][1][r] + z[i][2][r] + z[i][3][r];
            float q = z[i][0][r] * z[i][0][r] + z[i][1][r] * z[i][1][r]
                    + z[i][2][r] * z[i][2][r] + z[i][3][r] * z[i][3][r];
            #pragma unroll
            for (int msk = 1; msk < 16; msk <<= 1) {
                s += __shfl_xor(s, msk);
                q += __shfl_xor(q, msk);
            }
            if (lm == 0) {
                int rl = wm + i * 16 + lqd * 4 + r;
                red[(wid >> 1) * 128 + rl] = s;
                red[(wid >> 1) * 128 + 64 + rl] = q;
            }
        }
    }
    __syncthreads();

    float mean[2][4], inv[2][4];
    #pragma unroll
    for (int i = 0; i < 2; i++) {
        #pragma unroll
        for (int r = 0; r < 4; r++) {
            int rl = wm + i * 16 + lqd * 4 + r;
            float s = red[rl] + red[128 + rl];
            float q = red[64 + rl] + red[192 + rl];
            float m = s * (1.0f / 128.0f);
            float v = q * (1.0f / 128.0f) - m * m;
            mean[i][r] = m;
            inv[i][r] = rsqrtf(v + 1e-5f);
        }
    }

    #pragma unroll
    for (int i = 0; i < 2; i++) {
        #pragma unroll
        for (int j = 0; j < 4; j++) {
            int col = wn + j * 16 + lm;
            float gc = g[col], bc2 = b2[col];
            #pragma unroll
            for (int r = 0; r < 4; r++) {
                int row = bm + wm + i * 16 + lqd * 4 + r;
                float y = (z[i][j][r] - mean[i][r]) * inv[i][r] * gc + bc2;
                size_t o = (size_t)row * 128 + col;
                srcF[o] = y;
                srcB[o] = f2bf(y);
            }
        }
    }
}

// ---------------------------------------------------------------------------
// Fused FFN: per 32-token block:
//   f = relu(srcb @ Wff1^T + bff1)      (32 x 512, kept in LDS as bf16)
//   delta = f @ Wff2^T + bff2           (32 x 128)
//   y = LayerNorm(srcF + delta) * g + b2
// WQ: also write qb = bf16(y + pos). WMERGE: write only the merge-layout
// bf16 output mergeb[pix][n*128+c] (final layer). Otherwise write srcF+srcB.
// Weight fragments are read directly from global (L2-hot, reused by 600 blocks).
// ---------------------------------------------------------------------------
template<bool WQ, bool WMERGE>
__global__ __launch_bounds__(256) void ff_fused(
    const unsigned short* __restrict__ srcb, const float* __restrict__ srcF_in,
    const unsigned short* __restrict__ Wff1, const float* __restrict__ bff1,
    const unsigned short* __restrict__ Wff2, const float* __restrict__ bff2,
    const float* __restrict__ g, const float* __restrict__ b2,
    float* __restrict__ outF, unsigned short* __restrict__ outB,
    const float* __restrict__ pos, unsigned short* __restrict__ qb,
    unsigned short* __restrict__ mergeb)
{
    __shared__ unsigned short fs[32 * 520];     // 33,280 B ff activation
    __shared__ float red[4][2][32];             // per-wave LN partials
    const int bm = blockIdx.x * 32;
    const int tid = threadIdx.x;
    const int wid = tid >> 6, lane = tid & 63;
    const int lm = lane & 15, lqd = lane >> 4;

    // ---- Phase 1: f = relu(y1 @ Wff1^T + b); wave wid owns cols [wid*128,+128)
    {
        f32x4 acc[2][8] = {};
        const int wn = wid * 128;
        for (int k0 = 0; k0 < 128; k0 += 32) {
            bf16x8 a[2], b[8];
            #pragma unroll
            for (int i = 0; i < 2; i++)
                a[i] = *(const bf16x8*)(srcb + (size_t)(bm + i * 16 + lm) * 128 + k0 + lqd * 8);
            #pragma unroll
            for (int j = 0; j < 8; j++)
                b[j] = *(const bf16x8*)(Wff1 + (size_t)(wn + j * 16 + lm) * 128 + k0 + lqd * 8);
            #pragma unroll
            for (int i = 0; i < 2; i++)
                #pragma unroll
                for (int j = 0; j < 8; j++)
                    acc[i][j] = __builtin_amdgcn_mfma_f32_16x16x32_bf16(a[i], b[j], acc[i][j], 0, 0, 0);
        }
        #pragma unroll
        for (int i = 0; i < 2; i++) {
            #pragma unroll
            for (int j = 0; j < 8; j++) {
                int col = wn + j * 16 + lm;
                float bc = bff1[col];
                #pragma unroll
                for (int r = 0; r < 4; r++) {
                    int row = i * 16 + lqd * 4 + r;
                    fs[row * 520 + col] = f2bf(fmaxf(acc[i][j][r] + bc, 0.f));
                }
            }
        }
    }
    __syncthreads();

    // ---- Phase 2: delta = f @ Wff2^T; wave wid owns cols [wid*32,+32)
    f32x4 acc2[2][2] = {};
    const int wn2 = wid * 32;
    for (int k0 = 0; k0 < 512; k0 += 32) {
        bf16x8 a[2], b[2];
        #pragma unroll
        for (int i = 0; i < 2; i++)
            a[i] = *(const bf16x8*)(fs + (i * 16 + lm) * 520 + k0 + lqd * 8);
        #pragma unroll
        for (int j = 0; j < 2; j++)
            b[j] = *(const bf16x8*)(Wff2 + (size_t)(wn2 + j * 16 + lm) * 512 + k0 + lqd * 8);
        #pragma unroll
        for (int i = 0; i < 2; i++)
            #pragma unroll
            for (int j = 0; j < 2; j++)
                acc2[i][j] = __builtin_amdgcn_mfma_f32_16x16x32_bf16(a[i], b[j], acc2[i][j], 0, 0, 0);
    }

    // ---- Phase 3: z = delta + bias + src, LayerNorm
    float z[2][2][4];
    #pragma unroll
    for (int i = 0; i < 2; i++) {
        #pragma unroll
        for (int j = 0; j < 2; j++) {
            int col = wn2 + j * 16 + lm;
            float bc = bff2[col];
            #pragma unroll
            for (int r = 0; r < 4; r++) {
                int row = bm + i * 16 + lqd * 4 + r;
                z[i][j][r] = acc2[i][j][r] + bc + srcF_in[(size_t)row * 128 + col];
            }
        }
    }
    #pragma unroll
    for (int i = 0; i < 2; i++) {
        #pragma unroll
        for (int r = 0; r < 4; r++) {
            float s = z[i][0][r] + z[i][1][r];
            float q = z[i][0][r] * z[i][0][r] + z[i][1][r] * z[i][1][r];
            #pragma unroll
            for (int msk = 1; msk < 16; msk <<= 1) {
                s += __shfl_xor(s, msk);
                q += __shfl_xor(q, msk);
            }
            if (lm == 0) {
                int rl = i * 16 + lqd * 4 + r;
                red[wid][0][rl] = s;
                red[wid][1][rl] = q;
            }
        }
    }
    __syncthreads();

    #pragma unroll
    for (int i = 0; i < 2; i++) {
        float mean[4], inv[4];
        #pragma unroll
        for (int r = 0; r < 4; r++) {
            int rl = i * 16 + lqd * 4 + r;
            float s = red[0][0][rl] + red[1][0][rl] + red[2][0][rl] + red[3][0][rl];
            float q = red[0][1][rl] + red[1][1][rl] + red[2][1][rl] + red[3][1][rl];
            float m = s * (1.0f / 128.0f);
            float v = q * (1.0f / 128.0f) - m * m;
            mean[r] = m;
            inv[r] = rsqrtf(v + 1e-5f);
        }
        #pragma unroll
        for (int j = 0; j < 2; j++) {
            int col = wn2 + j * 16 + lm;
            float gc = g[col], bc2 = b2[col];
            #pragma unroll
            for (int r = 0; r < 4; r++) {
                int row = bm + i * 16 + lqd * 4 + r;
                float y = (z[i][j][r] - mean[r]) * inv[r] * gc + bc2;
                if constexpr (WMERGE) {
                    int n = row / HWp, pix = row % HWp;
                    mergeb[(size_t)pix * 512 + n * 128 + col] = f2bf(y);
                } else {
                    size_t o = (size_t)row * 128 + col;
                    outF[o] = y;
                    outB[o] = f2bf(y);
                    if constexpr (WQ) qb[o] = f2bf(y + pos[o]);
                }
            }
        }
    }
}

// ---------------------------------------------------------------------------
// Implicit-GEMM 3x3 conv from padded NHWC bf16 input, tap-major weights.
// MODE 0: dconv  — X:(4,82,242,128), stride 2, out: src fp32 + srcb bf16 +
//                  qb = bf16(src+pos), relu.
// MODE 1: uconv  — X:(82,242,128), stride 1, out: d_out fp32 (128,19200)
//                  via LDS-transposed store, relu.
// ---------------------------------------------------------------------------
template<int MODE>
__global__ __launch_bounds__(256) void conv3x3_gemm(
    const unsigned short* __restrict__ X,
    const unsigned short* __restrict__ Wp,
    const float* __restrict__ bias,
    float* __restrict__ OutF, unsigned short* __restrict__ OutB,
    const float* __restrict__ pos, unsigned short* __restrict__ Qb)
{
    constexpr int BM = 128, BN = 64, BK = 32;
    constexpr int SMEM = (MODE == 1) ? 33792 : 12288;
    __shared__ __align__(16) unsigned char smem[SMEM];
    unsigned short* As = (unsigned short*)smem;            // 128*32
    unsigned short* Bs = (unsigned short*)(smem + 8192);   // 64*32
    const int bm = blockIdx.y * BM, bn = blockIdx.x * BN;
    const int tid = threadIdx.x;
    const int wid = tid >> 6, lane = tid & 63;
    const int wm = (wid & 1) * 64, wn = (wid >> 1) * 32;
    const int lm = lane & 15, lqd = lane >> 4;

    f32x4 acc[4][2] = {};

    const int arow = lane >> 2;
    const int akc  = (lane & 3) * 8;
    const int r0 = bm + wid * 32 + arow;
    const int r1 = r0 + 16;
    size_t bA0, bA1;
    if (MODE == 0) {
        int n0 = r0 / HWp, rem0 = r0 % HWp, oh0 = rem0 / WW, ow0 = rem0 % WW;
        int n1 = r1 / HWp, rem1 = r1 % HWp, oh1 = rem1 / WW, ow1 = rem1 % WW;
        bA0 = ((size_t)(n0 * 82 + oh0 * 2) * 242 + ow0 * 2) * 128;
        bA1 = ((size_t)(n1 * 82 + oh1 * 2) * 242 + ow1 * 2) * 128;
    } else {
        int y0 = r0 / RWs, x0 = r0 % RWs;
        int y1 = r1 / RWs, x1 = r1 % RWs;
        bA0 = ((size_t)y0 * 242 + x0) * 128;
        bA1 = ((size_t)y1 * 242 + x1) * 128;
    }
    const unsigned short* bG = Wp + (size_t)(bn + wid * 16 + arow) * 1152 + akc;
    unsigned short* aL0 = As + wid * 1024 + lane * 8;
    unsigned short* aL1 = As + wid * 1024 + 512 + lane * 8;
    unsigned short* bL  = Bs + wid * 512 + lane * 8;

    for (int chunk = 0; chunk < 36; chunk++) {
        int tap = chunk >> 2;
        int cpart = (chunk & 3) << 5;
        int ky = tap / 3, kx = tap % 3;
        int toff = (ky * 242 + kx) * 128 + cpart + akc;
        __builtin_amdgcn_global_load_lds((GUI*)(X + bA0 + toff), (LUI*)aL0, 16, 0, 0);
        __builtin_amdgcn_global_load_lds((GUI*)(X + bA1 + toff), (LUI*)aL1, 16, 0, 0);
        __builtin_amdgcn_global_load_lds((GUI*)(bG + chunk * 32), (LUI*)bL, 16, 0, 0);
        __syncthreads();
        bf16x8 a[4], b[2];
        #pragma unroll
        for (int i = 0; i < 4; i++)
            a[i] = *(const bf16x8*)(As + (wm + i * 16 + lm) * BK + lqd * 8);
        #pragma unroll
        for (int j = 0; j < 2; j++)
            b[j] = *(const bf16x8*)(Bs + (wn + j * 16 + lm) * BK + lqd * 8);
        #pragma unroll
        for (int i = 0; i < 4; i++)
            #pragma unroll
            for (int j = 0; j < 2; j++)
                acc[i][j] = __builtin_amdgcn_mfma_f32_16x16x32_bf16(a[i], b[j], acc[i][j], 0, 0, 0);
        __syncthreads();
    }

    if (MODE == 0) {
        #pragma unroll
        for (int i = 0; i < 4; i++) {
            int row0 = bm + wm + i * 16 + lqd * 4;
            #pragma unroll
            for (int j = 0; j < 2; j++) {
                int col = bn + wn + j * 16 + lm;
                float bc = bias[col];
                #pragma unroll
                for (int r = 0; r < 4; r++) {
                    float v = fmaxf(acc[i][j][r] + bc, 0.f);
                    size_t o = (size_t)(row0 + r) * 128 + col;
                    OutF[o] = v;
                    OutB[o] = f2bf(v);
                    Qb[o] = f2bf(v + pos[o]);
                }
            }
        }
    } else {
        float* Ts = (float*)smem;                 // 64 x 132 floats
        #pragma unroll
        for (int i = 0; i < 4; i++) {
            int lr0 = wm + i * 16 + lqd * 4;
            #pragma unroll
            for (int j = 0; j < 2; j++) {
                int lc = wn + j * 16 + lm;
                float bc = bias[bn + lc];
                #pragma unroll
                for (int r = 0; r < 4; r++)
                    Ts[lc * 132 + lr0 + r] = fmaxf(acc[i][j][r] + bc, 0.f);
            }
        }
        __syncthreads();
        for (int f = tid; f < 64 * 32; f += 256) {
            int ch = f >> 5, p4 = (f & 31) << 2;
            float4 v4 = *(const float4*)(Ts + ch * 132 + p4);
            *(float4*)(OutF + (size_t)(bn + ch) * 19200 + bm + p4) = v4;
        }
    }
}

// ---------------------------------------------------------------------------
// One-dispatch prep: linear weights -> bf16, [W_off;W_attn] concat, conv
// weights tap-major, halo zero, pos embed.
// ---------------------------------------------------------------------------
__global__ void prep_all(
    const float* __restrict__ W_val, const float* __restrict__ W_out,
    const float* __restrict__ W_ff1, const float* __restrict__ W_ff2,
    const float* __restrict__ merge_w,
    const float* __restrict__ Woff, const float* __restrict__ boff,
    const float* __restrict__ Wattn, const float* __restrict__ battn,
    const float* __restrict__ dconv_w, const float* __restrict__ uconv_w,
    const float* __restrict__ lvl_emb,
    unsigned short* __restrict__ wb, unsigned short* __restrict__ wcat,
    float* __restrict__ bcat, unsigned short* __restrict__ dconv_wb,
    unsigned short* __restrict__ uconv_wb, unsigned short* __restrict__ xp,
    float* __restrict__ pos)
{
    int idx = blockIdx.x * 256 + threadIdx.x;
    if (idx < 557056) {
        const float* src; int rel;
        if      (idx <  49152) { src = W_val;   rel = idx;          }
        else if (idx <  98304) { src = W_out;   rel = idx - 49152;  }
        else if (idx < 294912) { src = W_ff1;   rel = idx - 98304;  }
        else if (idx < 491520) { src = W_ff2;   rel = idx - 294912; }
        else                   { src = merge_w; rel = idx - 491520; }
        wb[idx] = f2bf(src[rel]);
    } else if (idx < 705664) {
        int j = idx - 557056;
        if (j < 147456) {
            int layer = j / 49152, r = (j / 128) % 384, c = j & 127;
            float v = (r < 256) ? Woff[((size_t)layer * 256 + r) * 128 + c]
                                : Wattn[((size_t)layer * 128 + (r - 256)) * 128 + c];
            wcat[j] = f2bf(v);
        } else if (j < 148608) {
            int k = j - 147456;
            int layer = k / 384, r = k % 384;
            bcat[k] = (r < 256) ? boff[layer * 256 + r] : battn[layer * 128 + (r - 256)];
        }
    } else if (idx < 853120) {
        int j = idx - 705664;
        int cout = j / 1152, k = j % 1152;
        int tap = k >> 7, cin = k & 127;
        dconv_wb[j] = f2bf(dconv_w[(cout * 128 + cin) * 9 + tap]);
    } else if (idx < 1000576) {
        int j = idx - 853120;
        int cout = j / 1152, k = j % 1152;
        int tap = k >> 7, cin = k & 127;
        uconv_wb[j] = f2bf(uconv_w[(cout * 128 + cin) * 9 + tap]);
    } else if (idx < 1083008) {
        int j = idx - 1000576;                 // < 4*644*32
        int c4 = (j & 31) << 2;
        int t = j >> 5;
        int p = t % 644, n = t / 644;
        int y, x;
        if (p < 242)      { y = 0;       x = p;       }
        else if (p < 484) { y = 81;      x = p - 242; }
        else if (p < 564) { y = p - 483; x = 0;       }
        else              { y = p - 563; x = 241;     }
        ushort4 z = {0, 0, 0, 0};
        *(ushort4*)(xp + (((size_t)(n * 82 + y)) * 242 + x) * 128 + c4) = z;
    } else if (idx < 3540608) {
        int j = idx - 1083008;                 // < LQ*128
        int c = j & 127;
        int q = j >> 7;
        int n = q / HWp, pix = q % HWp;
        int h = pix / WW, w = pix % WW;
        int cc = (c < 64) ? c : (c - 64);
        float coord = (c < 64) ? (float)(h + 1) : (float)(w + 1);
        float denom = (c < 64) ? 40.0f : 120.0f;
        float e = coord / (denom + 1e-6f) * 6.283185307179586f;
        float expo = (float)(cc & ~1) * (1.0f / 64.0f);
        float dim_t = __expf(expo * 9.2103403719761836f);   // 10000^expo
        float p = e / dim_t;
        float v = (cc & 1) ? __cosf(p) : __sinf(p);
        pos[j] = v + lvl_emb[n * CCh + c];
    }
}

// NCHW fp32 (4,128,80,240) -> padded NHWC bf16 (4,82,242,128)
// One block per (n, y, 32-channel tile): grid 4*80*4 = 1280.
__global__ __launch_bounds__(256) void nchw_to_nhwc_pad(
    const float* __restrict__ x, unsigned short* __restrict__ xp)
{
    __shared__ unsigned short t[240 * 36];       // [x][c] pad to 36
    int b = blockIdx.x;
    int ct = b & 3;
    int tmp = b >> 2;
    int y = tmp % 80, n = tmp / 80;
    const float* xin = x + (((size_t)(n * 128 + ct * 32)) * 80 + y) * 240;
    for (int f = threadIdx.x; f < 32 * 240; f += 256) {
        int c = f / 240, xc = f % 240;
        t[xc * 36 + c] = f2bf(xin[(size_t)c * 19200 + xc]);
    }
    __syncthreads();
    unsigned short* out = xp + (((size_t)(n * 82 + y + 1)) * 242 + 1) * 128 + ct * 32;
    for (int f = threadIdx.x; f < 240 * 8; f += 256) {
        int xc = f >> 3, c4 = (f & 7) << 2;
        ushort4 v = *(const ushort4*)(t + xc * 36 + c4);
        *(ushort4*)(out + (size_t)xc * 128 + c4) = v;
    }
}

__device__ inline void fma8(float* acc, float w, uint4 v)
{
    acc[0] = fmaf(w, __uint_as_float(v.x << 16),          acc[0]);
    acc[1] = fmaf(w, __uint_as_float(v.x & 0xffff0000u),  acc[1]);
    acc[2] = fmaf(w, __uint_as_float(v.y << 16),          acc[2]);
    acc[3] = fmaf(w, __uint_as_float(v.y & 0xffff0000u),  acc[3]);
    acc[4] = fmaf(w, __uint_as_float(v.z << 16),          acc[4]);
    acc[5] = fmaf(w, __uint_as_float(v.z & 0xffff0000u),  acc[5]);
    acc[6] = fmaf(w, __uint_as_float(v.w << 16),          acc[6]);
    acc[7] = fmaf(w, __uint_as_float(v.w & 0xffff0000u),  acc[7]);
}
__device__ inline unsigned int pk2(float a, float b)
{ return (unsigned int)f2bf(a) | ((unsigned int)f2bf(b) << 16); }

// ---------------------------------------------------------------------------
// MS deformable attention sampling. Grid dim3(150, 8): blockIdx.y = head.
// Thread = (query, channel-half).
// ---------------------------------------------------------------------------
__global__ __launch_bounds__(256) void deform_sample(
    const unsigned short* __restrict__ val, const _Float16* __restrict__ off,
    const _Float16* __restrict__ attn, unsigned short* __restrict__ out)
{
    int t = threadIdx.x;
    int q = blockIdx.x * 128 + (t >> 1);
    int half = t & 1;
    int h = blockIdx.y;
    int pix = q % HWp;
    int qy = pix / WW, qx = pix % WW;
    const _Float16* offp = off + (size_t)q * 256 + h * 32;
    const _Float16* ap   = attn + (size_t)q * 128 + h * 16;
    h16x8 ovv[4];
    ovv[0] = *(const h16x8*)(offp);
    ovv[1] = *(const h16x8*)(offp + 8);
    ovv[2] = *(const h16x8*)(offp + 16);
    ovv[3] = *(const h16x8*)(offp + 24);
    h16x8 avv[2];
    avv[0] = *(const h16x8*)(ap);
    avv[1] = *(const h16x8*)(ap + 8);
    const unsigned short* vh = val + half * 8;
    float acc[8] = {};
    #pragma unroll
    for (int l = 0; l < 4; l++) {
        const unsigned short* vb = vh + (size_t)(l * 8 + h) * (HWp * 16);
        #pragma unroll
        for (int p = 0; p < 4; p++) {
            float ox = (float)ovv[l][2 * p];
            float oy = (float)ovv[l][2 * p + 1];
            int ai = l * 4 + p;
            float a = (float)avv[ai >> 3][ai & 7];
            float x = (float)qx + ox;
            float y = (float)qy + oy;
            float xf = floorf(x), yf = floorf(y);
            int x0 = (int)xf, y0 = (int)yf;
            float wx1 = x - xf, wy1 = y - yf;
            float wx0 = 1.f - wx1, wy0 = 1.f - wy1;
            #pragma unroll
            for (int dy = 0; dy < 2; dy++) {
                int yc = y0 + dy;
                bool vy = (unsigned)yc < (unsigned)HH;
                int yci = min(max(yc, 0), HH - 1);
                float wyv = dy ? wy1 : wy0;
                #pragma unroll
                for (int dx = 0; dx < 2; dx++) {
                    int xc = x0 + dx;
                    bool vld = vy && ((unsigned)xc < (unsigned)WW);
                    int xci = min(max(xc, 0), WW - 1);
                    float wgt = vld ? a * wyv * (dx ? wx1 : wx0) : 0.f;
                    uint4 v = *(const uint4*)(vb + (size_t)(yci * WW + xci) * 16);
                    fma8(acc, wgt, v);
                }
            }
        }
    }
    uint4 o = { pk2(acc[0], acc[1]), pk2(acc[2], acc[3]),
                pk2(acc[4], acc[5]), pk2(acc[6], acc[7]) };
    *(uint4*)(out + (size_t)q * CCh + h * 16 + half * 8) = o;
}

// Bilinear 2x upsample -> padded NHWC bf16 (82,242,128), halo zeroed
__global__ void upsample_nhwc(const float* __restrict__ m, unsigned short* __restrict__ up)
{
    unsigned idx = blockIdx.x * 256u + threadIdx.x;   // < 82*242*32
    if (idx >= 82u * 242u * 32u) return;
    int c4 = (idx & 31) << 2;
    int p = idx >> 5;
    int px = p % 242, py = p / 242;
    ushort4 o = {0, 0, 0, 0};
    if (py >= 1 && py <= RHs && px >= 1 && px <= RWs) {
        int y = py - 1, x = px - 1;
        float fy = (y + 0.5f) * 0.5f - 0.5f;
        float fx = (x + 0.5f) * 0.5f - 0.5f;
        float fyf = floorf(fy), fxf = floorf(fx);
        int y0 = (int)fyf, x0 = (int)fxf;
        float wy = fy - fyf, wx = fx - fxf;
        int y0c = max(y0, 0), y1c = min(y0 + 1, HH - 1);
        int x0c = max(x0, 0), x1c = min(x0 + 1, WW - 1);
        unsigned short r[4];
        #pragma unroll
        for (int cc = 0; cc < 4; cc++) {
            const float* mp = m + (size_t)(c4 + cc) * HWp;
            float v00 = mp[y0c * WW + x0c], v01 = mp[y0c * WW + x1c];
            float v10 = mp[y1c * WW + x0c], v11 = mp[y1c * WW + x1c];
            float v = (1.f - wy) * ((1.f - wx) * v00 + wx * v01)
                    + wy * ((1.f - wx) * v10 + wx * v11);
            r[cc] = f2bf(v);
        }
        o.x = r[0]; o.y = r[1]; o.z = r[2]; o.w = r[3];
    }
    *(ushort4*)(up + (size_t)p * 128 + c4) = o;
}

// ---------------------------------------------------------------------------
extern "C" void kernel_launch(void* const* d_in, const int* in_sizes, int n_in,
                              void* d_out, int out_size, void* d_ws, size_t ws_size,
                              hipStream_t stream)
{
    const float* x       = (const float*)d_in[0];
    const float* dconv_w = (const float*)d_in[1];
    const float* dconv_b = (const float*)d_in[2];
    const float* lvl_emb = (const float*)d_in[3];
    const float* W_off   = (const float*)d_in[4];
    const float* b_off   = (const float*)d_in[5];
    const float* W_attn  = (const float*)d_in[6];
    const float* b_attn  = (const float*)d_in[7];
    const float* W_val   = (const float*)d_in[8];
    const float* b_val   = (const float*)d_in[9];
    const float* W_out   = (const float*)d_in[10];
    const float* b_out   = (const float*)d_in[11];
    const float* ln1_g   = (const float*)d_in[12];
    const float* ln1_b   = (const float*)d_in[13];
    const float* W_ff1   = (const float*)d_in[14];
    const float* b_ff1   = (const float*)d_in[15];
    const float* W_ff2   = (const float*)d_in[16];
    const float* b_ff2   = (const float*)d_in[17];
    const float* ln2_g   = (const float*)d_in[18];
    const float* ln2_b   = (const float*)d_in[19];
    const float* merge_w = (const float*)d_in[20];
    const float* merge_b = (const float*)d_in[21];
    const float* uconv_w = (const float*)d_in[22];
    const float* uconv_b = (const float*)d_in[23];

    char* wsb = (char*)d_ws;
    unsigned short* xp       = (unsigned short*)(wsb);               // 20,320,256 B (4,82,242,128)
    unsigned short* up       = (unsigned short*)(wsb + 20320256);    //  5,080,064 B (82,242,128)
    float*          src      = (float*)(wsb + 25400320);             //  9,830,400 B
    unsigned short* srcb     = (unsigned short*)(wsb + 35230720);    //  4,915,200 B
    float*          pos      = (float*)(wsb + 40145920);             //  9,830,400 B
    unsigned short* qb       = (unsigned short*)(wsb + 49976320);    //  4,915,200 B
    unsigned short* valb     = (unsigned short*)(wsb + 54891520);    //  4,915,200 B
    _Float16*       attnh    = (_Float16*)(wsb + 59806720);          //  4,915,200 B
    unsigned short* attnoutb = (unsigned short*)(wsb + 69637120);    //  4,915,200 B
    unsigned short* wb       = (unsigned short*)(wsb + 104043520);   //  1,114,112 B
    unsigned short* dconv_wb = (unsigned short*)(wsb + 105452544);   //    294,912 B
    unsigned short* uconv_wb = (unsigned short*)(wsb + 105747456);   //    294,912 B
    unsigned short* wcat     = (unsigned short*)(wsb + 106042368);   //    294,912 B
    float*          bcat     = (float*)(wsb + 106337280);            //      4,608 B (end 106,341,888)
    // aliases (lifetimes disjoint):
    _Float16*       offh     = (_Float16*)xp;    // layers: xp dead after dconv gemm
    unsigned short* merge_in = up;               // written by layer-2 ff_fused; consumed before upsample writes up
    float*          mbuf     = (float*)valb;     // after layers
    float* outp = (float*)d_out;

    // bf16 linear weight table offsets (elements)
    unsigned short* W_val_b  = wb;
    unsigned short* W_out_b  = wb + 49152;
    unsigned short* W_ff1_b  = wb + 98304;
    unsigned short* W_ff2_b  = wb + 294912;
    unsigned short* merge_wb = wb + 491520;

    // 0) one-dispatch prep (weights, halo, pos) + input transpose
    prep_all<<<13831, 256, 0, stream>>>(
        W_val, W_out, W_ff1, W_ff2, merge_w, W_off, b_off, W_attn, b_attn,
        dconv_w, uconv_w, lvl_emb,
        wb, wcat, bcat, dconv_wb, uconv_wb, xp, pos);
    nchw_to_nhwc_pad<<<1280, 256, 0, stream>>>(x, xp);

    // 1) downsample conv (implicit GEMM) -> src fp32 + srcb bf16 + qb, relu
    conv3x3_gemm<0><<<dim3(2, 150), 256, 0, stream>>>(
        xp, dconv_wb, dconv_b, src, srcb, pos, qb);

    // 2) encoder layers (4 dispatches each)
    for (int i = 0; i < 3; i++) {
        gemm_oav<<<dim3(8, 150), 256, 0, stream>>>(
            qb, srcb,
            wcat + (size_t)i * 49152, bcat + i * 384,
            W_val_b + (size_t)i * 16384, b_val + i * 128,
            offh, attnh, valb);
        deform_sample<<<dim3(150, 8), 256, 0, stream>>>(valb, offh, attnh, attnoutb);
        gemm_ln<<<300, 256, 0, stream>>>(
            attnoutb, W_out_b + (size_t)i * 16384, b_out + i * 128,
            ln1_g + i * 128, ln1_b + i * 128, src, srcb, 128);
        if (i < 2) {
            ff_fused<true, false><<<600, 256, 0, stream>>>(
                srcb, src, W_ff1_b + (size_t)i * 65536, b_ff1 + i * 512,
                W_ff2_b + (size_t)i * 65536, b_ff2 + i * 128,
                ln2_g + i * 128, ln2_b + i * 128,
                src, srcb, pos, qb, nullptr);
        } else {
            ff_fused<false, true><<<600, 256, 0, stream>>>(
                srcb, src, W_ff1_b + (size_t)i * 65536, b_ff1 + i * 512,
                W_ff2_b + (size_t)i * 65536, b_ff2 + i * 128,
                ln2_g + i * 128, ln2_b + i * 128,
                nullptr, nullptr, nullptr, nullptr, merge_in);
        }
    }

    // 3) merge 1x1 conv, weights-as-A trick: mbuf[128,4800]
    gemm_bf16<true, true, 0><<<dim3(75, 1), 256, 0, stream>>>(
        merge_wb, merge_in, merge_b, mbuf, nullptr, 128, 4800, 512);

    // 4) bilinear 2x upsample -> padded NHWC bf16
    upsample_nhwc<<<2482, 256, 0, stream>>>(mbuf, up);

    // 5) uconv (implicit GEMM, transposed store) -> d_out (128,19200), relu
    conv3x3_gemm<1><<<dim3(2, 150), 256, 0, stream>>>(
        up, uconv_wb, uconv_b, outp, nullptr, nullptr, nullptr);
}

// Round 8
// 493.771 us; speedup vs baseline: 3.2836x; 1.0271x over previous
//
#include <hip/hip_runtime.h>
#include <math.h>
#include <cstddef>

// Problem constants
#define LQ   19200          // NL*H*W tokens
#define HH   40
#define WW   120
#define HWp  4800
#define CCh  128
#define NHd  8
#define NLv  4
#define NPt  4
#define RHs  80
#define RWs  240

typedef __attribute__((ext_vector_type(8))) short bf16x8;
typedef __attribute__((ext_vector_type(4))) float f32x4;
typedef __attribute__((ext_vector_type(8))) _Float16 h16x8;
typedef __attribute__((address_space(1))) const unsigned int GUI;
typedef __attribute__((address_space(3))) unsigned int LUI;

__device__ inline unsigned short f2bf(float f) {
    unsigned int u = __float_as_uint(f);
    u += 0x7fffu + ((u >> 16) & 1u);        // round-to-nearest-even
    return (unsigned short)(u >> 16);
}
__device__ inline float bf2f(unsigned int lo16) { return __uint_as_float(lo16 << 16); }

// ---------------------------------------------------------------------------
// bf16 MFMA GEMM: Out[M,N] = A[M,K] @ Bw[N,K]^T + bias, opt relu.
// BIAS_ROW: bias indexed by row (weights-as-A transposed trick).
// OMODE: 0 = fp32 OutF; 1 = bf16 OutB; 2 = both.
// ---------------------------------------------------------------------------
template<bool BIAS_ROW, bool RELU, int OMODE>
__global__ __launch_bounds__(256) void gemm_bf16(
    const unsigned short* __restrict__ A,
    const unsigned short* __restrict__ Bw,
    const float* __restrict__ bias,
    float* __restrict__ OutF, unsigned short* __restrict__ OutB,
    int M, int N, int K)
{
    constexpr int BM = 128, BN = 64, BK = 32;
    __shared__ unsigned short As[BM * BK];   // row-major [m][k]
    __shared__ unsigned short Bs[BN * BK];
    const int bm = blockIdx.y * BM, bn = blockIdx.x * BN;
    const int tid = threadIdx.x;
    const int wid = tid >> 6, lane = tid & 63;
    const int wm = (wid & 1) * 64, wn = (wid >> 1) * 32;
    const int lm = lane & 15, lqd = lane >> 4;

    f32x4 acc[4][2] = {};

    const int arow = lane >> 2;          // 0..15 within a 16-row chunk
    const int akc  = (lane & 3) * 8;     // k element offset (16 B granules)
    const unsigned short* aG0 = A  + (size_t)(bm + wid * 32 +      arow) * K + akc;
    const unsigned short* aG1 = A  + (size_t)(bm + wid * 32 + 16 + arow) * K + akc;
    const unsigned short* bG  = Bw + (size_t)(bn + wid * 16 +      arow) * K + akc;
    unsigned short* aL0 = As + wid * 1024 + lane * 8;
    unsigned short* aL1 = As + wid * 1024 + 512 + lane * 8;
    unsigned short* bL  = Bs + wid * 512 + lane * 8;

    for (int k0 = 0; k0 < K; k0 += BK) {
        __builtin_amdgcn_global_load_lds((GUI*)(aG0 + k0), (LUI*)aL0, 16, 0, 0);
        __builtin_amdgcn_global_load_lds((GUI*)(aG1 + k0), (LUI*)aL1, 16, 0, 0);
        __builtin_amdgcn_global_load_lds((GUI*)(bG  + k0), (LUI*)bL,  16, 0, 0);
        __syncthreads();
        bf16x8 a[4], b[2];
        #pragma unroll
        for (int i = 0; i < 4; i++)
            a[i] = *(const bf16x8*)(As + (wm + i * 16 + lm) * BK + lqd * 8);
        #pragma unroll
        for (int j = 0; j < 2; j++)
            b[j] = *(const bf16x8*)(Bs + (wn + j * 16 + lm) * BK + lqd * 8);
        #pragma unroll
        for (int i = 0; i < 4; i++)
            #pragma unroll
            for (int j = 0; j < 2; j++)
                acc[i][j] = __builtin_amdgcn_mfma_f32_16x16x32_bf16(a[i], b[j], acc[i][j], 0, 0, 0);
        __syncthreads();
    }

    #pragma unroll
    for (int i = 0; i < 4; i++) {
        int row0 = bm + wm + i * 16 + lqd * 4;
        #pragma unroll
        for (int j = 0; j < 2; j++) {
            int col = bn + wn + j * 16 + lm;
            float bc = BIAS_ROW ? 0.f : bias[col];
            #pragma unroll
            for (int r = 0; r < 4; r++) {
                int row = row0 + r;
                float v = acc[i][j][r] + (BIAS_ROW ? bias[row] : bc);
                if (RELU) v = fmaxf(v, 0.f);
                size_t o = (size_t)row * N + col;
                if (OMODE == 0) OutF[o] = v;
                else if (OMODE == 1) OutB[o] = f2bf(v);
                else { OutF[o] = v; OutB[o] = f2bf(v); }
            }
        }
    }
}

// ---------------------------------------------------------------------------
// Merged off/attn + val GEMM for one layer. Grid dim3(8, 150), BM=128, K=128.
// bx<6: A=qb, W=Woa(384x128): col<256 -> fp16 off (stride 256);
//       col>=256 -> softmax16 -> fp16 attn (stride 128).
// bx>=6: A=srcb, W=Wv(128x128): bf16 val in plane layout [l][h][4800][16].
// ---------------------------------------------------------------------------
__global__ __launch_bounds__(256) void gemm_oav(
    const unsigned short* __restrict__ Aq,
    const unsigned short* __restrict__ Asrc,
    const unsigned short* __restrict__ Woa, const float* __restrict__ boa,
    const unsigned short* __restrict__ Wv,  const float* __restrict__ bv,
    _Float16* __restrict__ OutH, _Float16* __restrict__ OutH2,
    unsigned short* __restrict__ OutV)
{
    constexpr int BK = 32, K = 128;
    __shared__ unsigned short As[128 * BK];
    __shared__ unsigned short Bs[64 * BK];
    const int bx = blockIdx.x;
    const bool isv = bx >= 6;
    const unsigned short* A  = isv ? Asrc : Aq;
    const unsigned short* Bw = isv ? Wv : Woa;
    const float* bias = isv ? bv : boa;
    const int bn = isv ? (bx - 6) * 64 : bx * 64;
    const int bm = blockIdx.y * 128;
    const int tid = threadIdx.x;
    const int wid = tid >> 6, lane = tid & 63;
    const int wm = (wid & 1) * 64, wn = (wid >> 1) * 32;
    const int lm = lane & 15, lqd = lane >> 4;

    f32x4 acc[4][2] = {};

    const int arow = lane >> 2;
    const int akc  = (lane & 3) * 8;
    const unsigned short* aG0 = A  + (size_t)(bm + wid * 32 +      arow) * K + akc;
    const unsigned short* aG1 = A  + (size_t)(bm + wid * 32 + 16 + arow) * K + akc;
    const unsigned short* bG  = Bw + (size_t)(bn + wid * 16 +      arow) * K + akc;
    unsigned short* aL0 = As + wid * 1024 + lane * 8;
    unsigned short* aL1 = As + wid * 1024 + 512 + lane * 8;
    unsigned short* bL  = Bs + wid * 512 + lane * 8;

    for (int k0 = 0; k0 < K; k0 += BK) {
        __builtin_amdgcn_global_load_lds((GUI*)(aG0 + k0), (LUI*)aL0, 16, 0, 0);
        __builtin_amdgcn_global_load_lds((GUI*)(aG1 + k0), (LUI*)aL1, 16, 0, 0);
        __builtin_amdgcn_global_load_lds((GUI*)(bG  + k0), (LUI*)bL,  16, 0, 0);
        __syncthreads();
        bf16x8 a[4], b[2];
        #pragma unroll
        for (int i = 0; i < 4; i++)
            a[i] = *(const bf16x8*)(As + (wm + i * 16 + lm) * BK + lqd * 8);
        #pragma unroll
        for (int j = 0; j < 2; j++)
            b[j] = *(const bf16x8*)(Bs + (wn + j * 16 + lm) * BK + lqd * 8);
        #pragma unroll
        for (int i = 0; i < 4; i++)
            #pragma unroll
            for (int j = 0; j < 2; j++)
                acc[i][j] = __builtin_amdgcn_mfma_f32_16x16x32_bf16(a[i], b[j], acc[i][j], 0, 0, 0);
        __syncthreads();
    }

    #pragma unroll
    for (int i = 0; i < 4; i++) {
        int row0 = bm + wm + i * 16 + lqd * 4;
        #pragma unroll
        for (int j = 0; j < 2; j++) {
            int col = bn + wn + j * 16 + lm;
            float bc = bias[col];
            if (!isv) {
                if (col < 256) {
                    #pragma unroll
                    for (int r = 0; r < 4; r++)
                        OutH[(size_t)(row0 + r) * 256 + col] = (_Float16)(acc[i][j][r] + bc);
                } else {
                    #pragma unroll
                    for (int r = 0; r < 4; r++) {
                        float v = acc[i][j][r] + bc;
                        float m = v;
                        #pragma unroll
                        for (int msk = 1; msk < 16; msk <<= 1)
                            m = fmaxf(m, __shfl_xor(m, msk));
                        float e = __expf(v - m);
                        float s = e;
                        #pragma unroll
                        for (int msk = 1; msk < 16; msk <<= 1)
                            s += __shfl_xor(s, msk);
                        OutH2[(size_t)(row0 + r) * 128 + (col - 256)] = (_Float16)(e / s);
                    }
                }
            } else {
                #pragma unroll
                for (int r = 0; r < 4; r++) {
                    int row = row0 + r;
                    int plane = (row / HWp) * 8 + (col >> 4);
                    size_t o = ((size_t)plane * HWp + (row % HWp)) * 16 + (col & 15);
                    OutV[o] = f2bf(acc[i][j][r] + bc);
                }
            }
        }
    }
}

// ---------------------------------------------------------------------------
// Fully-fused post-attention block, per 32-token block:
//   delta1 = attnout @ W_out^T + b_out
//   y1 = LayerNorm(src + delta1) * g1 + c1          (fp32 kept in registers;
//                                                    bf16 copy in LDS)
//   f = relu(y1 @ Wff1^T + bff1)                    (32 x 512, LDS bf16)
//   delta2 = f @ Wff2^T + bff2
//   y2 = LayerNorm(y1 + delta2) * g2 + c2
// WQ: also write qb = bf16(y2 + pos). WMERGE: write only merge-layout bf16
// output mergeb[pix][n*128+c] (final layer). Otherwise write src fp32 + srcb.
// Phase-A col ownership (wid*32..+32) == phase-C col ownership, so the y1
// residual for LN2 never leaves the wave's registers.
// ---------------------------------------------------------------------------
template<bool WQ, bool WMERGE>
__global__ __launch_bounds__(256) void attn_ff(
    const unsigned short* __restrict__ attnout, const float* __restrict__ srcF_in,
    const unsigned short* __restrict__ Wout, const float* __restrict__ bout,
    const float* __restrict__ g1, const float* __restrict__ c1,
    const unsigned short* __restrict__ Wff1, const float* __restrict__ bff1,
    const unsigned short* __restrict__ Wff2, const float* __restrict__ bff2,
    const float* __restrict__ g2, const float* __restrict__ c2,
    float* __restrict__ outF, unsigned short* __restrict__ outB,
    const float* __restrict__ pos, unsigned short* __restrict__ qb,
    unsigned short* __restrict__ mergeb)
{
    __shared__ unsigned short fs[32 * 520];     // 33,280 B ff activation
    __shared__ unsigned short y1s[32 * 136];    //  8,704 B LN1 output (bf16)
    __shared__ float red[4][2][32];             // cross-wave LN partials
    const int bm = blockIdx.x * 32;
    const int tid = threadIdx.x;
    const int wid = tid >> 6, lane = tid & 63;
    const int lm = lane & 15, lqd = lane >> 4;
    const int wn2 = wid * 32;                   // col ownership, phases A & C

    // ---- Phase A: delta1 = attnout @ Wout^T (cols wn2..wn2+32)
    float y1r[2][2][4];
    {
        f32x4 accA[2][2] = {};
        for (int k0 = 0; k0 < 128; k0 += 32) {
            bf16x8 a[2], b[2];
            #pragma unroll
            for (int i = 0; i < 2; i++)
                a[i] = *(const bf16x8*)(attnout + (size_t)(bm + i * 16 + lm) * 128 + k0 + lqd * 8);
            #pragma unroll
            for (int j = 0; j < 2; j++)
                b[j] = *(const bf16x8*)(Wout + (size_t)(wn2 + j * 16 + lm) * 128 + k0 + lqd * 8);
            #pragma unroll
            for (int i = 0; i < 2; i++)
                #pragma unroll
                for (int j = 0; j < 2; j++)
                    accA[i][j] = __builtin_amdgcn_mfma_f32_16x16x32_bf16(a[i], b[j], accA[i][j], 0, 0, 0);
        }
        #pragma unroll
        for (int i = 0; i < 2; i++)
            #pragma unroll
            for (int j = 0; j < 2; j++) {
                int col = wn2 + j * 16 + lm;
                float bc = bout[col];
                #pragma unroll
                for (int r = 0; r < 4; r++) {
                    int row = bm + i * 16 + lqd * 4 + r;
                    y1r[i][j][r] = accA[i][j][r] + bc + srcF_in[(size_t)row * 128 + col];
                }
            }
    }
    // LN1 stats
    #pragma unroll
    for (int i = 0; i < 2; i++) {
        #pragma unroll
        for (int r = 0; r < 4; r++) {
            float s = y1r[i][0][r] + y1r[i][1][r];
            float q = y1r[i][0][r] * y1r[i][0][r] + y1r[i][1][r] * y1r[i][1][r];
            #pragma unroll
            for (int msk = 1; msk < 16; msk <<= 1) {
                s += __shfl_xor(s, msk);
                q += __shfl_xor(q, msk);
            }
            if (lm == 0) {
                int rl = i * 16 + lqd * 4 + r;
                red[wid][0][rl] = s;
                red[wid][1][rl] = q;
            }
        }
    }
    __syncthreads();
    #pragma unroll
    for (int i = 0; i < 2; i++) {
        float mean[4], inv[4];
        #pragma unroll
        for (int r = 0; r < 4; r++) {
            int rl = i * 16 + lqd * 4 + r;
            float s = red[0][0][rl] + red[1][0][rl] + red[2][0][rl] + red[3][0][rl];
            float q = red[0][1][rl] + red[1][1][rl] + red[2][1][rl] + red[3][1][rl];
            float m = s * (1.0f / 128.0f);
            float v = q * (1.0f / 128.0f) - m * m;
            mean[r] = m;
            inv[r] = rsqrtf(v + 1e-5f);
        }
        #pragma unroll
        for (int j = 0; j < 2; j++) {
            int col = wn2 + j * 16 + lm;
            float gc = g1[col], bc = c1[col];
            #pragma unroll
            for (int r = 0; r < 4; r++) {
                float y = (y1r[i][j][r] - mean[r]) * inv[r] * gc + bc;
                y1r[i][j][r] = y;
                y1s[(i * 16 + lqd * 4 + r) * 136 + col] = f2bf(y);
            }
        }
    }
    __syncthreads();

    // ---- Phase B: f = relu(y1 @ Wff1^T + b); wave wid owns ff cols [wid*128,+128)
    {
        f32x4 acc[2][8] = {};
        const int wn = wid * 128;
        for (int k0 = 0; k0 < 128; k0 += 32) {
            bf16x8 a[2], b[8];
            #pragma unroll
            for (int i = 0; i < 2; i++)
                a[i] = *(const bf16x8*)(y1s + (i * 16 + lm) * 136 + k0 + lqd * 8);
            #pragma unroll
            for (int j = 0; j < 8; j++)
                b[j] = *(const bf16x8*)(Wff1 + (size_t)(wn + j * 16 + lm) * 128 + k0 + lqd * 8);
            #pragma unroll
            for (int i = 0; i < 2; i++)
                #pragma unroll
                for (int j = 0; j < 8; j++)
                    acc[i][j] = __builtin_amdgcn_mfma_f32_16x16x32_bf16(a[i], b[j], acc[i][j], 0, 0, 0);
        }
        #pragma unroll
        for (int i = 0; i < 2; i++) {
            #pragma unroll
            for (int j = 0; j < 8; j++) {
                int col = wn + j * 16 + lm;
                float bc = bff1[col];
                #pragma unroll
                for (int r = 0; r < 4; r++) {
                    int row = i * 16 + lqd * 4 + r;
                    fs[row * 520 + col] = f2bf(fmaxf(acc[i][j][r] + bc, 0.f));
                }
            }
        }
    }
    __syncthreads();

    // ---- Phase C: delta2 = f @ Wff2^T; wave wid owns cols wn2..+32
    f32x4 acc2[2][2] = {};
    for (int k0 = 0; k0 < 512; k0 += 32) {
        bf16x8 a[2], b[2];
        #pragma unroll
        for (int i = 0; i < 2; i++)
            a[i] = *(const bf16x8*)(fs + (i * 16 + lm) * 520 + k0 + lqd * 8);
        #pragma unroll
        for (int j = 0; j < 2; j++)
            b[j] = *(const bf16x8*)(Wff2 + (size_t)(wn2 + j * 16 + lm) * 512 + k0 + lqd * 8);
        #pragma unroll
        for (int i = 0; i < 2; i++)
            #pragma unroll
            for (int j = 0; j < 2; j++)
                acc2[i][j] = __builtin_amdgcn_mfma_f32_16x16x32_bf16(a[i], b[j], acc2[i][j], 0, 0, 0);
    }

    // z2 = delta2 + bias + y1 (registers), LN2
    float z[2][2][4];
    #pragma unroll
    for (int i = 0; i < 2; i++) {
        #pragma unroll
        for (int j = 0; j < 2; j++) {
            int col = wn2 + j * 16 + lm;
            float bc = bff2[col];
            #pragma unroll
            for (int r = 0; r < 4; r++)
                z[i][j][r] = acc2[i][j][r] + bc + y1r[i][j][r];
        }
    }
    __syncthreads();   // red reuse: ensure all LN1 reads done (covered) + fs reads done
    #pragma unroll
    for (int i = 0; i < 2; i++) {
        #pragma unroll
        for (int r = 0; r < 4; r++) {
            float s = z[i][0][r] + z[i][1][r];
            float q = z[i][0][r] * z[i][0][r] + z[i][1][r] * z[i][1][r];
            #pragma unroll
            for (int msk = 1; msk < 16; msk <<= 1) {
                s += __shfl_xor(s, msk);
                q += __shfl_xor(q, msk);
            }
            if (lm == 0) {
                int rl = i * 16 + lqd * 4 + r;
                red[wid][0][rl] = s;
                red[wid][1][rl] = q;
            }
        }
    }
    __syncthreads();

    #pragma unroll
    for (int i = 0; i < 2; i++) {
        float mean[4], inv[4];
        #pragma unroll
        for (int r = 0; r < 4; r++) {
            int rl = i * 16 + lqd * 4 + r;
            float s = red[0][0][rl] + red[1][0][rl] + red[2][0][rl] + red[3][0][rl];
            float q = red[0][1][rl] + red[1][1][rl] + red[2][1][rl] + red[3][1][rl];
            float m = s * (1.0f / 128.0f);
            float v = q * (1.0f / 128.0f) - m * m;
            mean[r] = m;
            inv[r] = rsqrtf(v + 1e-5f);
        }
        #pragma unroll
        for (int j = 0; j < 2; j++) {
            int col = wn2 + j * 16 + lm;
            float gc = g2[col], bc2 = c2[col];
            #pragma unroll
            for (int r = 0; r < 4; r++) {
                int row = bm + i * 16 + lqd * 4 + r;
                float y = (z[i][j][r] - mean[r]) * inv[r] * gc + bc2;
                if constexpr (WMERGE) {
                    int n = row / HWp, pix = row % HWp;
                    mergeb[(size_t)pix * 512 + n * 128 + col] = f2bf(y);
                } else {
                    size_t o = (size_t)row * 128 + col;
                    outF[o] = y;
                    outB[o] = f2bf(y);
                    if constexpr (WQ) qb[o] = f2bf(y + pos[o]);
                }
            }
        }
    }
}

// ---------------------------------------------------------------------------
// Implicit-GEMM 3x3 conv from padded NHWC bf16 input, tap-major weights.
// MODE 0: dconv  — X:(4,82,242,128), stride 2, out: src fp32 + srcb bf16 +
//                  qb = bf16(src+pos), relu.
// MODE 1: uconv  — X:(82,242,128), stride 1, out: d_out fp32 (128,19200)
//                  via LDS-transposed store, relu.
// ---------------------------------------------------------------------------
template<int MODE>
__global__ __launch_bounds__(256) void conv3x3_gemm(
    const unsigned short* __restrict__ X,
    const unsigned short* __restrict__ Wp,
    const float* __restrict__ bias,
    float* __restrict__ OutF, unsigned short* __restrict__ OutB,
    const float* __restrict__ pos, unsigned short* __restrict__ Qb)
{
    constexpr int BM = 128, BN = 64, BK = 32;
    constexpr int SMEM = (MODE == 1) ? 33792 : 12288;
    __shared__ __align__(16) unsigned char smem[SMEM];
    unsigned short* As = (unsigned short*)smem;            // 128*32
    unsigned short* Bs = (unsigned short*)(smem + 8192);   // 64*32
    const int bm = blockIdx.y * BM, bn = blockIdx.x * BN;
    const int tid = threadIdx.x;
    const int wid = tid >> 6, lane = tid & 63;
    const int wm = (wid & 1) * 64, wn = (wid >> 1) * 32;
    const int lm = lane & 15, lqd = lane >> 4;

    f32x4 acc[4][2] = {};

    const int arow = lane >> 2;
    const int akc  = (lane & 3) * 8;
    const int r0 = bm + wid * 32 + arow;
    const int r1 = r0 + 16;
    size_t bA0, bA1;
    if (MODE == 0) {
        int n0 = r0 / HWp, rem0 = r0 % HWp, oh0 = rem0 / WW, ow0 = rem0 % WW;
        int n1 = r1 / HWp, rem1 = r1 % HWp, oh1 = rem1 / WW, ow1 = rem1 % WW;
        bA0 = ((size_t)(n0 * 82 + oh0 * 2) * 242 + ow0 * 2) * 128;
        bA1 = ((size_t)(n1 * 82 + oh1 * 2) * 242 + ow1 * 2) * 128;
    } else {
        int y0 = r0 / RWs, x0 = r0 % RWs;
        int y1 = r1 / RWs, x1 = r1 % RWs;
        bA0 = ((size_t)y0 * 242 + x0) * 128;
        bA1 = ((size_t)y1 * 242 + x1) * 128;
    }
    const unsigned short* bG = Wp + (size_t)(bn + wid * 16 + arow) * 1152 + akc;
    unsigned short* aL0 = As + wid * 1024 + lane * 8;
    unsigned short* aL1 = As + wid * 1024 + 512 + lane * 8;
    unsigned short* bL  = Bs + wid * 512 + lane * 8;

    for (int chunk = 0; chunk < 36; chunk++) {
        int tap = chunk >> 2;
        int cpart = (chunk & 3) << 5;
        int ky = tap / 3, kx = tap % 3;
        int toff = (ky * 242 + kx) * 128 + cpart + akc;
        __builtin_amdgcn_global_load_lds((GUI*)(X + bA0 + toff), (LUI*)aL0, 16, 0, 0);
        __builtin_amdgcn_global_load_lds((GUI*)(X + bA1 + toff), (LUI*)aL1, 16, 0, 0);
        __builtin_amdgcn_global_load_lds((GUI*)(bG + chunk * 32), (LUI*)bL, 16, 0, 0);
        __syncthreads();
        bf16x8 a[4], b[2];
        #pragma unroll
        for (int i = 0; i < 4; i++)
            a[i] = *(const bf16x8*)(As + (wm + i * 16 + lm) * BK + lqd * 8);
        #pragma unroll
        for (int j = 0; j < 2; j++)
            b[j] = *(const bf16x8*)(Bs + (wn + j * 16 + lm) * BK + lqd * 8);
        #pragma unroll
        for (int i = 0; i < 4; i++)
            #pragma unroll
            for (int j = 0; j < 2; j++)
                acc[i][j] = __builtin_amdgcn_mfma_f32_16x16x32_bf16(a[i], b[j], acc[i][j], 0, 0, 0);
        __syncthreads();
    }

    if (MODE == 0) {
        #pragma unroll
        for (int i = 0; i < 4; i++) {
            int row0 = bm + wm + i * 16 + lqd * 4;
            #pragma unroll
            for (int j = 0; j < 2; j++) {
                int col = bn + wn + j * 16 + lm;
                float bc = bias[col];
                #pragma unroll
                for (int r = 0; r < 4; r++) {
                    float v = fmaxf(acc[i][j][r] + bc, 0.f);
                    size_t o = (size_t)(row0 + r) * 128 + col;
                    OutF[o] = v;
                    OutB[o] = f2bf(v);
                    Qb[o] = f2bf(v + pos[o]);
                }
            }
        }
    } else {
        float* Ts = (float*)smem;                 // 64 x 132 floats
        #pragma unroll
        for (int i = 0; i < 4; i++) {
            int lr0 = wm + i * 16 + lqd * 4;
            #pragma unroll
            for (int j = 0; j < 2; j++) {
                int lc = wn + j * 16 + lm;
                float bc = bias[bn + lc];
                #pragma unroll
                for (int r = 0; r < 4; r++)
                    Ts[lc * 132 + lr0 + r] = fmaxf(acc[i][j][r] + bc, 0.f);
            }
        }
        __syncthreads();
        for (int f = tid; f < 64 * 32; f += 256) {
            int ch = f >> 5, p4 = (f & 31) << 2;
            float4 v4 = *(const float4*)(Ts + ch * 132 + p4);
            *(float4*)(OutF + (size_t)(bn + ch) * 19200 + bm + p4) = v4;
        }
    }
}

// ---------------------------------------------------------------------------
// One-dispatch prep: linear weights -> bf16, [W_off;W_attn] concat, conv
// weights tap-major, halo zero, pos embed, and (block range) the NCHW->NHWC
// input transpose.
// ---------------------------------------------------------------------------
__global__ __launch_bounds__(256) void prep_all(
    const float* __restrict__ W_val, const float* __restrict__ W_out,
    const float* __restrict__ W_ff1, const float* __restrict__ W_ff2,
    const float* __restrict__ merge_w,
    const float* __restrict__ Woff, const float* __restrict__ boff,
    const float* __restrict__ Wattn, const float* __restrict__ battn,
    const float* __restrict__ dconv_w, const float* __restrict__ uconv_w,
    const float* __restrict__ lvl_emb, const float* __restrict__ x,
    unsigned short* __restrict__ wb, unsigned short* __restrict__ wcat,
    float* __restrict__ bcat, unsigned short* __restrict__ dconv_wb,
    unsigned short* __restrict__ uconv_wb, unsigned short* __restrict__ xp,
    float* __restrict__ pos)
{
    __shared__ unsigned short t[240 * 36];       // used by transpose blocks only
    int blk = blockIdx.x;
    if (blk >= 13831) {
        // NCHW fp32 (4,128,80,240) -> padded NHWC bf16 (4,82,242,128)
        int b = blk - 13831;                     // < 1280: (n, y, 32-ch tile)
        int ct = b & 3;
        int tmp = b >> 2;
        int y = tmp % 80, n = tmp / 80;
        const float* xin = x + (((size_t)(n * 128 + ct * 32)) * 80 + y) * 240;
        for (int f = threadIdx.x; f < 32 * 240; f += 256) {
            int c = f / 240, xc = f % 240;
            t[xc * 36 + c] = f2bf(xin[(size_t)c * 19200 + xc]);
        }
        __syncthreads();
        unsigned short* out = xp + (((size_t)(n * 82 + y + 1)) * 242 + 1) * 128 + ct * 32;
        for (int f = threadIdx.x; f < 240 * 8; f += 256) {
            int xc = f >> 3, c4 = (f & 7) << 2;
            ushort4 v = *(const ushort4*)(t + xc * 36 + c4);
            *(ushort4*)(out + (size_t)xc * 128 + c4) = v;
        }
        return;
    }
    int idx = blk * 256 + threadIdx.x;
    if (idx < 557056) {
        const float* src; int rel;
        if      (idx <  49152) { src = W_val;   rel = idx;          }
        else if (idx <  98304) { src = W_out;   rel = idx - 49152;  }
        else if (idx < 294912) { src = W_ff1;   rel = idx - 98304;  }
        else if (idx < 491520) { src = W_ff2;   rel = idx - 294912; }
        else                   { src = merge_w; rel = idx - 491520; }
        wb[idx] = f2bf(src[rel]);
    } else if (idx < 705664) {
        int j = idx - 557056;
        if (j < 147456) {
            int layer = j / 49152, r = (j / 128) % 384, c = j & 127;
            float v = (r < 256) ? Woff[((size_t)layer * 256 + r) * 128 + c]
                                : Wattn[((size_t)layer * 128 + (r - 256)) * 128 + c];
            wcat[j] = f2bf(v);
        } else if (j < 148608) {
            int k = j - 147456;
            int layer = k / 384, r = k % 384;
            bcat[k] = (r < 256) ? boff[layer * 256 + r] : battn[layer * 128 + (r - 256)];
        }
    } else if (idx < 853120) {
        int j = idx - 705664;
        int cout = j / 1152, k = j % 1152;
        int tap = k >> 7, cin = k & 127;
        dconv_wb[j] = f2bf(dconv_w[(cout * 128 + cin) * 9 + tap]);
    } else if (idx < 1000576) {
        int j = idx - 853120;
        int cout = j / 1152, k = j % 1152;
        int tap = k >> 7, cin = k & 127;
        uconv_wb[j] = f2bf(uconv_w[(cout * 128 + cin) * 9 + tap]);
    } else if (idx < 1083008) {
        int j = idx - 1000576;                 // < 4*644*32
        int c4 = (j & 31) << 2;
        int tt = j >> 5;
        int p = tt % 644, n = tt / 644;
        int y, xx;
        if (p < 242)      { y = 0;       xx = p;       }
        else if (p < 484) { y = 81;      xx = p - 242; }
        else if (p < 564) { y = p - 483; xx = 0;       }
        else              { y = p - 563; xx = 241;     }
        ushort4 z = {0, 0, 0, 0};
        *(ushort4*)(xp + (((size_t)(n * 82 + y)) * 242 + xx) * 128 + c4) = z;
    } else if (idx < 3540608) {
        int j = idx - 1083008;                 // < LQ*128
        int c = j & 127;
        int q = j >> 7;
        int n = q / HWp, pix = q % HWp;
        int h = pix / WW, w = pix % WW;
        int cc = (c < 64) ? c : (c - 64);
        float coord = (c < 64) ? (float)(h + 1) : (float)(w + 1);
        float denom = (c < 64) ? 40.0f : 120.0f;
        float e = coord / (denom + 1e-6f) * 6.283185307179586f;
        float expo = (float)(cc & ~1) * (1.0f / 64.0f);
        float dim_t = __expf(expo * 9.2103403719761836f);   // 10000^expo
        float p = e / dim_t;
        float v = (cc & 1) ? __cosf(p) : __sinf(p);
        pos[j] = v + lvl_emb[n * CCh + c];
    }
}

__device__ inline void fma8(float* acc, float w, uint4 v)
{
    acc[0] = fmaf(w, __uint_as_float(v.x << 16),          acc[0]);
    acc[1] = fmaf(w, __uint_as_float(v.x & 0xffff0000u),  acc[1]);
    acc[2] = fmaf(w, __uint_as_float(v.y << 16),          acc[2]);
    acc[3] = fmaf(w, __uint_as_float(v.y & 0xffff0000u),  acc[3]);
    acc[4] = fmaf(w, __uint_as_float(v.z << 16),          acc[4]);
    acc[5] = fmaf(w, __uint_as_float(v.z & 0xffff0000u),  acc[5]);
    acc[6] = fmaf(w, __uint_as_float(v.w << 16),          acc[6]);
    acc[7] = fmaf(w, __uint_as_float(v.w & 0xffff0000u),  acc[7]);
}
__device__ inline unsigned int pk2(float a, float b)
{ return (unsigned int)f2bf(a) | ((unsigned int)f2bf(b) << 16); }

// ---------------------------------------------------------------------------
// MS deformable attention sampling. Grid dim3(150, 8): blockIdx.y = head.
// Thread = (query, channel-half).
// ---------------------------------------------------------------------------
__global__ __launch_bounds__(256) void deform_sample(
    const unsigned short* __restrict__ val, const _Float16* __restrict__ off,
    const _Float16* __restrict__ attn, unsigned short* __restrict__ out)
{
    int t = threadIdx.x;
    int q = blockIdx.x * 128 + (t >> 1);
    int half = t & 1;
    int h = blockIdx.y;
    int pix = q % HWp;
    int qy = pix / WW, qx = pix % WW;
    const _Float16* offp = off + (size_t)q * 256 + h * 32;
    const _Float16* ap   = attn + (size_t)q * 128 + h * 16;
    h16x8 ovv[4];
    ovv[0] = *(const h16x8*)(offp);
    ovv[1] = *(const h16x8*)(offp + 8);
    ovv[2] = *(const h16x8*)(offp + 16);
    ovv[3] = *(const h16x8*)(offp + 24);
    h16x8 avv[2];
    avv[0] = *(const h16x8*)(ap);
    avv[1] = *(const h16x8*)(ap + 8);
    const unsigned short* vh = val + half * 8;
    float acc[8] = {};
    #pragma unroll
    for (int l = 0; l < 4; l++) {
        const unsigned short* vb = vh + (size_t)(l * 8 + h) * (HWp * 16);
        #pragma unroll
        for (int p = 0; p < 4; p++) {
            float ox = (float)ovv[l][2 * p];
            float oy = (float)ovv[l][2 * p + 1];
            int ai = l * 4 + p;
            float a = (float)avv[ai >> 3][ai & 7];
            float x = (float)qx + ox;
            float y = (float)qy + oy;
            float xf = floorf(x), yf = floorf(y);
            int x0 = (int)xf, y0 = (int)yf;
            float wx1 = x - xf, wy1 = y - yf;
            float wx0 = 1.f - wx1, wy0 = 1.f - wy1;
            #pragma unroll
            for (int dy = 0; dy < 2; dy++) {
                int yc = y0 + dy;
                bool vy = (unsigned)yc < (unsigned)HH;
                int yci = min(max(yc, 0), HH - 1);
                float wyv = dy ? wy1 : wy0;
                #pragma unroll
                for (int dx = 0; dx < 2; dx++) {
                    int xc = x0 + dx;
                    bool vld = vy && ((unsigned)xc < (unsigned)WW);
                    int xci = min(max(xc, 0), WW - 1);
                    float wgt = vld ? a * wyv * (dx ? wx1 : wx0) : 0.f;
                    uint4 v = *(const uint4*)(vb + (size_t)(yci * WW + xci) * 16);
                    fma8(acc, wgt, v);
                }
            }
        }
    }
    uint4 o = { pk2(acc[0], acc[1]), pk2(acc[2], acc[3]),
                pk2(acc[4], acc[5]), pk2(acc[6], acc[7]) };
    *(uint4*)(out + (size_t)q * CCh + h * 16 + half * 8) = o;
}

// Bilinear 2x upsample -> padded NHWC bf16 (82,242,128), halo zeroed
__global__ void upsample_nhwc(const float* __restrict__ m, unsigned short* __restrict__ up)
{
    unsigned idx = blockIdx.x * 256u + threadIdx.x;   // < 82*242*32
    if (idx >= 82u * 242u * 32u) return;
    int c4 = (idx & 31) << 2;
    int p = idx >> 5;
    int px = p % 242, py = p / 242;
    ushort4 o = {0, 0, 0, 0};
    if (py >= 1 && py <= RHs && px >= 1 && px <= RWs) {
        int y = py - 1, x = px - 1;
        float fy = (y + 0.5f) * 0.5f - 0.5f;
        float fx = (x + 0.5f) * 0.5f - 0.5f;
        float fyf = floorf(fy), fxf = floorf(fx);
        int y0 = (int)fyf, x0 = (int)fxf;
        float wy = fy - fyf, wx = fx - fxf;
        int y0c = max(y0, 0), y1c = min(y0 + 1, HH - 1);
        int x0c = max(x0, 0), x1c = min(x0 + 1, WW - 1);
        unsigned short r[4];
        #pragma unroll
        for (int cc = 0; cc < 4; cc++) {
            const float* mp = m + (size_t)(c4 + cc) * HWp;
            float v00 = mp[y0c * WW + x0c], v01 = mp[y0c * WW + x1c];
            float v10 = mp[y1c * WW + x0c], v11 = mp[y1c * WW + x1c];
            float v = (1.f - wy) * ((1.f - wx) * v00 + wx * v01)
                    + wy * ((1.f - wx) * v10 + wx * v11);
            r[cc] = f2bf(v);
        }
        o.x = r[0]; o.y = r[1]; o.z = r[2]; o.w = r[3];
    }
    *(ushort4*)(up + (size_t)p * 128 + c4) = o;
}

// ---------------------------------------------------------------------------
extern "C" void kernel_launch(void* const* d_in, const int* in_sizes, int n_in,
                              void* d_out, int out_size, void* d_ws, size_t ws_size,
                              hipStream_t stream)
{
    const float* x       = (const float*)d_in[0];
    const float* dconv_w = (const float*)d_in[1];
    const float* dconv_b = (const float*)d_in[2];
    const float* lvl_emb = (const float*)d_in[3];
    const float* W_off   = (const float*)d_in[4];
    const float* b_off   = (const float*)d_in[5];
    const float* W_attn  = (const float*)d_in[6];
    const float* b_attn  = (const float*)d_in[7];
    const float* W_val   = (const float*)d_in[8];
    const float* b_val   = (const float*)d_in[9];
    const float* W_out   = (const float*)d_in[10];
    const float* b_out   = (const float*)d_in[11];
    const float* ln1_g   = (const float*)d_in[12];
    const float* ln1_b   = (const float*)d_in[13];
    const float* W_ff1   = (const float*)d_in[14];
    const float* b_ff1   = (const float*)d_in[15];
    const float* W_ff2   = (const float*)d_in[16];
    const float* b_ff2   = (const float*)d_in[17];
    const float* ln2_g   = (const float*)d_in[18];
    const float* ln2_b   = (const float*)d_in[19];
    const float* merge_w = (const float*)d_in[20];
    const float* merge_b = (const float*)d_in[21];
    const float* uconv_w = (const float*)d_in[22];
    const float* uconv_b = (const float*)d_in[23];

    char* wsb = (char*)d_ws;
    unsigned short* xp       = (unsigned short*)(wsb);               // 20,320,256 B (4,82,242,128)
    unsigned short* up       = (unsigned short*)(wsb + 20320256);    //  5,080,064 B (82,242,128)
    float*          src      = (float*)(wsb + 25400320);             //  9,830,400 B
    unsigned short* srcb     = (unsigned short*)(wsb + 35230720);    //  4,915,200 B
    float*          pos      = (float*)(wsb + 40145920);             //  9,830,400 B
    unsigned short* qb       = (unsigned short*)(wsb + 49976320);    //  4,915,200 B
    unsigned short* valb     = (unsigned short*)(wsb + 54891520);    //  4,915,200 B
    _Float16*       attnh    = (_Float16*)(wsb + 59806720);          //  4,915,200 B
    unsigned short* attnoutb = (unsigned short*)(wsb + 69637120);    //  4,915,200 B
    unsigned short* wb       = (unsigned short*)(wsb + 104043520);   //  1,114,112 B
    unsigned short* dconv_wb = (unsigned short*)(wsb + 105452544);   //    294,912 B
    unsigned short* uconv_wb = (unsigned short*)(wsb + 105747456);   //    294,912 B
    unsigned short* wcat     = (unsigned short*)(wsb + 106042368);   //    294,912 B
    float*          bcat     = (float*)(wsb + 106337280);            //      4,608 B (end 106,341,888)
    // aliases (lifetimes disjoint):
    _Float16*       offh     = (_Float16*)xp;    // layers: xp dead after dconv gemm
    unsigned short* merge_in = up;               // written by layer-2 attn_ff; consumed before upsample writes up
    float*          mbuf     = (float*)valb;     // after layers
    float* outp = (float*)d_out;

    // bf16 linear weight table offsets (elements)
    unsigned short* W_val_b  = wb;
    unsigned short* W_out_b  = wb + 49152;
    unsigned short* W_ff1_b  = wb + 98304;
    unsigned short* W_ff2_b  = wb + 294912;
    unsigned short* merge_wb = wb + 491520;

    // 0) one-dispatch prep: weights, halo, pos, input transpose
    prep_all<<<15111, 256, 0, stream>>>(
        W_val, W_out, W_ff1, W_ff2, merge_w, W_off, b_off, W_attn, b_attn,
        dconv_w, uconv_w, lvl_emb, x,
        wb, wcat, bcat, dconv_wb, uconv_wb, xp, pos);

    // 1) downsample conv (implicit GEMM) -> src fp32 + srcb bf16 + qb, relu
    conv3x3_gemm<0><<<dim3(2, 150), 256, 0, stream>>>(
        xp, dconv_wb, dconv_b, src, srcb, pos, qb);

    // 2) encoder layers (3 dispatches each)
    for (int i = 0; i < 3; i++) {
        gemm_oav<<<dim3(8, 150), 256, 0, stream>>>(
            qb, srcb,
            wcat + (size_t)i * 49152, bcat + i * 384,
            W_val_b + (size_t)i * 16384, b_val + i * 128,
            offh, attnh, valb);
        deform_sample<<<dim3(150, 8), 256, 0, stream>>>(valb, offh, attnh, attnoutb);
        if (i < 2) {
            attn_ff<true, false><<<600, 256, 0, stream>>>(
                attnoutb, src,
                W_out_b + (size_t)i * 16384, b_out + i * 128,
                ln1_g + i * 128, ln1_b + i * 128,
                W_ff1_b + (size_t)i * 65536, b_ff1 + i * 512,
                W_ff2_b + (size_t)i * 65536, b_ff2 + i * 128,
                ln2_g + i * 128, ln2_b + i * 128,
                src, srcb, pos, qb, nullptr);
        } else {
            attn_ff<false, true><<<600, 256, 0, stream>>>(
                attnoutb, src,
                W_out_b + (size_t)i * 16384, b_out + i * 128,
                ln1_g + i * 128, ln1_b + i * 128,
                W_ff1_b + (size_t)i * 65536, b_ff1 + i * 512,
                W_ff2_b + (size_t)i * 65536, b_ff2 + i * 128,
                ln2_g + i * 128, ln2_b + i * 128,
                nullptr, nullptr, nullptr, nullptr, merge_in);
        }
    }

    // 3) merge 1x1 conv, weights-as-A trick: mbuf[128,4800]
    gemm_bf16<true, true, 0><<<dim3(75, 1), 256, 0, stream>>>(
        merge_wb, merge_in, merge_b, mbuf, nullptr, 128, 4800, 512);

    // 4) bilinear 2x upsample -> padded NHWC bf16
    upsample_nhwc<<<2482, 256, 0, stream>>>(mbuf, up);

    // 5) uconv (implicit GEMM, transposed store) -> d_out (128,19200), relu
    conv3x3_gemm<1><<<dim3(2, 150), 256, 0, stream>>>(
        up, uconv_wb, uconv_b, outp, nullptr, nullptr, nullptr);
}